// Round 1
// baseline (72492.841 us; speedup 1.0000x reference)
//
// ViT-Base/16 forward + JVP (jax.jvp) on MI355X — Round 0: correctness-first fp32.
// Structure: generic batched tiled GEMM (64x64x16 LDS, 4x4/thread) + LN-JVP,
// softmax-JVP, GELU-JVP, im2col, assemble kernels. All fp32.
#include <hip/hip_runtime.h>
#include <math.h>

static constexpr int B_   = 32;
static constexpr int S_   = 197;   // tokens
static constexpr int D_   = 768;
static constexpr int H_   = 12;
static constexpr int DH_  = 64;
static constexpr int L_   = 12;
static constexpr int MD_  = 3072;
static constexpr int NC_  = 1000;
static constexpr int GP_  = 196;   // 14*14 patches

// ---------------- reduction helpers (blockDim.x == 256) ----------------
__device__ __forceinline__ float blk_sum(float v, float* smem) {
    #pragma unroll
    for (int off = 32; off > 0; off >>= 1) v += __shfl_down(v, off);
    __syncthreads();
    if ((threadIdx.x & 63) == 0) smem[threadIdx.x >> 6] = v;
    __syncthreads();
    return smem[0] + smem[1] + smem[2] + smem[3];
}
__device__ __forceinline__ float blk_max(float v, float* smem) {
    #pragma unroll
    for (int off = 32; off > 0; off >>= 1) v = fmaxf(v, __shfl_down(v, off));
    __syncthreads();
    if ((threadIdx.x & 63) == 0) smem[threadIdx.x >> 6] = v;
    __syncthreads();
    return fmaxf(fmaxf(smem[0], smem[1]), fmaxf(smem[2], smem[3]));
}

// ---------------- generic batched GEMM ----------------
// C[m,n] (+)= alpha * sum_k A[m*lda+k] * (TRANSB ? B[n*ldb+k] : B[k*ldb+n]) (+ bias[n])
// batch index z: b1 = z / batch2, b2 = z % batch2; each operand offset by b1*s?1 + b2*s?2.
template<bool TRANSB, bool ACC, bool BIAS>
__global__ __launch_bounds__(256) void gemm_kernel(
    const float* __restrict__ A, const float* __restrict__ Bm,
    const float* __restrict__ bias, float* __restrict__ C,
    int M, int N, int K, int lda, int ldb, int ldc,
    long long sA1, long long sA2, long long sB1, long long sB2,
    long long sC1, long long sC2, int batch2, float alpha)
{
    const int bz = blockIdx.z;
    const int b1 = bz / batch2, b2 = bz - b1 * batch2;
    A  += b1 * sA1 + b2 * sA2;
    Bm += b1 * sB1 + b2 * sB2;
    C  += b1 * sC1 + b2 * sC2;

    const int tile_m = blockIdx.y * 64, tile_n = blockIdx.x * 64;
    __shared__ float As[16][64];
    __shared__ float Bs[16][64];
    const int tid = threadIdx.x;
    const int tx = tid & 15, ty = tid >> 4;   // 16x16 thread grid, 4x4 per thread
    float acc[4][4] = {};

    for (int k0 = 0; k0 < K; k0 += 16) {
        { // A tile: [64 m][16 k] -> As[k][m]
            const int row = tid >> 2;
            const int kc  = (tid & 3) * 4;
            const int gm  = tile_m + row;
            #pragma unroll
            for (int i = 0; i < 4; ++i) {
                const int gk = k0 + kc + i;
                float v = 0.f;
                if (gm < M && gk < K) v = A[(long long)gm * lda + gk];
                As[kc + i][row] = v;
            }
        }
        if (TRANSB) { // B[n][k] -> Bs[k][n]
            const int row = tid >> 2;
            const int kc  = (tid & 3) * 4;
            const int gn  = tile_n + row;
            #pragma unroll
            for (int i = 0; i < 4; ++i) {
                const int gk = k0 + kc + i;
                float v = 0.f;
                if (gn < N && gk < K) v = Bm[(long long)gn * ldb + gk];
                Bs[kc + i][row] = v;
            }
        } else {      // B[k][n] -> Bs[k][n]
            const int kk = tid >> 4;
            const int nc = (tid & 15) * 4;
            const int gk = k0 + kk;
            #pragma unroll
            for (int i = 0; i < 4; ++i) {
                const int gn = tile_n + nc + i;
                float v = 0.f;
                if (gk < K && gn < N) v = Bm[(long long)gk * ldb + gn];
                Bs[kk][nc + i] = v;
            }
        }
        __syncthreads();
        #pragma unroll
        for (int kk = 0; kk < 16; ++kk) {
            float a[4], b[4];
            #pragma unroll
            for (int i = 0; i < 4; ++i) a[i] = As[kk][ty * 4 + i];
            #pragma unroll
            for (int j = 0; j < 4; ++j) b[j] = Bs[kk][tx * 4 + j];
            #pragma unroll
            for (int i = 0; i < 4; ++i)
                #pragma unroll
                for (int j = 0; j < 4; ++j)
                    acc[i][j] += a[i] * b[j];
        }
        __syncthreads();
    }
    #pragma unroll
    for (int i = 0; i < 4; ++i) {
        const int gm = tile_m + ty * 4 + i;
        if (gm >= M) continue;
        #pragma unroll
        for (int j = 0; j < 4; ++j) {
            const int gn = tile_n + tx * 4 + j;
            if (gn >= N) continue;
            float v = acc[i][j] * alpha;
            if (BIAS) v += bias[gn];
            const long long off = (long long)gm * ldc + gn;
            if (ACC) C[off] += v; else C[off] = v;
        }
    }
}

// ---------------- LayerNorm JVP ----------------
// one block (256 thr) per row of 768; y = (x-mu)*r*g + b ; dy per JVP.
__global__ __launch_bounds__(256) void ln_jvp_kernel(
    const float* __restrict__ z, const float* __restrict__ dz,
    const float* __restrict__ g, const float* __restrict__ b,
    float* __restrict__ y, float* __restrict__ dy)
{
    const long long row = blockIdx.x;
    const float* xr  = z  + row * D_;
    const float* dxr = dz + row * D_;
    float* yr  = y  + row * D_;
    float* dyr = dy + row * D_;
    __shared__ float smem[4];
    const int t = threadIdx.x;
    float x[3], dx[3];
    #pragma unroll
    for (int i = 0; i < 3; ++i) { x[i] = xr[t + 256 * i]; dx[i] = dxr[t + 256 * i]; }
    float sx = x[0] + x[1] + x[2];
    float sdx = dx[0] + dx[1] + dx[2];
    sx  = blk_sum(sx, smem);
    sdx = blk_sum(sdx, smem);
    const float mu = sx / D_, dmu = sdx / D_;
    float sv = 0.f, sc = 0.f;
    #pragma unroll
    for (int i = 0; i < 3; ++i) {
        const float xc = x[i] - mu;
        sv += xc * xc;
        sc += xc * (dx[i] - dmu);
    }
    sv = blk_sum(sv, smem);
    sc = blk_sum(sc, smem);
    const float var  = sv / D_;
    const float rstd = rsqrtf(var + 1e-6f);
    const float k2   = (sc / D_) * rstd * rstd;   // (dvar/2)/sigma^2
    #pragma unroll
    for (int i = 0; i < 3; ++i) {
        const int c = t + 256 * i;
        const float yh  = (x[i] - mu) * rstd;
        const float dyh = (dx[i] - dmu) * rstd - yh * k2;
        yr[c]  = yh * g[c] + b[c];
        dyr[c] = dyh * g[c];
    }
}

// ---------------- softmax JVP (in place) ----------------
// one block per row of length S_=197; a = softmax(s); da = a*(ds - sum(a*ds))
__global__ __launch_bounds__(256) void softmax_jvp_kernel(
    float* __restrict__ a, float* __restrict__ da)
{
    const long long row = blockIdx.x;
    float* sr  = a  + row * S_;
    float* dsr = da + row * S_;
    __shared__ float smem[4];
    const int t = threadIdx.x;
    float x = -3.4e38f, dx = 0.f;
    if (t < S_) { x = sr[t]; dx = dsr[t]; }
    const float m = blk_max(x, smem);
    const float e = (t < S_) ? expf(x - m) : 0.f;
    const float den = blk_sum(e, smem);
    const float av = e / den;
    const float tsum = blk_sum(av * dx, smem);
    if (t < S_) { sr[t] = av; dsr[t] = av * (dx - tsum); }
}

// ---------------- exact GELU JVP (in place) ----------------
__global__ __launch_bounds__(256) void gelu_jvp_kernel(
    float* __restrict__ h, float* __restrict__ dh, int total)
{
    for (int i = blockIdx.x * blockDim.x + threadIdx.x; i < total;
         i += gridDim.x * blockDim.x) {
        const float u = h[i], du = dh[i];
        const float cdf = 0.5f * (1.0f + erff(u * 0.70710678118654752f));
        const float pdf = 0.3989422804014327f * expf(-0.5f * u * u);
        h[i]  = u * cdf;
        dh[i] = du * (cdf + u * pdf);
    }
}

// ---------------- im2col: x[B,3,224,224] -> xp[B*196, 768] (k = c*256+p*16+q) --------
__global__ __launch_bounds__(256) void im2col_kernel(
    const float* __restrict__ x, float* __restrict__ xp, int total)
{
    for (int i = blockIdx.x * blockDim.x + threadIdx.x; i < total;
         i += gridDim.x * blockDim.x) {
        const int k  = i % 768;
        const int m  = i / 768;
        const int gh = m % GP_;
        const int n  = m / GP_;
        const int q  = k & 15;
        const int p  = (k >> 4) & 15;
        const int c  = k >> 8;
        const int hc = gh % 14, gr = gh / 14;
        const int ir = gr * 16 + p, ic = hc * 16 + q;
        xp[i] = x[(((long long)n * 3 + c) * 224 + ir) * 224 + ic];
    }
}

// ---------------- assemble: class token + pos_emb; zero dz cls row ----------------
__global__ __launch_bounds__(256) void assemble_kernel(
    float* __restrict__ z, float* __restrict__ dz,
    const float* __restrict__ cls, const float* __restrict__ pos, int total)
{
    for (int i = blockIdx.x * blockDim.x + threadIdx.x; i < total;
         i += gridDim.x * blockDim.x) {
        const int d = i % D_;
        const int s = (i / D_) % S_;
        if (s == 0) {
            z[i]  = cls[d] + pos[d];
            dz[i] = 0.f;
        } else {
            z[i] += pos[s * D_ + d];
        }
    }
}

// ---------------- host-side GEMM dispatch ----------------
static inline void gemm(hipStream_t st, const float* A, const float* Bm, const float* bias,
                        float* C, int M, int N, int K, int lda, int ldb, int ldc,
                        long long sA1, long long sA2, long long sB1, long long sB2,
                        long long sC1, long long sC2, int batch1, int batch2,
                        float alpha, bool transB, bool acc, bool hasbias)
{
    dim3 grid((N + 63) / 64, (M + 63) / 64, batch1 * batch2);
    dim3 blk(256);
#define GK(TB, AC, BI) gemm_kernel<TB, AC, BI><<<grid, blk, 0, st>>>( \
        A, Bm, bias, C, M, N, K, lda, ldb, ldc, sA1, sA2, sB1, sB2, sC1, sC2, batch2, alpha)
    if (transB) {
        if (acc)  { if (hasbias) GK(true,  true,  true);  else GK(true,  true,  false); }
        else      { if (hasbias) GK(true,  false, true);  else GK(true,  false, false); }
    } else {
        if (acc)  { if (hasbias) GK(false, true,  true);  else GK(false, true,  false); }
        else      { if (hasbias) GK(false, false, true);  else GK(false, false, false); }
    }
#undef GK
}

extern "C" void kernel_launch(void* const* d_in, const int* in_sizes, int n_in,
                              void* d_out, int out_size, void* d_ws, size_t ws_size,
                              hipStream_t stream)
{
    const float* x       = (const float*)d_in[0];
    const float* tangent = (const float*)d_in[1];
    const float* conv_w  = (const float*)d_in[2];
    const float* conv_b  = (const float*)d_in[3];
    const float* cls     = (const float*)d_in[4];
    const float* pos     = (const float*)d_in[5];
    const float* ln1_g   = (const float*)d_in[6];
    const float* ln1_b   = (const float*)d_in[7];
    const float* qkv_w   = (const float*)d_in[8];
    const float* qkv_b   = (const float*)d_in[9];
    const float* out_w   = (const float*)d_in[10];
    const float* out_b   = (const float*)d_in[11];
    const float* ln2_g   = (const float*)d_in[12];
    const float* ln2_b   = (const float*)d_in[13];
    const float* fc1_w   = (const float*)d_in[14];
    const float* fc1_b   = (const float*)d_in[15];
    const float* fc2_w   = (const float*)d_in[16];
    const float* fc2_b   = (const float*)d_in[17];
    const float* lnf_g   = (const float*)d_in[18];
    const float* lnf_b   = (const float*)d_in[19];
    const float* head_w  = (const float*)d_in[20];
    const float* head_b  = (const float*)d_in[21];
    float* out = (float*)d_out;

    // ---- workspace arena (fp32), ~313 MB total ----
    const long long ZSZ = (long long)B_ * S_ * D_;          // 4,841,472
    const long long QSZ = (long long)B_ * S_ * 3 * D_;      // 14,524,416
    const long long ASZ = (long long)B_ * H_ * S_ * S_;     // 14,902,656
    const long long RSZ = QSZ + ASZ;                        // 29,427,072
    float* ws = (float*)d_ws;
    float* z    = ws;
    float* dz   = z  + ZSZ;
    float* y    = dz + ZSZ;
    float* dy   = y  + ZSZ;
    float* R1   = dy + ZSZ;
    float* R2   = R1 + RSZ;
    float* qkv   = R1;           float* attn  = R1 + QSZ;   // scores/probs
    float* hbuf  = R1;                                      // mlp hidden (aliases dead qkv+attn)
    float* xp    = R1;                                      // im2col (aliases dead qkv)
    float* dqkv  = R2;           float* dattn = R2 + QSZ;
    float* dhbuf = R2;
    float* dxp   = R2;

    const int nBS = B_ * S_;                 // 6304
    const long long SD = (long long)S_ * D_; // 151296

    // ---- patch embedding ----
    {
        const int total = B_ * GP_ * D_;     // 4,816,896
        im2col_kernel<<<(total + 255) / 256, 256, 0, stream>>>(x, xp, total);
        im2col_kernel<<<(total + 255) / 256, 256, 0, stream>>>(tangent, dxp, total);
        // tok = xp @ conv_w^T + conv_b, written into z rows s=1..196 (batched over n)
        gemm(stream, xp,  conv_w, conv_b, z + D_,  GP_, D_, D_, D_, D_, D_,
             (long long)GP_ * D_, 0, 0, 0, SD, 0, B_, 1, 1.f, true, false, true);
        gemm(stream, dxp, conv_w, nullptr, dz + D_, GP_, D_, D_, D_, D_, D_,
             (long long)GP_ * D_, 0, 0, 0, SD, 0, B_, 1, 1.f, true, false, false);
        const int tz = (int)(B_ * SD);
        assemble_kernel<<<(tz + 255) / 256, 256, 0, stream>>>(z, dz, cls, pos, tz);
    }

    // ---- transformer blocks ----
    for (int l = 0; l < L_; ++l) {
        const float* l1g = ln1_g + (long long)l * D_;
        const float* l1b = ln1_b + (long long)l * D_;
        const float* qw  = qkv_w + (long long)l * 3 * D_ * D_;
        const float* qb  = qkv_b + (long long)l * 3 * D_;
        const float* ow  = out_w + (long long)l * D_ * D_;
        const float* ob  = out_b + (long long)l * D_;
        const float* l2g = ln2_g + (long long)l * D_;
        const float* l2b = ln2_b + (long long)l * D_;
        const float* f1w = fc1_w + (long long)l * MD_ * D_;
        const float* f1b = fc1_b + (long long)l * MD_;
        const float* f2w = fc2_w + (long long)l * D_ * MD_;
        const float* f2b = fc2_b + (long long)l * D_;

        // LN1
        ln_jvp_kernel<<<nBS, 256, 0, stream>>>(z, dz, l1g, l1b, y, dy);
        // QKV
        gemm(stream, y,  qw, qb,      qkv,  nBS, 3 * D_, D_, D_, D_, 3 * D_,
             0,0,0,0,0,0, 1, 1, 1.f, true, false, true);
        gemm(stream, dy, qw, nullptr, dqkv, nBS, 3 * D_, D_, D_, D_, 3 * D_,
             0,0,0,0,0,0, 1, 1, 1.f, true, false, false);

        // attention scores: s = q k^T /8 ; ds = (dq k^T + q dk^T)/8   (batched over n,h)
        const long long sQn = (long long)S_ * 3 * D_;   // per-n stride in qkv
        const long long sAn = (long long)H_ * S_ * S_;  // per-n stride in attn
        const long long sAh = (long long)S_ * S_;
        gemm(stream, qkv,        qkv + D_,  nullptr, attn,  S_, S_, DH_, 3*D_, 3*D_, S_,
             sQn, 64, sQn, 64, sAn, sAh, B_, H_, 0.125f, true, false, false);
        gemm(stream, dqkv,       qkv + D_,  nullptr, dattn, S_, S_, DH_, 3*D_, 3*D_, S_,
             sQn, 64, sQn, 64, sAn, sAh, B_, H_, 0.125f, true, false, false);
        gemm(stream, qkv,        dqkv + D_, nullptr, dattn, S_, S_, DH_, 3*D_, 3*D_, S_,
             sQn, 64, sQn, 64, sAn, sAh, B_, H_, 0.125f, true, true,  false);

        // softmax JVP (rows = B*H*S)
        softmax_jvp_kernel<<<B_ * H_ * S_, 256, 0, stream>>>(attn, dattn);

        // o = a v ; do = da v + a dv  -> assembled straight into y/dy as [n,s,D]
        gemm(stream, attn,  qkv  + 2*D_, nullptr, y,  S_, DH_, S_, S_, 3*D_, D_,
             sAn, sAh, sQn, 64, SD, 64, B_, H_, 1.f, false, false, false);
        gemm(stream, dattn, qkv  + 2*D_, nullptr, dy, S_, DH_, S_, S_, 3*D_, D_,
             sAn, sAh, sQn, 64, SD, 64, B_, H_, 1.f, false, false, false);
        gemm(stream, attn,  dqkv + 2*D_, nullptr, dy, S_, DH_, S_, S_, 3*D_, D_,
             sAn, sAh, sQn, 64, SD, 64, B_, H_, 1.f, false, true,  false);

        // projection + residual (accumulate into z/dz)
        gemm(stream, y,  ow, ob,      z,  nBS, D_, D_, D_, D_, D_,
             0,0,0,0,0,0, 1, 1, 1.f, true, true, true);
        gemm(stream, dy, ow, nullptr, dz, nBS, D_, D_, D_, D_, D_,
             0,0,0,0,0,0, 1, 1, 1.f, true, true, false);

        // LN2
        ln_jvp_kernel<<<nBS, 256, 0, stream>>>(z, dz, l2g, l2b, y, dy);
        // MLP
        gemm(stream, y,  f1w, f1b,     hbuf,  nBS, MD_, D_, D_, D_, MD_,
             0,0,0,0,0,0, 1, 1, 1.f, true, false, true);
        gemm(stream, dy, f1w, nullptr, dhbuf, nBS, MD_, D_, D_, D_, MD_,
             0,0,0,0,0,0, 1, 1, 1.f, true, false, false);
        gelu_jvp_kernel<<<4096, 256, 0, stream>>>(hbuf, dhbuf, nBS * MD_);
        gemm(stream, hbuf,  f2w, f2b,     z,  nBS, D_, MD_, MD_, MD_, D_,
             0,0,0,0,0,0, 1, 1, 1.f, true, true, true);
        gemm(stream, dhbuf, f2w, nullptr, dz, nBS, D_, MD_, MD_, MD_, D_,
             0,0,0,0,0,0, 1, 1, 1.f, true, true, false);
    }

    // ---- final LN + head (row n of A is token 0 of image n via lda = S*D) ----
    ln_jvp_kernel<<<nBS, 256, 0, stream>>>(z, dz, lnf_g, lnf_b, y, dy);
    gemm(stream, y,  head_w, head_b,  out,            B_, NC_, D_, (int)SD, D_, NC_,
         0,0,0,0,0,0, 1, 1, 1.f, true, false, true);
    gemm(stream, dy, head_w, nullptr, out + B_ * NC_, B_, NC_, D_, (int)SD, D_, NC_,
         0,0,0,0,0,0, 1, 1, 1.f, true, false, false);
}

// Round 2
// 15729.097 us; speedup vs baseline: 4.6088x; 4.6088x over previous
//
// ViT-Base/16 forward + JVP — Round 1: dense GEMMs on bf16 MFMA (16x16x32),
// m97 structure (128x128 tile, global_load_lds w=16, XOR chunk swizzle).
// Attention GEMMs + softmax/LN stay fp32.
#include <hip/hip_runtime.h>
#include <math.h>

static constexpr int B_   = 32;
static constexpr int S_   = 197;
static constexpr int D_   = 768;
static constexpr int H_   = 12;
static constexpr int DH_  = 64;
static constexpr int L_   = 12;
static constexpr int MD_  = 3072;
static constexpr int NC_  = 1000;
static constexpr int GP_  = 196;

typedef __attribute__((ext_vector_type(8))) short bf16x8v;
typedef __attribute__((ext_vector_type(4))) float f32x4v;

__device__ __forceinline__ unsigned short f2bf(float x) {
    union { float f; unsigned u; } v; v.f = x;
    unsigned r = v.u + 0x7fffu + ((v.u >> 16) & 1u);   // RNE
    return (unsigned short)(r >> 16);
}

#define GLOAD_LDS16(gptr, lptr) \
    __builtin_amdgcn_global_load_lds((const __attribute__((address_space(1))) void*)(gptr), \
        (__attribute__((address_space(3))) void*)(lptr), 16, 0, 0)

// ---------------- bf16 MFMA GEMM: C[m,n] (+)= sum_k A[m][k]*B[n][k] (+bias[n]) -------
// A: bf16 [>=M][K] (rows padded to x128 so staging never OOB), B: bf16 [N][K],
// C: fp32 [M][ldc]. N%128==0, K%32==0. 256 thr = 4 waves (2x2), wave tile 64x64.
template<bool ACC, bool BIAS>
__global__ __launch_bounds__(256) void mfma_gemm_kernel(
    const short* __restrict__ A, const short* __restrict__ Bm,
    const float* __restrict__ bias, float* __restrict__ C,
    int M, int N, int K, int ldc)
{
    __shared__ __align__(16) short ldsA[128 * 32];
    __shared__ __align__(16) short ldsB[128 * 32];
    const int tid  = threadIdx.x;
    const int lane = tid & 63;
    const int w    = tid >> 6;
    const int m0 = blockIdx.y * 128, n0 = blockIdx.x * 128;
    const int wr = w >> 1, wc = w & 1;

    f32x4v acc[4][4] = {};

    const int r_in = lane >> 2;   // row within 16-row staging chunk
    const int cdst = lane & 3;    // dest 16B chunk within 64B row

    for (int k0 = 0; k0 < K; k0 += 32) {
        // stage A/B tile: 8 x 16-row chunks; wave w does chunks {w, w+4}
        #pragma unroll
        for (int i = 0; i < 2; ++i) {
            const int c0  = w + i * 4;
            const int row = c0 * 16 + r_in;
            const int csrc = cdst ^ ((row >> 1) & 3);     // involutive chunk swizzle
            GLOAD_LDS16(A  + (size_t)(m0 + row) * K + k0 + csrc * 8, &ldsA[c0 * 16 * 32]);
            GLOAD_LDS16(Bm + (size_t)(n0 + row) * K + k0 + csrc * 8, &ldsB[c0 * 16 * 32]);
        }
        __syncthreads();
        bf16x8v af[4], bfr[4];
        #pragma unroll
        for (int m = 0; m < 4; ++m) {
            const int row = wr * 64 + m * 16 + (lane & 15);
            const int c = (lane >> 4) ^ ((row >> 1) & 3);
            af[m] = *(const bf16x8v*)&ldsA[row * 32 + c * 8];
        }
        #pragma unroll
        for (int n = 0; n < 4; ++n) {
            const int row = wc * 64 + n * 16 + (lane & 15);
            const int c = (lane >> 4) ^ ((row >> 1) & 3);
            bfr[n] = *(const bf16x8v*)&ldsB[row * 32 + c * 8];
        }
        #pragma unroll
        for (int m = 0; m < 4; ++m)
            #pragma unroll
            for (int n = 0; n < 4; ++n)
                acc[m][n] = __builtin_amdgcn_mfma_f32_16x16x32_bf16(af[m], bfr[n], acc[m][n], 0, 0, 0);
        __syncthreads();
    }
    // epilogue: C/D map col=lane&15, row=(lane>>4)*4+r
    const int col_base = n0 + wc * 64 + (lane & 15);
    const int row_base = m0 + wr * 64 + (lane >> 4) * 4;
    #pragma unroll
    for (int n = 0; n < 4; ++n) {
        const int col = col_base + n * 16;
        const float bv = BIAS ? bias[col] : 0.f;
        #pragma unroll
        for (int m = 0; m < 4; ++m) {
            const int row = row_base + m * 16;
            #pragma unroll
            for (int r = 0; r < 4; ++r) {
                if (row + r < M) {
                    const size_t off = (size_t)(row + r) * ldc + col;
                    const float v = acc[m][n][r] + bv;
                    if (ACC) C[off] += v; else C[off] = v;
                }
            }
        }
    }
}

// ---------------- fp32 reduction helpers ----------------
__device__ __forceinline__ float blk_sum(float v, float* smem) {
    #pragma unroll
    for (int off = 32; off > 0; off >>= 1) v += __shfl_down(v, off);
    __syncthreads();
    if ((threadIdx.x & 63) == 0) smem[threadIdx.x >> 6] = v;
    __syncthreads();
    return smem[0] + smem[1] + smem[2] + smem[3];
}
__device__ __forceinline__ float blk_max(float v, float* smem) {
    #pragma unroll
    for (int off = 32; off > 0; off >>= 1) v = fmaxf(v, __shfl_down(v, off));
    __syncthreads();
    if ((threadIdx.x & 63) == 0) smem[threadIdx.x >> 6] = v;
    __syncthreads();
    return fmaxf(fmaxf(smem[0], smem[1]), fmaxf(smem[2], smem[3]));
}

// ---------------- fp32 batched GEMM (attention + head only) ----------------
template<bool TRANSB, bool ACC, bool BIAS>
__global__ __launch_bounds__(256) void gemm_kernel(
    const float* __restrict__ A, const float* __restrict__ Bm,
    const float* __restrict__ bias, float* __restrict__ C,
    int M, int N, int K, int lda, int ldb, int ldc,
    long long sA1, long long sA2, long long sB1, long long sB2,
    long long sC1, long long sC2, int batch2, float alpha)
{
    const int bz = blockIdx.z;
    const int b1 = bz / batch2, b2 = bz - b1 * batch2;
    A  += b1 * sA1 + b2 * sA2;
    Bm += b1 * sB1 + b2 * sB2;
    C  += b1 * sC1 + b2 * sC2;

    const int tile_m = blockIdx.y * 64, tile_n = blockIdx.x * 64;
    __shared__ float As[16][64];
    __shared__ float Bs[16][64];
    const int tid = threadIdx.x;
    const int tx = tid & 15, ty = tid >> 4;
    float acc[4][4] = {};

    for (int k0 = 0; k0 < K; k0 += 16) {
        {
            const int row = tid >> 2;
            const int kc  = (tid & 3) * 4;
            const int gm  = tile_m + row;
            #pragma unroll
            for (int i = 0; i < 4; ++i) {
                const int gk = k0 + kc + i;
                float v = 0.f;
                if (gm < M && gk < K) v = A[(long long)gm * lda + gk];
                As[kc + i][row] = v;
            }
        }
        if (TRANSB) {
            const int row = tid >> 2;
            const int kc  = (tid & 3) * 4;
            const int gn  = tile_n + row;
            #pragma unroll
            for (int i = 0; i < 4; ++i) {
                const int gk = k0 + kc + i;
                float v = 0.f;
                if (gn < N && gk < K) v = Bm[(long long)gn * ldb + gk];
                Bs[kc + i][row] = v;
            }
        } else {
            const int kk = tid >> 4;
            const int nc = (tid & 15) * 4;
            const int gk = k0 + kk;
            #pragma unroll
            for (int i = 0; i < 4; ++i) {
                const int gn = tile_n + nc + i;
                float v = 0.f;
                if (gk < K && gn < N) v = Bm[(long long)gk * ldb + gn];
                Bs[kk][nc + i] = v;
            }
        }
        __syncthreads();
        #pragma unroll
        for (int kk = 0; kk < 16; ++kk) {
            float a[4], b[4];
            #pragma unroll
            for (int i = 0; i < 4; ++i) a[i] = As[kk][ty * 4 + i];
            #pragma unroll
            for (int j = 0; j < 4; ++j) b[j] = Bs[kk][tx * 4 + j];
            #pragma unroll
            for (int i = 0; i < 4; ++i)
                #pragma unroll
                for (int j = 0; j < 4; ++j)
                    acc[i][j] += a[i] * b[j];
        }
        __syncthreads();
    }
    #pragma unroll
    for (int i = 0; i < 4; ++i) {
        const int gm = tile_m + ty * 4 + i;
        if (gm >= M) continue;
        #pragma unroll
        for (int j = 0; j < 4; ++j) {
            const int gn = tile_n + tx * 4 + j;
            if (gn >= N) continue;
            float v = acc[i][j] * alpha;
            if (BIAS) v += bias[gn];
            const long long off = (long long)gm * ldc + gn;
            if (ACC) C[off] += v; else C[off] = v;
        }
    }
}

// ---------------- LayerNorm JVP (emits fp32 + bf16 copies) ----------------
__global__ __launch_bounds__(256) void ln_jvp_kernel(
    const float* __restrict__ z, const float* __restrict__ dz,
    const float* __restrict__ g, const float* __restrict__ b,
    float* __restrict__ y, float* __restrict__ dy,
    short* __restrict__ ybf, short* __restrict__ dybf)
{
    const long long row = blockIdx.x;
    const float* xr  = z  + row * D_;
    const float* dxr = dz + row * D_;
    __shared__ float smem[4];
    const int t = threadIdx.x;
    float x[3], dx[3];
    #pragma unroll
    for (int i = 0; i < 3; ++i) { x[i] = xr[t + 256 * i]; dx[i] = dxr[t + 256 * i]; }
    float sx = x[0] + x[1] + x[2];
    float sdx = dx[0] + dx[1] + dx[2];
    sx  = blk_sum(sx, smem);
    sdx = blk_sum(sdx, smem);
    const float mu = sx / D_, dmu = sdx / D_;
    float sv = 0.f, sc = 0.f;
    #pragma unroll
    for (int i = 0; i < 3; ++i) {
        const float xc = x[i] - mu;
        sv += xc * xc;
        sc += xc * (dx[i] - dmu);
    }
    sv = blk_sum(sv, smem);
    sc = blk_sum(sc, smem);
    const float rstd = rsqrtf(sv / D_ + 1e-6f);
    const float k2   = (sc / D_) * rstd * rstd;
    #pragma unroll
    for (int i = 0; i < 3; ++i) {
        const int c = t + 256 * i;
        const float yh  = (x[i] - mu) * rstd;
        const float dyh = (dx[i] - dmu) * rstd - yh * k2;
        const float yv  = yh * g[c] + b[c];
        const float dyv = dyh * g[c];
        y[row * D_ + c]  = yv;
        dy[row * D_ + c] = dyv;
        ybf[row * D_ + c]  = (short)f2bf(yv);
        dybf[row * D_ + c] = (short)f2bf(dyv);
    }
}

// ---------------- softmax JVP (in place, fp32) ----------------
__global__ __launch_bounds__(256) void softmax_jvp_kernel(
    float* __restrict__ a, float* __restrict__ da)
{
    const long long row = blockIdx.x;
    float* sr  = a  + row * S_;
    float* dsr = da + row * S_;
    __shared__ float smem[4];
    const int t = threadIdx.x;
    float x = -3.4e38f, dx = 0.f;
    if (t < S_) { x = sr[t]; dx = dsr[t]; }
    const float m = blk_max(x, smem);
    const float e = (t < S_) ? expf(x - m) : 0.f;
    const float den = blk_sum(e, smem);
    const float av = e / den;
    const float tsum = blk_sum(av * dx, smem);
    if (t < S_) { sr[t] = av; dsr[t] = av * (dx - tsum); }
}

// ---------------- exact GELU JVP: fp32 in, bf16 out ----------------
__global__ __launch_bounds__(256) void gelu_jvp_kernel(
    const float* __restrict__ h, const float* __restrict__ dh,
    short* __restrict__ ho, short* __restrict__ dho, int n4)
{
    for (int i = blockIdx.x * blockDim.x + threadIdx.x; i < n4;
         i += gridDim.x * blockDim.x) {
        const float4 u4 = ((const float4*)h)[i];
        const float4 du4 = ((const float4*)dh)[i];
        short o[4], doo[4];
        const float us[4] = {u4.x, u4.y, u4.z, u4.w};
        const float dus[4] = {du4.x, du4.y, du4.z, du4.w};
        #pragma unroll
        for (int j = 0; j < 4; ++j) {
            const float u = us[j], du = dus[j];
            const float cdf = 0.5f * (1.0f + erff(u * 0.70710678118654752f));
            const float pdf = 0.3989422804014327f * expf(-0.5f * u * u);
            o[j]  = (short)f2bf(u * cdf);
            doo[j] = (short)f2bf(du * (cdf + u * pdf));
        }
        *(short4*)&ho[i * 4]  = *(short4*)o;
        *(short4*)&dho[i * 4] = *(short4*)doo;
    }
}

// ---------------- cast fp32 -> bf16, vectorized x4 ----------------
__global__ __launch_bounds__(256) void cast_bf16_kernel(
    const float* __restrict__ in, short* __restrict__ out, int n4)
{
    for (int i = blockIdx.x * blockDim.x + threadIdx.x; i < n4;
         i += gridDim.x * blockDim.x) {
        const float4 v = ((const float4*)in)[i];
        short o[4];
        o[0] = (short)f2bf(v.x); o[1] = (short)f2bf(v.y);
        o[2] = (short)f2bf(v.z); o[3] = (short)f2bf(v.w);
        *(short4*)&out[i * 4] = *(short4*)o;
    }
}

// ---------------- im2col -> bf16: x[B,3,224,224] -> xp[B*196][768] ----------------
__global__ __launch_bounds__(256) void im2col_kernel(
    const float* __restrict__ x, short* __restrict__ xp, int total)
{
    for (int i = blockIdx.x * blockDim.x + threadIdx.x; i < total;
         i += gridDim.x * blockDim.x) {
        const int k  = i % 768;
        const int m  = i / 768;
        const int gh = m % GP_;
        const int n  = m / GP_;
        const int q  = k & 15;
        const int p  = (k >> 4) & 15;
        const int c  = k >> 8;
        const int hc = gh % 14, gr = gh / 14;
        const int ir = gr * 16 + p, ic = hc * 16 + q;
        xp[i] = (short)f2bf(x[(((long long)n * 3 + c) * 224 + ir) * 224 + ic]);
    }
}

// ---------------- assemble: z = [cls|tok] + pos ; dz = [0|dtok] ----------------
__global__ __launch_bounds__(256) void assemble_kernel(
    const float* __restrict__ tok, const float* __restrict__ dtok,
    float* __restrict__ z, float* __restrict__ dz,
    const float* __restrict__ cls, const float* __restrict__ pos, int total)
{
    for (int i = blockIdx.x * blockDim.x + threadIdx.x; i < total;
         i += gridDim.x * blockDim.x) {
        const int d = i % D_;
        const int s = (i / D_) % S_;
        const int n = i / (D_ * S_);
        if (s == 0) {
            z[i]  = cls[d] + pos[d];
            dz[i] = 0.f;
        } else {
            const long long ti = ((long long)n * GP_ + s - 1) * D_ + d;
            z[i]  = tok[ti]  + pos[s * D_ + d];
            dz[i] = dtok[ti];
        }
    }
}

// ---------------- host dispatch ----------------
static inline void gemm(hipStream_t st, const float* A, const float* Bm, const float* bias,
                        float* C, int M, int N, int K, int lda, int ldb, int ldc,
                        long long sA1, long long sA2, long long sB1, long long sB2,
                        long long sC1, long long sC2, int batch1, int batch2,
                        float alpha, bool transB, bool acc, bool hasbias)
{
    dim3 grid((N + 63) / 64, (M + 63) / 64, batch1 * batch2);
    dim3 blk(256);
#define GK(TB, AC, BI) gemm_kernel<TB, AC, BI><<<grid, blk, 0, st>>>( \
        A, Bm, bias, C, M, N, K, lda, ldb, ldc, sA1, sA2, sB1, sB2, sC1, sC2, batch2, alpha)
    if (transB) {
        if (acc)  { if (hasbias) GK(true,  true,  true);  else GK(true,  true,  false); }
        else      { if (hasbias) GK(true,  false, true);  else GK(true,  false, false); }
    } else {
        if (acc)  { if (hasbias) GK(false, true,  true);  else GK(false, true,  false); }
        else      { if (hasbias) GK(false, false, true);  else GK(false, false, false); }
    }
#undef GK
}

static inline void mgemm(hipStream_t st, const short* A, const short* Bm, const float* bias,
                         float* C, int M, int N, int K, int ldc, bool acc, bool hasbias)
{
    dim3 grid(N / 128, (M + 127) / 128);
    dim3 blk(256);
#define MK(AC, BI) mfma_gemm_kernel<AC, BI><<<grid, blk, 0, st>>>(A, Bm, bias, C, M, N, K, ldc)
    if (acc) { if (hasbias) MK(true, true);  else MK(true, false); }
    else     { if (hasbias) MK(false, true); else MK(false, false); }
#undef MK
}

static inline void cast_bf(hipStream_t st, const float* in, short* out, long long n) {
    const int n4 = (int)(n / 4);
    cast_bf16_kernel<<<(n4 + 255) / 256 < 4096 ? (n4 + 255) / 256 : 4096, 256, 0, st>>>(in, out, n4);
}

extern "C" void kernel_launch(void* const* d_in, const int* in_sizes, int n_in,
                              void* d_out, int out_size, void* d_ws, size_t ws_size,
                              hipStream_t stream)
{
    const float* x       = (const float*)d_in[0];
    const float* tangent = (const float*)d_in[1];
    const float* conv_w  = (const float*)d_in[2];
    const float* conv_b  = (const float*)d_in[3];
    const float* cls     = (const float*)d_in[4];
    const float* pos     = (const float*)d_in[5];
    const float* ln1_g   = (const float*)d_in[6];
    const float* ln1_b   = (const float*)d_in[7];
    const float* qkv_w   = (const float*)d_in[8];
    const float* qkv_b   = (const float*)d_in[9];
    const float* out_w   = (const float*)d_in[10];
    const float* out_b   = (const float*)d_in[11];
    const float* ln2_g   = (const float*)d_in[12];
    const float* ln2_b   = (const float*)d_in[13];
    const float* fc1_w   = (const float*)d_in[14];
    const float* fc1_b   = (const float*)d_in[15];
    const float* fc2_w   = (const float*)d_in[16];
    const float* fc2_b   = (const float*)d_in[17];
    const float* lnf_g   = (const float*)d_in[18];
    const float* lnf_b   = (const float*)d_in[19];
    const float* head_w  = (const float*)d_in[20];
    const float* head_b  = (const float*)d_in[21];
    float* out = (float*)d_out;

    const long long ZSZ = (long long)B_ * S_ * D_;          // 4,841,472
    const long long QSZ = (long long)B_ * S_ * 3 * D_;      // 14,524,416
    const long long ASZ = (long long)B_ * H_ * S_ * S_;     // 14,902,656
    const long long RSZ = QSZ + ASZ;
    const int nBS = B_ * S_;                 // 6304
    const int MPAD = 6400;                   // 50*128, A-operand row padding
    const long long SD = (long long)S_ * D_;

    float* ws = (float*)d_ws;
    float* z   = ws;
    float* dz  = z  + ZSZ;
    float* y   = dz + ZSZ;   // also tok
    float* dy  = y  + ZSZ;   // also dtok
    float* R1  = dy + ZSZ;   // qkv | hbuf
    float* R2  = R1 + RSZ;   // dqkv | dhbuf
    float* qkv   = R1;  float* attn  = R1 + QSZ;
    float* dqkv  = R2;  float* dattn = R2 + QSZ;
    float* hbuf  = R1;  float* dhbuf = R2;

    short* bfb   = (short*)(R2 + RSZ);
    short* ybf   = bfb;                              // [6400][768]
    short* dybf  = ybf  + (long long)MPAD * D_;
    short* hbf   = dybf + (long long)MPAD * D_;      // [6400][3072]
    short* dhbf  = hbf  + (long long)MPAD * MD_;
    short* xpbf  = hbf;                              // alias (patch stage only)
    short* dxpbf = dhbf;
    short* wslab = dhbf + (long long)MPAD * MD_;     // per-layer weights: 7,077,888
    short* wq    = wslab;                 // 2304*768
    short* wo    = wq + 2304 * 768;       // 768*768
    short* w1    = wo + 768 * 768;        // 3072*768
    short* w2    = w1 + 3072 * 768;       // 768*3072
    short* cwbf  = w2 + 768 * 3072;       // conv_w 768*768

    // ---- patch embedding ----
    {
        const int total = B_ * GP_ * D_;
        im2col_kernel<<<8192, 256, 0, stream>>>(x, xpbf, total);
        im2col_kernel<<<8192, 256, 0, stream>>>(tangent, dxpbf, total);
        cast_bf(stream, conv_w, cwbf, 768 * 768);
        mgemm(stream, xpbf,  cwbf, conv_b, y,  B_ * GP_, D_, D_, D_, false, true);
        mgemm(stream, dxpbf, cwbf, nullptr, dy, B_ * GP_, D_, D_, D_, false, false);
        const int tz = (int)(B_ * SD);
        assemble_kernel<<<8192, 256, 0, stream>>>(y, dy, z, dz, cls, pos, tz);
    }

    for (int l = 0; l < L_; ++l) {
        const float* l1g = ln1_g + (long long)l * D_;
        const float* l1b = ln1_b + (long long)l * D_;
        const float* qb  = qkv_b + (long long)l * 3 * D_;
        const float* ob  = out_b + (long long)l * D_;
        const float* l2g = ln2_g + (long long)l * D_;
        const float* l2b = ln2_b + (long long)l * D_;
        const float* f1b = fc1_b + (long long)l * MD_;
        const float* f2b = fc2_b + (long long)l * D_;

        // per-layer weight casts into reused slab
        cast_bf(stream, qkv_w + (long long)l * 3 * D_ * D_, wq, (long long)3 * D_ * D_);
        cast_bf(stream, out_w + (long long)l * D_ * D_,     wo, (long long)D_ * D_);
        cast_bf(stream, fc1_w + (long long)l * MD_ * D_,    w1, (long long)MD_ * D_);
        cast_bf(stream, fc2_w + (long long)l * D_ * MD_,    w2, (long long)D_ * MD_);

        // LN1 -> y/dy (fp32) + ybf/dybf (bf16)
        ln_jvp_kernel<<<nBS, 256, 0, stream>>>(z, dz, l1g, l1b, y, dy, ybf, dybf);
        // QKV (MFMA)
        mgemm(stream, ybf,  wq, qb,      qkv,  nBS, 3 * D_, D_, 3 * D_, false, true);
        mgemm(stream, dybf, wq, nullptr, dqkv, nBS, 3 * D_, D_, 3 * D_, false, false);

        // attention scores + JVP (fp32 batched)
        const long long sQn = (long long)S_ * 3 * D_;
        const long long sAn = (long long)H_ * S_ * S_;
        const long long sAh = (long long)S_ * S_;
        gemm(stream, qkv,  qkv + D_,  nullptr, attn,  S_, S_, DH_, 3*D_, 3*D_, S_,
             sQn, 64, sQn, 64, sAn, sAh, B_, H_, 0.125f, true, false, false);
        gemm(stream, dqkv, qkv + D_,  nullptr, dattn, S_, S_, DH_, 3*D_, 3*D_, S_,
             sQn, 64, sQn, 64, sAn, sAh, B_, H_, 0.125f, true, false, false);
        gemm(stream, qkv,  dqkv + D_, nullptr, dattn, S_, S_, DH_, 3*D_, 3*D_, S_,
             sQn, 64, sQn, 64, sAn, sAh, B_, H_, 0.125f, true, true,  false);

        softmax_jvp_kernel<<<B_ * H_ * S_, 256, 0, stream>>>(attn, dattn);

        // o = a v ; do = da v + a dv  -> y/dy fp32 [n,s,D]
        gemm(stream, attn,  qkv  + 2*D_, nullptr, y,  S_, DH_, S_, S_, 3*D_, D_,
             sAn, sAh, sQn, 64, SD, 64, B_, H_, 1.f, false, false, false);
        gemm(stream, dattn, qkv  + 2*D_, nullptr, dy, S_, DH_, S_, S_, 3*D_, D_,
             sAn, sAh, sQn, 64, SD, 64, B_, H_, 1.f, false, false, false);
        gemm(stream, attn,  dqkv + 2*D_, nullptr, dy, S_, DH_, S_, S_, 3*D_, D_,
             sAn, sAh, sQn, 64, SD, 64, B_, H_, 1.f, false, true,  false);

        // cast attention output, project + residual (MFMA, ACC)
        cast_bf(stream, y,  ybf,  ZSZ);
        cast_bf(stream, dy, dybf, ZSZ);
        mgemm(stream, ybf,  wo, ob,      z,  nBS, D_, D_, D_, true, true);
        mgemm(stream, dybf, wo, nullptr, dz, nBS, D_, D_, D_, true, false);

        // LN2 + MLP
        ln_jvp_kernel<<<nBS, 256, 0, stream>>>(z, dz, l2g, l2b, y, dy, ybf, dybf);
        mgemm(stream, ybf,  w1, f1b,     hbuf,  nBS, MD_, D_, MD_, false, true);
        mgemm(stream, dybf, w1, nullptr, dhbuf, nBS, MD_, D_, MD_, false, false);
        gelu_jvp_kernel<<<4096, 256, 0, stream>>>(hbuf, dhbuf, hbf, dhbf, nBS * MD_ / 4);
        mgemm(stream, hbf,  w2, f2b,     z,  nBS, D_, MD_, D_, true, true);
        mgemm(stream, dhbf, w2, nullptr, dz, nBS, D_, MD_, D_, true, false);
    }

    // final LN + head (fp32; head is tiny)
    ln_jvp_kernel<<<nBS, 256, 0, stream>>>(z, dz, lnf_g, lnf_b, y, dy, ybf, dybf);
    gemm(stream, y,  head_w, head_b,  out,            B_, NC_, D_, (int)SD, D_, NC_,
         0,0,0,0,0,0, 1, 1, 1.f, true, false, true);
    gemm(stream, dy, head_w, nullptr, out + B_ * NC_, B_, NC_, D_, (int)SD, D_, NC_,
         0,0,0,0,0,0, 1, 1, 1.f, true, false, false);
}

// Round 3
// 10008.038 us; speedup vs baseline: 7.2435x; 1.5716x over previous
//
// ViT-Base/16 fwd + JVP — Round 2: attention fully on bf16 MFMA.
// Fused S/dS kernel, softmax-JVP -> bf16 P/dP (K-padded), LDS V-transpose,
// fused PV/dPV kernel writing bf16 proj operands. Dense GEMMs as R1.
#include <hip/hip_runtime.h>
#include <math.h>

static constexpr int B_   = 32;
static constexpr int S_   = 197;
static constexpr int D_   = 768;
static constexpr int H_   = 12;
static constexpr int L_   = 12;
static constexpr int MD_  = 3072;
static constexpr int NC_  = 1000;
static constexpr int GP_  = 196;
static constexpr int KP_  = 224;   // padded attention-K (7*32)

typedef __attribute__((ext_vector_type(8))) short bf16x8v;
typedef __attribute__((ext_vector_type(4))) float f32x4v;

__device__ __forceinline__ unsigned short f2bf(float x) {
    union { float f; unsigned u; } v; v.f = x;
    unsigned r = v.u + 0x7fffu + ((v.u >> 16) & 1u);   // RNE
    return (unsigned short)(r >> 16);
}

#define GLOAD_LDS16(gptr, lptr) \
    __builtin_amdgcn_global_load_lds((const __attribute__((address_space(1))) void*)(gptr), \
        (__attribute__((address_space(3))) void*)(lptr), 16, 0, 0)

// ================= dense MFMA GEMM (128x128 tile) =================
// C[m,n] (+)= sum_k A[m][k]*B[n][k] (+bias[n]); A bf16 [rows>=gridM*128][K], B bf16 [N][K].
// OUTBF: C is bf16 (no ACC); else fp32.
template<bool ACC, bool BIAS, bool OUTBF>
__global__ __launch_bounds__(256) void mfma_gemm_kernel(
    const short* __restrict__ A, const short* __restrict__ Bm,
    const float* __restrict__ bias, void* __restrict__ Cv,
    int M, int N, int K, int ldc)
{
    __shared__ __align__(16) short ldsA[128 * 32];
    __shared__ __align__(16) short ldsB[128 * 32];
    const int tid  = threadIdx.x;
    const int lane = tid & 63;
    const int w    = tid >> 6;
    const int m0 = blockIdx.y * 128, n0 = blockIdx.x * 128;
    const int wr = w >> 1, wc = w & 1;
    f32x4v acc[4][4] = {};

    const int r_in = lane >> 2;
    const int cdst = lane & 3;

    for (int k0 = 0; k0 < K; k0 += 32) {
        #pragma unroll
        for (int i = 0; i < 2; ++i) {
            const int c0  = w + i * 4;
            const int row = c0 * 16 + r_in;
            const int csrc = cdst ^ ((row >> 1) & 3);
            GLOAD_LDS16(A  + (size_t)(m0 + row) * K + k0 + csrc * 8, &ldsA[c0 * 16 * 32]);
            GLOAD_LDS16(Bm + (size_t)(n0 + row) * K + k0 + csrc * 8, &ldsB[c0 * 16 * 32]);
        }
        __syncthreads();
        bf16x8v af[4], bfr[4];
        #pragma unroll
        for (int m = 0; m < 4; ++m) {
            const int row = wr * 64 + m * 16 + (lane & 15);
            const int c = (lane >> 4) ^ ((row >> 1) & 3);
            af[m] = *(const bf16x8v*)&ldsA[row * 32 + c * 8];
        }
        #pragma unroll
        for (int n = 0; n < 4; ++n) {
            const int row = wc * 64 + n * 16 + (lane & 15);
            const int c = (lane >> 4) ^ ((row >> 1) & 3);
            bfr[n] = *(const bf16x8v*)&ldsB[row * 32 + c * 8];
        }
        #pragma unroll
        for (int m = 0; m < 4; ++m)
            #pragma unroll
            for (int n = 0; n < 4; ++n)
                acc[m][n] = __builtin_amdgcn_mfma_f32_16x16x32_bf16(af[m], bfr[n], acc[m][n], 0, 0, 0);
        __syncthreads();
    }
    const int col_base = n0 + wc * 64 + (lane & 15);
    const int row_base = m0 + wr * 64 + (lane >> 4) * 4;
    #pragma unroll
    for (int n = 0; n < 4; ++n) {
        const int col = col_base + n * 16;
        const float bv = BIAS ? bias[col] : 0.f;
        #pragma unroll
        for (int m = 0; m < 4; ++m) {
            const int row = row_base + m * 16;
            #pragma unroll
            for (int r = 0; r < 4; ++r) {
                if (row + r < M) {
                    const size_t off = (size_t)(row + r) * ldc + col;
                    const float v = acc[m][n][r] + bv;
                    if (OUTBF) ((short*)Cv)[off] = (short)f2bf(v);
                    else if (ACC) ((float*)Cv)[off] += v;
                    else ((float*)Cv)[off] = v;
                }
            }
        }
    }
}

// ================= fused attention scores JVP =================
// per batch b=(n,h): S = (q·k^T)/8 ; dS = (dq·k^T + q·dk^T)/8. 64x64 tiles.
__global__ __launch_bounds__(256) void attn_scores_kernel(
    const short* __restrict__ qkvb, const short* __restrict__ dqkvb,
    float* __restrict__ S, float* __restrict__ dS)
{
    const int bz = blockIdx.z;
    const int n = bz / H_, h = bz - n * H_;
    const short* qb  = qkvb  + (size_t)n * S_ * 2304 + h * 64;
    const short* kb  = qb + 768;
    const short* dqb = dqkvb + (size_t)n * S_ * 2304 + h * 64;
    const short* dkb = dqb + 768;
    float* Sb  = S  + (size_t)bz * S_ * S_;
    float* dSb = dS + (size_t)bz * S_ * S_;

    __shared__ __align__(16) short lq[64*32], ldq[64*32], lk[64*32], ldk[64*32];
    const int tid = threadIdx.x, lane = tid & 63, w = tid >> 6;
    const int m0 = blockIdx.y * 64, n0 = blockIdx.x * 64;
    const int wr = w >> 1, wc = w & 1;
    f32x4v aS[2][2] = {}, aD[2][2] = {};

    const int r_in = lane >> 2;            // 0..15 within wave chunk
    const int cdst = lane & 3;
    const int row  = w * 16 + r_in;        // 0..63
    const int csrc = cdst ^ ((row >> 1) & 3);
    const size_t ar = (size_t)min(m0 + row, S_ - 1) * 2304;
    const size_t br = (size_t)min(n0 + row, S_ - 1) * 2304;

    #pragma unroll
    for (int k0 = 0; k0 < 64; k0 += 32) {
        GLOAD_LDS16(qb  + ar + k0 + csrc * 8, &lq [w * 16 * 32]);
        GLOAD_LDS16(dqb + ar + k0 + csrc * 8, &ldq[w * 16 * 32]);
        GLOAD_LDS16(kb  + br + k0 + csrc * 8, &lk [w * 16 * 32]);
        GLOAD_LDS16(dkb + br + k0 + csrc * 8, &ldk[w * 16 * 32]);
        __syncthreads();
        bf16x8v qf[2], dqf[2], kf[2], dkf[2];
        #pragma unroll
        for (int m = 0; m < 2; ++m) {
            const int rr = wr * 32 + m * 16 + (lane & 15);
            const int c = (lane >> 4) ^ ((rr >> 1) & 3);
            qf[m]  = *(const bf16x8v*)&lq [rr * 32 + c * 8];
            dqf[m] = *(const bf16x8v*)&ldq[rr * 32 + c * 8];
        }
        #pragma unroll
        for (int nn = 0; nn < 2; ++nn) {
            const int rr = wc * 32 + nn * 16 + (lane & 15);
            const int c = (lane >> 4) ^ ((rr >> 1) & 3);
            kf[nn]  = *(const bf16x8v*)&lk [rr * 32 + c * 8];
            dkf[nn] = *(const bf16x8v*)&ldk[rr * 32 + c * 8];
        }
        #pragma unroll
        for (int m = 0; m < 2; ++m)
            #pragma unroll
            for (int nn = 0; nn < 2; ++nn) {
                aS[m][nn] = __builtin_amdgcn_mfma_f32_16x16x32_bf16(qf[m],  kf[nn],  aS[m][nn], 0,0,0);
                aD[m][nn] = __builtin_amdgcn_mfma_f32_16x16x32_bf16(dqf[m], kf[nn],  aD[m][nn], 0,0,0);
                aD[m][nn] = __builtin_amdgcn_mfma_f32_16x16x32_bf16(qf[m],  dkf[nn], aD[m][nn], 0,0,0);
            }
        __syncthreads();
    }
    #pragma unroll
    for (int m = 0; m < 2; ++m) {
        const int rbase = m0 + wr * 32 + m * 16 + (lane >> 4) * 4;
        #pragma unroll
        for (int nn = 0; nn < 2; ++nn) {
            const int col = n0 + wc * 32 + nn * 16 + (lane & 15);
            if (col >= S_) continue;
            #pragma unroll
            for (int r = 0; r < 4; ++r) {
                const int rw = rbase + r;
                if (rw < S_) {
                    Sb [(size_t)rw * S_ + col] = aS[m][nn][r] * 0.125f;
                    dSb[(size_t)rw * S_ + col] = aD[m][nn][r] * 0.125f;
                }
            }
        }
    }
}

// ================= softmax JVP -> bf16 P/dP (padded to KP_) =================
__global__ __launch_bounds__(256) void softmax_pjvp_kernel(
    const float* __restrict__ S, const float* __restrict__ dS,
    short* __restrict__ P, short* __restrict__ dP)
{
    const size_t row = blockIdx.x;
    const float* sr  = S  + row * S_;
    const float* dsr = dS + row * S_;
    short* pr  = P  + row * KP_;
    short* dpr = dP + row * KP_;
    __shared__ float smem[4];
    const int t = threadIdx.x;
    float x = -3.4e38f, dx = 0.f;
    if (t < S_) { x = sr[t]; dx = dsr[t]; }
    // block max
    float v = x;
    #pragma unroll
    for (int off = 32; off > 0; off >>= 1) v = fmaxf(v, __shfl_down(v, off));
    __syncthreads();
    if ((t & 63) == 0) smem[t >> 6] = v;
    __syncthreads();
    const float m = fmaxf(fmaxf(smem[0], smem[1]), fmaxf(smem[2], smem[3]));
    const float e = (t < S_) ? expf(x - m) : 0.f;
    float s = e;
    #pragma unroll
    for (int off = 32; off > 0; off >>= 1) s += __shfl_down(s, off);
    __syncthreads();
    if ((t & 63) == 0) smem[t >> 6] = s;
    __syncthreads();
    const float den = smem[0] + smem[1] + smem[2] + smem[3];
    const float av = e / den;
    float ts = av * dx;
    #pragma unroll
    for (int off = 32; off > 0; off >>= 1) ts += __shfl_down(ts, off);
    __syncthreads();
    if ((t & 63) == 0) smem[t >> 6] = ts;
    __syncthreads();
    const float tsum = smem[0] + smem[1] + smem[2] + smem[3];
    if (t < KP_) {
        pr[t]  = (t < S_) ? (short)f2bf(av) : (short)0;
        dpr[t] = (t < S_) ? (short)f2bf(av * (dx - tsum)) : (short)0;
    }
}

// ================= V transpose: qkv v-section -> Vt[b][64][KP_] =================
__global__ __launch_bounds__(256) void vtrans_kernel(
    const short* __restrict__ qkvb, const short* __restrict__ dqkvb,
    short* __restrict__ Vt, short* __restrict__ dVt)
{
    const int blk = blockIdx.x;           // b*4 + kt
    const int b = blk >> 2, kt = blk & 3;
    const int n = b / H_, h = b - n * H_;
    const short* vb  = qkvb  + (size_t)n * S_ * 2304 + 1536 + h * 64;
    const short* dvb = dqkvb + (size_t)n * S_ * 2304 + 1536 + h * 64;
    __shared__ short t1[64][65], t2[64][65];
    const int tid = threadIdx.x;
    #pragma unroll
    for (int j = 0; j < 16; ++j) {
        const int e = tid + 256 * j;
        const int kk = e >> 6, dh = e & 63;
        const int gk = kt * 64 + kk;
        short v = 0, dv = 0;
        if (gk < S_) { v = vb[(size_t)gk * 2304 + dh]; dv = dvb[(size_t)gk * 2304 + dh]; }
        t1[dh][kk] = v; t2[dh][kk] = dv;
    }
    __syncthreads();
    #pragma unroll
    for (int j = 0; j < 16; ++j) {
        const int e = tid + 256 * j;
        const int dh = e >> 6, kk = e & 63;
        const int ok = kt * 64 + kk;
        if (ok < KP_) {
            Vt [(size_t)b * 64 * KP_ + (size_t)dh * KP_ + ok] = t1[dh][kk];
            dVt[(size_t)b * 64 * KP_ + (size_t)dh * KP_ + ok] = t2[dh][kk];
        }
    }
}

// ================= fused PV JVP: o = P·V, do = dP·V + P·dV -> bf16 =================
__global__ __launch_bounds__(256) void attn_pv_kernel(
    const short* __restrict__ P, const short* __restrict__ dP,
    const short* __restrict__ Vt, const short* __restrict__ dVt,
    short* __restrict__ obf, short* __restrict__ dobf)
{
    const int bz = blockIdx.z;
    const int n = bz / H_, h = bz - n * H_;
    const short* Pb  = P   + (size_t)bz * S_ * KP_;
    const short* dPb = dP  + (size_t)bz * S_ * KP_;
    const short* Vb  = Vt  + (size_t)bz * 64 * KP_;
    const short* dVb = dVt + (size_t)bz * 64 * KP_;
    short* ob  = obf  + (size_t)n * S_ * D_ + h * 64;
    short* dob = dobf + (size_t)n * S_ * D_ + h * 64;

    __shared__ __align__(16) short lp[64*32], ldp[64*32], lv[64*32], ldv[64*32];
    const int tid = threadIdx.x, lane = tid & 63, w = tid >> 6;
    const int m0 = blockIdx.y * 64;
    const int wr = w >> 1, wc = w & 1;
    f32x4v aO[2][2] = {}, aDO[2][2] = {};

    const int r_in = lane >> 2;
    const int cdst = lane & 3;
    const int row  = w * 16 + r_in;
    const int csrc = cdst ^ ((row >> 1) & 3);
    const size_t pr = (size_t)min(m0 + row, S_ - 1) * KP_;
    const size_t vr = (size_t)row * KP_;

    for (int k0 = 0; k0 < KP_; k0 += 32) {
        GLOAD_LDS16(Pb  + pr + k0 + csrc * 8, &lp [w * 16 * 32]);
        GLOAD_LDS16(dPb + pr + k0 + csrc * 8, &ldp[w * 16 * 32]);
        GLOAD_LDS16(Vb  + vr + k0 + csrc * 8, &lv [w * 16 * 32]);
        GLOAD_LDS16(dVb + vr + k0 + csrc * 8, &ldv[w * 16 * 32]);
        __syncthreads();
        bf16x8v pf[2], dpf[2], vf[2], dvf[2];
        #pragma unroll
        for (int m = 0; m < 2; ++m) {
            const int rr = wr * 32 + m * 16 + (lane & 15);
            const int c = (lane >> 4) ^ ((rr >> 1) & 3);
            pf[m]  = *(const bf16x8v*)&lp [rr * 32 + c * 8];
            dpf[m] = *(const bf16x8v*)&ldp[rr * 32 + c * 8];
        }
        #pragma unroll
        for (int nn = 0; nn < 2; ++nn) {
            const int rr = wc * 32 + nn * 16 + (lane & 15);
            const int c = (lane >> 4) ^ ((rr >> 1) & 3);
            vf[nn]  = *(const bf16x8v*)&lv [rr * 32 + c * 8];
            dvf[nn] = *(const bf16x8v*)&ldv[rr * 32 + c * 8];
        }
        #pragma unroll
        for (int m = 0; m < 2; ++m)
            #pragma unroll
            for (int nn = 0; nn < 2; ++nn) {
                aO [m][nn] = __builtin_amdgcn_mfma_f32_16x16x32_bf16(pf[m],  vf[nn],  aO [m][nn], 0,0,0);
                aDO[m][nn] = __builtin_amdgcn_mfma_f32_16x16x32_bf16(dpf[m], vf[nn],  aDO[m][nn], 0,0,0);
                aDO[m][nn] = __builtin_amdgcn_mfma_f32_16x16x32_bf16(pf[m],  dvf[nn], aDO[m][nn], 0,0,0);
            }
        __syncthreads();
    }
    #pragma unroll
    for (int m = 0; m < 2; ++m) {
        const int rbase = m0 + wr * 32 + m * 16 + (lane >> 4) * 4;
        #pragma unroll
        for (int nn = 0; nn < 2; ++nn) {
            const int col = wc * 32 + nn * 16 + (lane & 15);   // < 64
            #pragma unroll
            for (int r = 0; r < 4; ++r) {
                const int rw = rbase + r;
                if (rw < S_) {
                    ob [(size_t)rw * D_ + col] = (short)f2bf(aO [m][nn][r]);
                    dob[(size_t)rw * D_ + col] = (short)f2bf(aDO[m][nn][r]);
                }
            }
        }
    }
}

// ================= fp32 GEMM (head only) =================
template<bool TRANSB, bool ACC, bool BIAS>
__global__ __launch_bounds__(256) void gemm_kernel(
    const float* __restrict__ A, const float* __restrict__ Bm,
    const float* __restrict__ bias, float* __restrict__ C,
    int M, int N, int K, int lda, int ldb, int ldc, float alpha)
{
    const int tile_m = blockIdx.y * 64, tile_n = blockIdx.x * 64;
    __shared__ float As[16][64];
    __shared__ float Bs[16][64];
    const int tid = threadIdx.x;
    const int tx = tid & 15, ty = tid >> 4;
    float acc[4][4] = {};
    for (int k0 = 0; k0 < K; k0 += 16) {
        {
            const int row = tid >> 2, kc = (tid & 3) * 4, gm = tile_m + row;
            #pragma unroll
            for (int i = 0; i < 4; ++i) {
                const int gk = k0 + kc + i;
                float v = 0.f;
                if (gm < M && gk < K) v = A[(long long)gm * lda + gk];
                As[kc + i][row] = v;
            }
        }
        {
            const int row = tid >> 2, kc = (tid & 3) * 4, gn = tile_n + row;
            #pragma unroll
            for (int i = 0; i < 4; ++i) {
                const int gk = k0 + kc + i;
                float v = 0.f;
                if (gn < N && gk < K) v = Bm[(long long)gn * ldb + gk];
                Bs[kc + i][row] = v;
            }
        }
        __syncthreads();
        #pragma unroll
        for (int kk = 0; kk < 16; ++kk) {
            float a[4], b[4];
            #pragma unroll
            for (int i = 0; i < 4; ++i) a[i] = As[kk][ty * 4 + i];
            #pragma unroll
            for (int j = 0; j < 4; ++j) b[j] = Bs[kk][tx * 4 + j];
            #pragma unroll
            for (int i = 0; i < 4; ++i)
                #pragma unroll
                for (int j = 0; j < 4; ++j)
                    acc[i][j] += a[i] * b[j];
        }
        __syncthreads();
    }
    #pragma unroll
    for (int i = 0; i < 4; ++i) {
        const int gm = tile_m + ty * 4 + i;
        if (gm >= M) continue;
        #pragma unroll
        for (int j = 0; j < 4; ++j) {
            const int gn = tile_n + tx * 4 + j;
            if (gn >= N) continue;
            float v = acc[i][j] * alpha;
            if (BIAS) v += bias[gn];
            const long long off = (long long)gm * ldc + gn;
            if (ACC) C[off] += v; else C[off] = v;
        }
    }
}

// ================= LayerNorm JVP =================
__device__ __forceinline__ float blk_sum4(float v, float* smem) {
    #pragma unroll
    for (int off = 32; off > 0; off >>= 1) v += __shfl_down(v, off);
    __syncthreads();
    if ((threadIdx.x & 63) == 0) smem[threadIdx.x >> 6] = v;
    __syncthreads();
    return smem[0] + smem[1] + smem[2] + smem[3];
}

template<bool WF32>
__global__ __launch_bounds__(256) void ln_jvp_kernel(
    const float* __restrict__ z, const float* __restrict__ dz,
    const float* __restrict__ g, const float* __restrict__ b,
    float* __restrict__ y, float* __restrict__ dy,
    short* __restrict__ ybf, short* __restrict__ dybf)
{
    const long long row = blockIdx.x;
    const float* xr  = z  + row * D_;
    const float* dxr = dz + row * D_;
    __shared__ float smem[4];
    const int t = threadIdx.x;
    float x[3], dx[3];
    #pragma unroll
    for (int i = 0; i < 3; ++i) { x[i] = xr[t + 256 * i]; dx[i] = dxr[t + 256 * i]; }
    float sx  = blk_sum4(x[0] + x[1] + x[2], smem);
    float sdx = blk_sum4(dx[0] + dx[1] + dx[2], smem);
    const float mu = sx / D_, dmu = sdx / D_;
    float sv = 0.f, sc = 0.f;
    #pragma unroll
    for (int i = 0; i < 3; ++i) {
        const float xc = x[i] - mu;
        sv += xc * xc;
        sc += xc * (dx[i] - dmu);
    }
    sv = blk_sum4(sv, smem);
    sc = blk_sum4(sc, smem);
    const float rstd = rsqrtf(sv / D_ + 1e-6f);
    const float k2   = (sc / D_) * rstd * rstd;
    #pragma unroll
    for (int i = 0; i < 3; ++i) {
        const int c = t + 256 * i;
        const float yh  = (x[i] - mu) * rstd;
        const float dyh = (dx[i] - dmu) * rstd - yh * k2;
        const float yv  = yh * g[c] + b[c];
        const float dyv = dyh * g[c];
        if (WF32) { y[row * D_ + c] = yv; dy[row * D_ + c] = dyv; }
        ybf[row * D_ + c]  = (short)f2bf(yv);
        dybf[row * D_ + c] = (short)f2bf(dyv);
    }
}

// ================= GELU JVP: fp32 in, bf16 out =================
__global__ __launch_bounds__(256) void gelu_jvp_kernel(
    const float* __restrict__ h, const float* __restrict__ dh,
    short* __restrict__ ho, short* __restrict__ dho, int n4)
{
    for (int i = blockIdx.x * blockDim.x + threadIdx.x; i < n4;
         i += gridDim.x * blockDim.x) {
        const float4 u4 = ((const float4*)h)[i];
        const float4 du4 = ((const float4*)dh)[i];
        short o[4], doo[4];
        const float us[4] = {u4.x, u4.y, u4.z, u4.w};
        const float dus[4] = {du4.x, du4.y, du4.z, du4.w};
        #pragma unroll
        for (int j = 0; j < 4; ++j) {
            const float u = us[j], du = dus[j];
            const float cdf = 0.5f * (1.0f + erff(u * 0.70710678118654752f));
            const float pdf = 0.3989422804014327f * expf(-0.5f * u * u);
            o[j]   = (short)f2bf(u * cdf);
            doo[j] = (short)f2bf(du * (cdf + u * pdf));
        }
        *(short4*)&ho[i * 4]  = *(short4*)o;
        *(short4*)&dho[i * 4] = *(short4*)doo;
    }
}

__global__ __launch_bounds__(256) void cast_bf16_kernel(
    const float* __restrict__ in, short* __restrict__ out, int n4)
{
    for (int i = blockIdx.x * blockDim.x + threadIdx.x; i < n4;
         i += gridDim.x * blockDim.x) {
        const float4 v = ((const float4*)in)[i];
        short o[4];
        o[0] = (short)f2bf(v.x); o[1] = (short)f2bf(v.y);
        o[2] = (short)f2bf(v.z); o[3] = (short)f2bf(v.w);
        *(short4*)&out[i * 4] = *(short4*)o;
    }
}

__global__ __launch_bounds__(256) void im2col_kernel(
    const float* __restrict__ x, short* __restrict__ xp, int total)
{
    for (int i = blockIdx.x * blockDim.x + threadIdx.x; i < total;
         i += gridDim.x * blockDim.x) {
        const int k  = i % 768;
        const int m  = i / 768;
        const int gh = m % GP_;
        const int n  = m / GP_;
        const int q  = k & 15;
        const int p  = (k >> 4) & 15;
        const int c  = k >> 8;
        const int hc = gh % 14, gr = gh / 14;
        const int ir = gr * 16 + p, ic = hc * 16 + q;
        xp[i] = (short)f2bf(x[(((long long)n * 3 + c) * 224 + ir) * 224 + ic]);
    }
}

__global__ __launch_bounds__(256) void assemble_kernel(
    const float* __restrict__ tok, const float* __restrict__ dtok,
    float* __restrict__ z, float* __restrict__ dz,
    const float* __restrict__ cls, const float* __restrict__ pos, int total)
{
    for (int i = blockIdx.x * blockDim.x + threadIdx.x; i < total;
         i += gridDim.x * blockDim.x) {
        const int d = i % D_;
        const int s = (i / D_) % S_;
        const int n = i / (D_ * S_);
        if (s == 0) {
            z[i]  = cls[d] + pos[d];
            dz[i] = 0.f;
        } else {
            const long long ti = ((long long)n * GP_ + s - 1) * D_ + d;
            z[i]  = tok[ti]  + pos[s * D_ + d];
            dz[i] = dtok[ti];
        }
    }
}

// ================= host helpers =================
static inline void mgemm(hipStream_t st, const short* A, const short* Bm, const float* bias,
                         void* C, int M, int N, int K, int ldc, bool acc, bool hasbias, bool outbf)
{
    dim3 grid(N / 128, (M + 127) / 128);
    dim3 blk(256);
#define MK(AC, BI, OB) mfma_gemm_kernel<AC, BI, OB><<<grid, blk, 0, st>>>(A, Bm, bias, C, M, N, K, ldc)
    if (outbf) { if (hasbias) MK(false, true, true); else MK(false, false, true); }
    else if (acc) { if (hasbias) MK(true, true, false);  else MK(true, false, false); }
    else     { if (hasbias) MK(false, true, false); else MK(false, false, false); }
#undef MK
}

static inline void cast_bf(hipStream_t st, const float* in, short* out, long long n) {
    const int n4 = (int)(n / 4);
    int g = (n4 + 255) / 256; if (g > 4096) g = 4096;
    cast_bf16_kernel<<<g, 256, 0, st>>>(in, out, n4);
}

extern "C" void kernel_launch(void* const* d_in, const int* in_sizes, int n_in,
                              void* d_out, int out_size, void* d_ws, size_t ws_size,
                              hipStream_t stream)
{
    const float* x       = (const float*)d_in[0];
    const float* tangent = (const float*)d_in[1];
    const float* conv_w  = (const float*)d_in[2];
    const float* conv_b  = (const float*)d_in[3];
    const float* cls     = (const float*)d_in[4];
    const float* pos     = (const float*)d_in[5];
    const float* ln1_g   = (const float*)d_in[6];
    const float* ln1_b   = (const float*)d_in[7];
    const float* qkv_w   = (const float*)d_in[8];
    const float* qkv_b   = (const float*)d_in[9];
    const float* out_w   = (const float*)d_in[10];
    const float* out_b   = (const float*)d_in[11];
    const float* ln2_g   = (const float*)d_in[12];
    const float* ln2_b   = (const float*)d_in[13];
    const float* fc1_w   = (const float*)d_in[14];
    const float* fc1_b   = (const float*)d_in[15];
    const float* fc2_w   = (const float*)d_in[16];
    const float* fc2_b   = (const float*)d_in[17];
    const float* lnf_g   = (const float*)d_in[18];
    const float* lnf_b   = (const float*)d_in[19];
    const float* head_w  = (const float*)d_in[20];
    const float* head_b  = (const float*)d_in[21];
    float* out = (float*)d_out;

    const long long ZSZ = (long long)B_ * S_ * D_;      // 4,841,472
    const long long HSZ = (long long)B_ * S_ * MD_;     // 19,365,888
    const int nBS = B_ * S_;                            // 6304
    const int MPAD = 6400;
    const long long SD = (long long)S_ * D_;
    const int NB = B_ * H_;                             // 384 batches

    float* f = (float*)d_ws;
    float* z     = f;
    float* dz    = z + ZSZ;
    float* y     = dz + ZSZ;
    float* dy    = y + ZSZ;
    float* hbuf  = dy + ZSZ;          // fc1 out; S aliases front (NB*S_*S_ = 14.9M <= HSZ)
    float* dhbuf = hbuf + HSZ;
    float* Sb    = hbuf;
    float* dSb   = dhbuf;

    short* sh     = (short*)(dhbuf + HSZ);
    short* ybf    = sh;                                   // [6400][768]
    short* dybf   = ybf + (long long)MPAD * D_;
    short* qkvbf  = dybf + (long long)MPAD * D_;          // [6304][2304]
    short* dqkvbf = qkvbf + (long long)nBS * 2304;
    short* Vt     = dqkvbf + (long long)nBS * 2304;       // [384][64][224]
    short* dVt    = Vt + (long long)NB * 64 * KP_;
    short* hbf    = dVt + (long long)NB * 64 * KP_;       // [6400][3072]; P aliases front
    short* dhbf   = hbf + (long long)MPAD * MD_;
    short* Pbf    = hbf;
    short* dPbf   = dhbf;
    short* xpbf   = hbf;                                  // patch stage alias
    short* dxpbf  = dhbf;
    short* wq     = dhbf + (long long)MPAD * MD_;         // per-layer weight slab
    short* wo     = wq + 2304 * 768;
    short* w1     = wo + 768 * 768;
    short* w2     = w1 + 3072 * 768;
    short* cwbf   = w2 + 768 * 3072;

    // ---- patch embedding ----
    {
        const int total = B_ * GP_ * D_;   // 4,816,896 = 6272*768
        im2col_kernel<<<8192, 256, 0, stream>>>(x, xpbf, total);
        im2col_kernel<<<8192, 256, 0, stream>>>(tangent, dxpbf, total);
        cast_bf(stream, conv_w, cwbf, 768 * 768);
        mgemm(stream, xpbf,  cwbf, conv_b, y,  B_ * GP_, D_, D_, D_, false, true,  false);
        mgemm(stream, dxpbf, cwbf, nullptr, dy, B_ * GP_, D_, D_, D_, false, false, false);
        const int tz = (int)(B_ * SD);
        assemble_kernel<<<8192, 256, 0, stream>>>(y, dy, z, dz, cls, pos, tz);
    }

    for (int l = 0; l < L_; ++l) {
        const float* l1g = ln1_g + (long long)l * D_;
        const float* l1b = ln1_b + (long long)l * D_;
        const float* qb  = qkv_b + (long long)l * 3 * D_;
        const float* ob  = out_b + (long long)l * D_;
        const float* l2g = ln2_g + (long long)l * D_;
        const float* l2b = ln2_b + (long long)l * D_;
        const float* f1b = fc1_b + (long long)l * MD_;
        const float* f2b = fc2_b + (long long)l * D_;

        cast_bf(stream, qkv_w + (long long)l * 3 * D_ * D_, wq, (long long)3 * D_ * D_);
        cast_bf(stream, out_w + (long long)l * D_ * D_,     wo, (long long)D_ * D_);
        cast_bf(stream, fc1_w + (long long)l * MD_ * D_,    w1, (long long)MD_ * D_);
        cast_bf(stream, fc2_w + (long long)l * D_ * MD_,    w2, (long long)D_ * MD_);

        // LN1 (bf16 outputs only)
        ln_jvp_kernel<false><<<nBS, 256, 0, stream>>>(z, dz, l1g, l1b, nullptr, nullptr, ybf, dybf);
        // QKV -> bf16 directly
        mgemm(stream, ybf,  wq, qb,      qkvbf,  nBS, 3 * D_, D_, 3 * D_, false, true,  true);
        mgemm(stream, dybf, wq, nullptr, dqkvbf, nBS, 3 * D_, D_, 3 * D_, false, false, true);

        // fused scores S/dS
        attn_scores_kernel<<<dim3(4, 4, NB), 256, 0, stream>>>(qkvbf, dqkvbf, Sb, dSb);
        // V transpose
        vtrans_kernel<<<NB * 4, 256, 0, stream>>>(qkvbf, dqkvbf, Vt, dVt);
        // softmax JVP -> bf16 P/dP
        softmax_pjvp_kernel<<<NB * S_, 256, 0, stream>>>(Sb, dSb, Pbf, dPbf);
        // fused PV -> bf16 o/do straight into proj A-operands
        attn_pv_kernel<<<dim3(1, 4, NB), 256, 0, stream>>>(Pbf, dPbf, Vt, dVt, ybf, dybf);

        // projection + residual
        mgemm(stream, ybf,  wo, ob,      z,  nBS, D_, D_, D_, true, true,  false);
        mgemm(stream, dybf, wo, nullptr, dz, nBS, D_, D_, D_, true, false, false);

        // LN2 + MLP
        ln_jvp_kernel<false><<<nBS, 256, 0, stream>>>(z, dz, l2g, l2b, nullptr, nullptr, ybf, dybf);
        mgemm(stream, ybf,  w1, f1b,     hbuf,  nBS, MD_, D_, MD_, false, true,  false);
        mgemm(stream, dybf, w1, nullptr, dhbuf, nBS, MD_, D_, MD_, false, false, false);
        gelu_jvp_kernel<<<4096, 256, 0, stream>>>(hbuf, dhbuf, hbf, dhbf, (int)(HSZ / 4));
        mgemm(stream, hbf,  w2, f2b,     z,  nBS, D_, MD_, D_, true, true,  false);
        mgemm(stream, dhbf, w2, nullptr, dz, nBS, D_, MD_, D_, true, false, false);
    }

    // final LN (fp32 out for head) + head GEMM
    ln_jvp_kernel<true><<<nBS, 256, 0, stream>>>(z, dz, lnf_g, lnf_b, y, dy, ybf, dybf);
    gemm_kernel<true, false, true><<<dim3((NC_ + 63) / 64, 1), 256, 0, stream>>>(
        y,  head_w, head_b, out,            B_, NC_, D_, (int)SD, D_, NC_, 1.f);
    gemm_kernel<true, false, false><<<dim3((NC_ + 63) / 64, 1), 256, 0, stream>>>(
        dy, head_w, nullptr, out + B_ * NC_, B_, NC_, D_, (int)SD, D_, NC_, 1.f);
}

// Round 4
// 8151.299 us; speedup vs baseline: 8.8934x; 1.2278x over previous
//
// ViT-Base/16 fwd + JVP — Round 3: fwd+tangent GEMMs fused into single launches
// (M stacked 2x6400, row-padded buffers), bias row-gated, XCD-aware block swizzle.
#include <hip/hip_runtime.h>
#include <math.h>

static constexpr int B_   = 32;
static constexpr int S_   = 197;
static constexpr int D_   = 768;
static constexpr int H_   = 12;
static constexpr int L_   = 12;
static constexpr int MD_  = 3072;
static constexpr int NC_  = 1000;
static constexpr int GP_  = 196;
static constexpr int KP_  = 224;   // padded attention-K (7*32)
static constexpr int MP_  = 6400;  // padded row count (50*128)

typedef __attribute__((ext_vector_type(8))) short bf16x8v;
typedef __attribute__((ext_vector_type(4))) float f32x4v;

__device__ __forceinline__ unsigned short f2bf(float x) {
    union { float f; unsigned u; } v; v.f = x;
    unsigned r = v.u + 0x7fffu + ((v.u >> 16) & 1u);   // RNE
    return (unsigned short)(r >> 16);
}

#define GLOAD_LDS16(gptr, lptr) \
    __builtin_amdgcn_global_load_lds((const __attribute__((address_space(1))) void*)(gptr), \
        (__attribute__((address_space(3))) void*)(lptr), 16, 0, 0)

// ================= dense MFMA GEMM (128x128 tile) =================
// C[m,n] (+)= sum_k A[m][k]*B[n][k] (+bias[n] if row<bias_rows).
// A bf16 [gridM*128][K]; B bf16 [N][K]; C fp32 (opt ACC) or bf16.
template<bool ACC, bool BIAS, bool OUTBF>
__global__ __launch_bounds__(256) void mfma_gemm_kernel(
    const short* __restrict__ A, const short* __restrict__ Bm,
    const float* __restrict__ bias, void* __restrict__ Cv,
    int M, int N, int K, int ldc, int bias_rows)
{
    // bijective XCD-aware swizzle (m204)
    int bx, by;
    {
        const int gx = gridDim.x, nwg = gx * gridDim.y;
        const int flat = blockIdx.y * gx + blockIdx.x;
        const int q = nwg >> 3, r = nwg & 7;
        const int xcd = flat & 7, idx = flat >> 3;
        const int nf = (xcd < r ? xcd * (q + 1) : r * (q + 1) + (xcd - r) * q) + idx;
        bx = nf % gx; by = nf / gx;
    }
    __shared__ __align__(16) short ldsA[128 * 32];
    __shared__ __align__(16) short ldsB[128 * 32];
    const int tid  = threadIdx.x;
    const int lane = tid & 63;
    const int w    = tid >> 6;
    const int m0 = by * 128, n0 = bx * 128;
    const int wr = w >> 1, wc = w & 1;
    f32x4v acc[4][4] = {};

    const int r_in = lane >> 2;
    const int cdst = lane & 3;

    for (int k0 = 0; k0 < K; k0 += 32) {
        #pragma unroll
        for (int i = 0; i < 2; ++i) {
            const int c0  = w + i * 4;
            const int row = c0 * 16 + r_in;
            const int csrc = cdst ^ ((row >> 1) & 3);
            GLOAD_LDS16(A  + (size_t)(m0 + row) * K + k0 + csrc * 8, &ldsA[c0 * 16 * 32]);
            GLOAD_LDS16(Bm + (size_t)(n0 + row) * K + k0 + csrc * 8, &ldsB[c0 * 16 * 32]);
        }
        __syncthreads();
        bf16x8v af[4], bfr[4];
        #pragma unroll
        for (int m = 0; m < 4; ++m) {
            const int row = wr * 64 + m * 16 + (lane & 15);
            const int c = (lane >> 4) ^ ((row >> 1) & 3);
            af[m] = *(const bf16x8v*)&ldsA[row * 32 + c * 8];
        }
        #pragma unroll
        for (int n = 0; n < 4; ++n) {
            const int row = wc * 64 + n * 16 + (lane & 15);
            const int c = (lane >> 4) ^ ((row >> 1) & 3);
            bfr[n] = *(const bf16x8v*)&ldsB[row * 32 + c * 8];
        }
        #pragma unroll
        for (int m = 0; m < 4; ++m)
            #pragma unroll
            for (int n = 0; n < 4; ++n)
                acc[m][n] = __builtin_amdgcn_mfma_f32_16x16x32_bf16(af[m], bfr[n], acc[m][n], 0, 0, 0);
        __syncthreads();
    }
    const int col_base = n0 + wc * 64 + (lane & 15);
    const int row_base = m0 + wr * 64 + (lane >> 4) * 4;
    #pragma unroll
    for (int n = 0; n < 4; ++n) {
        const int col = col_base + n * 16;
        const float bv = BIAS ? bias[col] : 0.f;
        #pragma unroll
        for (int m = 0; m < 4; ++m) {
            const int row = row_base + m * 16;
            const float bvr = (BIAS && row < bias_rows) ? bv : 0.f;  // strip-uniform
            #pragma unroll
            for (int r = 0; r < 4; ++r) {
                if (row + r < M) {
                    const size_t off = (size_t)(row + r) * ldc + col;
                    const float v = acc[m][n][r] + bvr;
                    if (OUTBF) ((short*)Cv)[off] = (short)f2bf(v);
                    else if (ACC) ((float*)Cv)[off] += v;
                    else ((float*)Cv)[off] = v;
                }
            }
        }
    }
}

// ================= fused attention scores JVP =================
__global__ __launch_bounds__(256) void attn_scores_kernel(
    const short* __restrict__ qkvb, const short* __restrict__ dqkvb,
    float* __restrict__ S, float* __restrict__ dS)
{
    const int bz = blockIdx.z;
    const int n = bz / H_, h = bz - n * H_;
    const short* qb  = qkvb  + (size_t)n * S_ * 2304 + h * 64;
    const short* kb  = qb + 768;
    const short* dqb = dqkvb + (size_t)n * S_ * 2304 + h * 64;
    const short* dkb = dqb + 768;
    float* Sb  = S  + (size_t)bz * S_ * S_;
    float* dSb = dS + (size_t)bz * S_ * S_;

    __shared__ __align__(16) short lq[64*32], ldq[64*32], lk[64*32], ldk[64*32];
    const int tid = threadIdx.x, lane = tid & 63, w = tid >> 6;
    const int m0 = blockIdx.y * 64, n0 = blockIdx.x * 64;
    const int wr = w >> 1, wc = w & 1;
    f32x4v aS[2][2] = {}, aD[2][2] = {};

    const int r_in = lane >> 2;
    const int cdst = lane & 3;
    const int row  = w * 16 + r_in;
    const int csrc = cdst ^ ((row >> 1) & 3);
    const size_t ar = (size_t)min(m0 + row, S_ - 1) * 2304;
    const size_t br = (size_t)min(n0 + row, S_ - 1) * 2304;

    #pragma unroll
    for (int k0 = 0; k0 < 64; k0 += 32) {
        GLOAD_LDS16(qb  + ar + k0 + csrc * 8, &lq [w * 16 * 32]);
        GLOAD_LDS16(dqb + ar + k0 + csrc * 8, &ldq[w * 16 * 32]);
        GLOAD_LDS16(kb  + br + k0 + csrc * 8, &lk [w * 16 * 32]);
        GLOAD_LDS16(dkb + br + k0 + csrc * 8, &ldk[w * 16 * 32]);
        __syncthreads();
        bf16x8v qf[2], dqf[2], kf[2], dkf[2];
        #pragma unroll
        for (int m = 0; m < 2; ++m) {
            const int rr = wr * 32 + m * 16 + (lane & 15);
            const int c = (lane >> 4) ^ ((rr >> 1) & 3);
            qf[m]  = *(const bf16x8v*)&lq [rr * 32 + c * 8];
            dqf[m] = *(const bf16x8v*)&ldq[rr * 32 + c * 8];
        }
        #pragma unroll
        for (int nn = 0; nn < 2; ++nn) {
            const int rr = wc * 32 + nn * 16 + (lane & 15);
            const int c = (lane >> 4) ^ ((rr >> 1) & 3);
            kf[nn]  = *(const bf16x8v*)&lk [rr * 32 + c * 8];
            dkf[nn] = *(const bf16x8v*)&ldk[rr * 32 + c * 8];
        }
        #pragma unroll
        for (int m = 0; m < 2; ++m)
            #pragma unroll
            for (int nn = 0; nn < 2; ++nn) {
                aS[m][nn] = __builtin_amdgcn_mfma_f32_16x16x32_bf16(qf[m],  kf[nn],  aS[m][nn], 0,0,0);
                aD[m][nn] = __builtin_amdgcn_mfma_f32_16x16x32_bf16(dqf[m], kf[nn],  aD[m][nn], 0,0,0);
                aD[m][nn] = __builtin_amdgcn_mfma_f32_16x16x32_bf16(qf[m],  dkf[nn], aD[m][nn], 0,0,0);
            }
        __syncthreads();
    }
    #pragma unroll
    for (int m = 0; m < 2; ++m) {
        const int rbase = m0 + wr * 32 + m * 16 + (lane >> 4) * 4;
        #pragma unroll
        for (int nn = 0; nn < 2; ++nn) {
            const int col = n0 + wc * 32 + nn * 16 + (lane & 15);
            if (col >= S_) continue;
            #pragma unroll
            for (int r = 0; r < 4; ++r) {
                const int rw = rbase + r;
                if (rw < S_) {
                    Sb [(size_t)rw * S_ + col] = aS[m][nn][r] * 0.125f;
                    dSb[(size_t)rw * S_ + col] = aD[m][nn][r] * 0.125f;
                }
            }
        }
    }
}

// ================= softmax JVP -> bf16 P/dP (padded to KP_) =================
__global__ __launch_bounds__(256) void softmax_pjvp_kernel(
    const float* __restrict__ S, const float* __restrict__ dS,
    short* __restrict__ P, short* __restrict__ dP)
{
    const size_t row = blockIdx.x;
    const float* sr  = S  + row * S_;
    const float* dsr = dS + row * S_;
    short* pr  = P  + row * KP_;
    short* dpr = dP + row * KP_;
    __shared__ float smem[4];
    const int t = threadIdx.x;
    float x = -3.4e38f, dx = 0.f;
    if (t < S_) { x = sr[t]; dx = dsr[t]; }
    float v = x;
    #pragma unroll
    for (int off = 32; off > 0; off >>= 1) v = fmaxf(v, __shfl_down(v, off));
    __syncthreads();
    if ((t & 63) == 0) smem[t >> 6] = v;
    __syncthreads();
    const float m = fmaxf(fmaxf(smem[0], smem[1]), fmaxf(smem[2], smem[3]));
    const float e = (t < S_) ? expf(x - m) : 0.f;
    float s = e;
    #pragma unroll
    for (int off = 32; off > 0; off >>= 1) s += __shfl_down(s, off);
    __syncthreads();
    if ((t & 63) == 0) smem[t >> 6] = s;
    __syncthreads();
    const float den = smem[0] + smem[1] + smem[2] + smem[3];
    const float av = e / den;
    float ts = av * dx;
    #pragma unroll
    for (int off = 32; off > 0; off >>= 1) ts += __shfl_down(ts, off);
    __syncthreads();
    if ((t & 63) == 0) smem[t >> 6] = ts;
    __syncthreads();
    const float tsum = smem[0] + smem[1] + smem[2] + smem[3];
    if (t < KP_) {
        pr[t]  = (t < S_) ? (short)f2bf(av) : (short)0;
        dpr[t] = (t < S_) ? (short)f2bf(av * (dx - tsum)) : (short)0;
    }
}

// ================= V transpose =================
__global__ __launch_bounds__(256) void vtrans_kernel(
    const short* __restrict__ qkvb, const short* __restrict__ dqkvb,
    short* __restrict__ Vt, short* __restrict__ dVt)
{
    const int blk = blockIdx.x;
    const int b = blk >> 2, kt = blk & 3;
    const int n = b / H_, h = b - n * H_;
    const short* vb  = qkvb  + (size_t)n * S_ * 2304 + 1536 + h * 64;
    const short* dvb = dqkvb + (size_t)n * S_ * 2304 + 1536 + h * 64;
    __shared__ short t1[64][65], t2[64][65];
    const int tid = threadIdx.x;
    #pragma unroll
    for (int j = 0; j < 16; ++j) {
        const int e = tid + 256 * j;
        const int kk = e >> 6, dh = e & 63;
        const int gk = kt * 64 + kk;
        short v = 0, dv = 0;
        if (gk < S_) { v = vb[(size_t)gk * 2304 + dh]; dv = dvb[(size_t)gk * 2304 + dh]; }
        t1[dh][kk] = v; t2[dh][kk] = dv;
    }
    __syncthreads();
    #pragma unroll
    for (int j = 0; j < 16; ++j) {
        const int e = tid + 256 * j;
        const int dh = e >> 6, kk = e & 63;
        const int ok = kt * 64 + kk;
        if (ok < KP_) {
            Vt [(size_t)b * 64 * KP_ + (size_t)dh * KP_ + ok] = t1[dh][kk];
            dVt[(size_t)b * 64 * KP_ + (size_t)dh * KP_ + ok] = t2[dh][kk];
        }
    }
}

// ================= fused PV JVP =================
__global__ __launch_bounds__(256) void attn_pv_kernel(
    const short* __restrict__ P, const short* __restrict__ dP,
    const short* __restrict__ Vt, const short* __restrict__ dVt,
    short* __restrict__ obf, short* __restrict__ dobf)
{
    const int bz = blockIdx.z;
    const int n = bz / H_, h = bz - n * H_;
    const short* Pb  = P   + (size_t)bz * S_ * KP_;
    const short* dPb = dP  + (size_t)bz * S_ * KP_;
    const short* Vb  = Vt  + (size_t)bz * 64 * KP_;
    const short* dVb = dVt + (size_t)bz * 64 * KP_;
    short* ob  = obf  + (size_t)n * S_ * D_ + h * 64;
    short* dob = dobf + (size_t)n * S_ * D_ + h * 64;

    __shared__ __align__(16) short lp[64*32], ldp[64*32], lv[64*32], ldv[64*32];
    const int tid = threadIdx.x, lane = tid & 63, w = tid >> 6;
    const int m0 = blockIdx.y * 64;
    const int wr = w >> 1, wc = w & 1;
    f32x4v aO[2][2] = {}, aDO[2][2] = {};

    const int r_in = lane >> 2;
    const int cdst = lane & 3;
    const int row  = w * 16 + r_in;
    const int csrc = cdst ^ ((row >> 1) & 3);
    const size_t pr = (size_t)min(m0 + row, S_ - 1) * KP_;
    const size_t vr = (size_t)row * KP_;

    for (int k0 = 0; k0 < KP_; k0 += 32) {
        GLOAD_LDS16(Pb  + pr + k0 + csrc * 8, &lp [w * 16 * 32]);
        GLOAD_LDS16(dPb + pr + k0 + csrc * 8, &ldp[w * 16 * 32]);
        GLOAD_LDS16(Vb  + vr + k0 + csrc * 8, &lv [w * 16 * 32]);
        GLOAD_LDS16(dVb + vr + k0 + csrc * 8, &ldv[w * 16 * 32]);
        __syncthreads();
        bf16x8v pf[2], dpf[2], vf[2], dvf[2];
        #pragma unroll
        for (int m = 0; m < 2; ++m) {
            const int rr = wr * 32 + m * 16 + (lane & 15);
            const int c = (lane >> 4) ^ ((rr >> 1) & 3);
            pf[m]  = *(const bf16x8v*)&lp [rr * 32 + c * 8];
            dpf[m] = *(const bf16x8v*)&ldp[rr * 32 + c * 8];
        }
        #pragma unroll
        for (int nn = 0; nn < 2; ++nn) {
            const int rr = wc * 32 + nn * 16 + (lane & 15);
            const int c = (lane >> 4) ^ ((rr >> 1) & 3);
            vf[nn]  = *(const bf16x8v*)&lv [rr * 32 + c * 8];
            dvf[nn] = *(const bf16x8v*)&ldv[rr * 32 + c * 8];
        }
        #pragma unroll
        for (int m = 0; m < 2; ++m)
            #pragma unroll
            for (int nn = 0; nn < 2; ++nn) {
                aO [m][nn] = __builtin_amdgcn_mfma_f32_16x16x32_bf16(pf[m],  vf[nn],  aO [m][nn], 0,0,0);
                aDO[m][nn] = __builtin_amdgcn_mfma_f32_16x16x32_bf16(dpf[m], vf[nn],  aDO[m][nn], 0,0,0);
                aDO[m][nn] = __builtin_amdgcn_mfma_f32_16x16x32_bf16(pf[m],  dvf[nn], aDO[m][nn], 0,0,0);
            }
        __syncthreads();
    }
    #pragma unroll
    for (int m = 0; m < 2; ++m) {
        const int rbase = m0 + wr * 32 + m * 16 + (lane >> 4) * 4;
        #pragma unroll
        for (int nn = 0; nn < 2; ++nn) {
            const int col = wc * 32 + nn * 16 + (lane & 15);
            #pragma unroll
            for (int r = 0; r < 4; ++r) {
                const int rw = rbase + r;
                if (rw < S_) {
                    ob [(size_t)rw * D_ + col] = (short)f2bf(aO [m][nn][r]);
                    dob[(size_t)rw * D_ + col] = (short)f2bf(aDO[m][nn][r]);
                }
            }
        }
    }
}

// ================= fp32 GEMM (head only) =================
template<bool BIAS>
__global__ __launch_bounds__(256) void gemm_kernel(
    const float* __restrict__ A, const float* __restrict__ Bm,
    const float* __restrict__ bias, float* __restrict__ C,
    int M, int N, int K, int lda, int ldb, int ldc)
{
    const int tile_m = blockIdx.y * 64, tile_n = blockIdx.x * 64;
    __shared__ float As[16][64];
    __shared__ float Bs[16][64];
    const int tid = threadIdx.x;
    const int tx = tid & 15, ty = tid >> 4;
    float acc[4][4] = {};
    for (int k0 = 0; k0 < K; k0 += 16) {
        {
            const int row = tid >> 2, kc = (tid & 3) * 4, gm = tile_m + row;
            #pragma unroll
            for (int i = 0; i < 4; ++i) {
                const int gk = k0 + kc + i;
                float v = 0.f;
                if (gm < M && gk < K) v = A[(long long)gm * lda + gk];
                As[kc + i][row] = v;
            }
        }
        {
            const int row = tid >> 2, kc = (tid & 3) * 4, gn = tile_n + row;
            #pragma unroll
            for (int i = 0; i < 4; ++i) {
                const int gk = k0 + kc + i;
                float v = 0.f;
                if (gn < N && gk < K) v = Bm[(long long)gn * ldb + gk];
                Bs[kc + i][row] = v;
            }
        }
        __syncthreads();
        #pragma unroll
        for (int kk = 0; kk < 16; ++kk) {
            float a[4], b[4];
            #pragma unroll
            for (int i = 0; i < 4; ++i) a[i] = As[kk][ty * 4 + i];
            #pragma unroll
            for (int j = 0; j < 4; ++j) b[j] = Bs[kk][tx * 4 + j];
            #pragma unroll
            for (int i = 0; i < 4; ++i)
                #pragma unroll
                for (int j = 0; j < 4; ++j)
                    acc[i][j] += a[i] * b[j];
        }
        __syncthreads();
    }
    #pragma unroll
    for (int i = 0; i < 4; ++i) {
        const int gm = tile_m + ty * 4 + i;
        if (gm >= M) continue;
        #pragma unroll
        for (int j = 0; j < 4; ++j) {
            const int gn = tile_n + tx * 4 + j;
            if (gn >= N) continue;
            float v = acc[i][j];
            if (BIAS) v += bias[gn];
            C[(long long)gm * ldc + gn] = v;
        }
    }
}

// ================= LayerNorm JVP =================
__device__ __forceinline__ float blk_sum4(float v, float* smem) {
    #pragma unroll
    for (int off = 32; off > 0; off >>= 1) v += __shfl_down(v, off);
    __syncthreads();
    if ((threadIdx.x & 63) == 0) smem[threadIdx.x >> 6] = v;
    __syncthreads();
    return smem[0] + smem[1] + smem[2] + smem[3];
}

template<bool WF32>
__global__ __launch_bounds__(256) void ln_jvp_kernel(
    const float* __restrict__ z, const float* __restrict__ dz,
    const float* __restrict__ g, const float* __restrict__ b,
    float* __restrict__ y, float* __restrict__ dy,
    short* __restrict__ ybf, short* __restrict__ dybf)
{
    const long long row = blockIdx.x;
    const float* xr  = z  + row * D_;
    const float* dxr = dz + row * D_;
    __shared__ float smem[4];
    const int t = threadIdx.x;
    float x[3], dx[3];
    #pragma unroll
    for (int i = 0; i < 3; ++i) { x[i] = xr[t + 256 * i]; dx[i] = dxr[t + 256 * i]; }
    float sx  = blk_sum4(x[0] + x[1] + x[2], smem);
    float sdx = blk_sum4(dx[0] + dx[1] + dx[2], smem);
    const float mu = sx / D_, dmu = sdx / D_;
    float sv = 0.f, sc = 0.f;
    #pragma unroll
    for (int i = 0; i < 3; ++i) {
        const float xc = x[i] - mu;
        sv += xc * xc;
        sc += xc * (dx[i] - dmu);
    }
    sv = blk_sum4(sv, smem);
    sc = blk_sum4(sc, smem);
    const float rstd = rsqrtf(sv / D_ + 1e-6f);
    const float k2   = (sc / D_) * rstd * rstd;
    #pragma unroll
    for (int i = 0; i < 3; ++i) {
        const int c = t + 256 * i;
        const float yh  = (x[i] - mu) * rstd;
        const float dyh = (dx[i] - dmu) * rstd - yh * k2;
        const float yv  = yh * g[c] + b[c];
        const float dyv = dyh * g[c];
        if (WF32) { y[row * D_ + c] = yv; dy[row * D_ + c] = dyv; }
        ybf[row * D_ + c]  = (short)f2bf(yv);
        dybf[row * D_ + c] = (short)f2bf(dyv);
    }
}

// ================= GELU JVP: fp32 in, bf16 out =================
__global__ __launch_bounds__(256) void gelu_jvp_kernel(
    const float* __restrict__ h, const float* __restrict__ dh,
    short* __restrict__ ho, short* __restrict__ dho, int n4)
{
    for (int i = blockIdx.x * blockDim.x + threadIdx.x; i < n4;
         i += gridDim.x * blockDim.x) {
        const float4 u4 = ((const float4*)h)[i];
        const float4 du4 = ((const float4*)dh)[i];
        short o[4], doo[4];
        const float us[4] = {u4.x, u4.y, u4.z, u4.w};
        const float dus[4] = {du4.x, du4.y, du4.z, du4.w};
        #pragma unroll
        for (int j = 0; j < 4; ++j) {
            const float u = us[j], du = dus[j];
            const float cdf = 0.5f * (1.0f + erff(u * 0.70710678118654752f));
            const float pdf = 0.3989422804014327f * expf(-0.5f * u * u);
            o[j]   = (short)f2bf(u * cdf);
            doo[j] = (short)f2bf(du * (cdf + u * pdf));
        }
        *(short4*)&ho[i * 4]  = *(short4*)o;
        *(short4*)&dho[i * 4] = *(short4*)doo;
    }
}

__global__ __launch_bounds__(256) void cast_bf16_kernel(
    const float* __restrict__ in, short* __restrict__ out, int n4)
{
    for (int i = blockIdx.x * blockDim.x + threadIdx.x; i < n4;
         i += gridDim.x * blockDim.x) {
        const float4 v = ((const float4*)in)[i];
        short o[4];
        o[0] = (short)f2bf(v.x); o[1] = (short)f2bf(v.y);
        o[2] = (short)f2bf(v.z); o[3] = (short)f2bf(v.w);
        *(short4*)&out[i * 4] = *(short4*)o;
    }
}

__global__ __launch_bounds__(256) void im2col_kernel(
    const float* __restrict__ x, short* __restrict__ xp, int total)
{
    for (int i = blockIdx.x * blockDim.x + threadIdx.x; i < total;
         i += gridDim.x * blockDim.x) {
        const int k  = i % 768;
        const int m  = i / 768;
        const int gh = m % GP_;
        const int n  = m / GP_;
        const int q  = k & 15;
        const int p  = (k >> 4) & 15;
        const int c  = k >> 8;
        const int hc = gh % 14, gr = gh / 14;
        const int ir = gr * 16 + p, ic = hc * 16 + q;
        xp[i] = (short)f2bf(x[(((long long)n * 3 + c) * 224 + ir) * 224 + ic]);
    }
}

__global__ __launch_bounds__(256) void assemble_kernel(
    const float* __restrict__ tok, const float* __restrict__ dtok,
    float* __restrict__ z, float* __restrict__ dz,
    const float* __restrict__ cls, const float* __restrict__ pos, int total)
{
    for (int i = blockIdx.x * blockDim.x + threadIdx.x; i < total;
         i += gridDim.x * blockDim.x) {
        const int d = i % D_;
        const int s = (i / D_) % S_;
        const int n = i / (D_ * S_);
        if (s == 0) {
            z[i]  = cls[d] + pos[d];
            dz[i] = 0.f;
        } else {
            const long long ti = ((long long)n * GP_ + s - 1) * D_ + d;
            z[i]  = tok[ti]  + pos[s * D_ + d];
            dz[i] = dtok[ti];
        }
    }
}

// ================= host helpers =================
static inline void mgemm(hipStream_t st, const short* A, const short* Bm, const float* bias,
                         void* C, int M, int N, int K, int ldc, int bias_rows,
                         bool acc, bool hasbias, bool outbf)
{
    dim3 grid(N / 128, (M + 127) / 128);
    dim3 blk(256);
#define MK(AC, BI, OB) mfma_gemm_kernel<AC, BI, OB><<<grid, blk, 0, st>>>(A, Bm, bias, C, M, N, K, ldc, bias_rows)
    if (outbf) { if (hasbias) MK(false, true, true); else MK(false, false, true); }
    else if (acc) { if (hasbias) MK(true, true, false);  else MK(true, false, false); }
    else     { if (hasbias) MK(false, true, false); else MK(false, false, false); }
#undef MK
}

static inline void cast_bf(hipStream_t st, const float* in, short* out, long long n) {
    const int n4 = (int)(n / 4);
    int g = (n4 + 255) / 256; if (g > 4096) g = 4096;
    cast_bf16_kernel<<<g, 256, 0, st>>>(in, out, n4);
}

extern "C" void kernel_launch(void* const* d_in, const int* in_sizes, int n_in,
                              void* d_out, int out_size, void* d_ws, size_t ws_size,
                              hipStream_t stream)
{
    const float* x       = (const float*)d_in[0];
    const float* tangent = (const float*)d_in[1];
    const float* conv_w  = (const float*)d_in[2];
    const float* conv_b  = (const float*)d_in[3];
    const float* cls     = (const float*)d_in[4];
    const float* pos     = (const float*)d_in[5];
    const float* ln1_g   = (const float*)d_in[6];
    const float* ln1_b   = (const float*)d_in[7];
    const float* qkv_w   = (const float*)d_in[8];
    const float* qkv_b   = (const float*)d_in[9];
    const float* out_w   = (const float*)d_in[10];
    const float* out_b   = (const float*)d_in[11];
    const float* ln2_g   = (const float*)d_in[12];
    const float* ln2_b   = (const float*)d_in[13];
    const float* fc1_w   = (const float*)d_in[14];
    const float* fc1_b   = (const float*)d_in[15];
    const float* fc2_w   = (const float*)d_in[16];
    const float* fc2_b   = (const float*)d_in[17];
    const float* lnf_g   = (const float*)d_in[18];
    const float* lnf_b   = (const float*)d_in[19];
    const float* head_w  = (const float*)d_in[20];
    const float* head_b  = (const float*)d_in[21];
    float* out = (float*)d_out;

    const int nBS = B_ * S_;                            // 6304
    const int NB = B_ * H_;                             // 384
    const long long SD = (long long)S_ * D_;
    const long long PZ = (long long)MP_ * D_;           // 4,915,200 (padded z rows)
    const long long PQ = (long long)MP_ * 2304;         // 14,745,600
    const long long PH = (long long)MP_ * MD_;          // 19,660,800
    const long long PTOK = (long long)B_ * GP_ * D_;    // 4,816,896 (6272 rows)

    // ---- fp32 region ----
    float* f = (float*)d_ws;
    float* z     = f;             // [6400][768] (rows>=6304 pad)
    float* dz    = z + PZ;
    float* hbuf  = dz + PZ;       // [6400][3072] fwd; aliases: S, tok, final y
    float* dhbuf = hbuf + PH;     // tangent half
    float* Sb    = hbuf;
    float* dSb   = dhbuf;
    float* tok   = hbuf;          // patch stage: C = tok‖dtok [2*6272][768]
    float* dtok  = hbuf + PTOK;
    float* yf    = hbuf;          // final-LN fp32 out
    float* dyf   = dhbuf;

    // ---- bf16 region ----
    short* sh     = (short*)(dhbuf + PH);
    short* ybf    = sh;                       // [2*6400][768]  fwd‖tan
    short* dybf   = ybf + PZ;
    short* qkvbf  = dybf + PZ;                // [2*6400][2304]
    short* dqkvbf = qkvbf + PQ;
    short* Vt     = dqkvbf + PQ;              // [384][64][224] x2
    short* dVt    = Vt + (long long)NB * 64 * KP_;
    short* hbf    = dVt + (long long)NB * 64 * KP_;   // [2*6400][3072]
    short* dhbf   = hbf + PH;
    short* Pbf    = hbf;   short* dPbf = dhbf;        // aliases
    short* xpbf   = hbf;                               // patch A: xp‖dxp [2*6272][768]
    short* dxpbf  = xpbf + PTOK;
    short* wq     = dhbf + PH;                // weight slab
    short* wo     = wq + 2304 * 768;
    short* w1     = wo + 768 * 768;
    short* w2     = w1 + 3072 * 768;
    short* cwbf   = w2 + 768 * 3072;

    // ---- patch embedding (single fused GEMM, M = 2*6272) ----
    {
        const int total = (int)PTOK;
        im2col_kernel<<<8192, 256, 0, stream>>>(x, xpbf, total);
        im2col_kernel<<<8192, 256, 0, stream>>>(tangent, dxpbf, total);
        cast_bf(stream, conv_w, cwbf, 768 * 768);
        mgemm(stream, xpbf, cwbf, conv_b, tok, 2 * B_ * GP_, D_, D_, D_,
              B_ * GP_, false, true, false);
        const int tz = (int)(B_ * SD);
        assemble_kernel<<<8192, 256, 0, stream>>>(tok, dtok, z, dz, cls, pos, tz);
    }

    for (int l = 0; l < L_; ++l) {
        const float* l1g = ln1_g + (long long)l * D_;
        const float* l1b = ln1_b + (long long)l * D_;
        const float* qb  = qkv_b + (long long)l * 3 * D_;
        const float* ob  = out_b + (long long)l * D_;
        const float* l2g = ln2_g + (long long)l * D_;
        const float* l2b = ln2_b + (long long)l * D_;
        const float* f1b = fc1_b + (long long)l * MD_;
        const float* f2b = fc2_b + (long long)l * D_;

        cast_bf(stream, qkv_w + (long long)l * 3 * D_ * D_, wq, (long long)3 * D_ * D_);
        cast_bf(stream, out_w + (long long)l * D_ * D_,     wo, (long long)D_ * D_);
        cast_bf(stream, fc1_w + (long long)l * MD_ * D_,    w1, (long long)MD_ * D_);
        cast_bf(stream, fc2_w + (long long)l * D_ * MD_,    w2, (long long)D_ * MD_);

        // LN1
        ln_jvp_kernel<false><<<nBS, 256, 0, stream>>>(z, dz, l1g, l1b, nullptr, nullptr, ybf, dybf);
        // QKV fwd+tan fused (bias only on fwd half)
        mgemm(stream, ybf, wq, qb, qkvbf, 2 * MP_, 3 * D_, D_, 3 * D_, MP_, false, true, true);

        // attention
        attn_scores_kernel<<<dim3(4, 4, NB), 256, 0, stream>>>(qkvbf, dqkvbf, Sb, dSb);
        vtrans_kernel<<<NB * 4, 256, 0, stream>>>(qkvbf, dqkvbf, Vt, dVt);
        softmax_pjvp_kernel<<<NB * S_, 256, 0, stream>>>(Sb, dSb, Pbf, dPbf);
        attn_pv_kernel<<<dim3(1, 4, NB), 256, 0, stream>>>(Pbf, dPbf, Vt, dVt, ybf, dybf);

        // projection + residual, fwd+tan fused (ACC into z‖dz)
        mgemm(stream, ybf, wo, ob, z, 2 * MP_, D_, D_, D_, MP_, true, true, false);

        // LN2 + MLP
        ln_jvp_kernel<false><<<nBS, 256, 0, stream>>>(z, dz, l2g, l2b, nullptr, nullptr, ybf, dybf);
        mgemm(stream, ybf, w1, f1b, hbuf, 2 * MP_, MD_, D_, MD_, MP_, false, true, false);
        gelu_jvp_kernel<<<4096, 256, 0, stream>>>(hbuf, dhbuf, hbf, dhbf, (int)(PH / 4));
        mgemm(stream, hbf, w2, f2b, z, 2 * MP_, D_, MD_, D_, MP_, true, true, false);
    }

    // final LN (fp32 out) + head
    ln_jvp_kernel<true><<<nBS, 256, 0, stream>>>(z, dz, lnf_g, lnf_b, yf, dyf, ybf, dybf);
    gemm_kernel<true><<<dim3((NC_ + 63) / 64, 1), 256, 0, stream>>>(
        yf,  head_w, head_b, out,            B_, NC_, D_, (int)SD, D_, NC_);
    gemm_kernel<false><<<dim3((NC_ + 63) / 64, 1), 256, 0, stream>>>(
        dyf, head_w, nullptr, out + B_ * NC_, B_, NC_, D_, (int)SD, D_, NC_);
}

// Round 5
// 7482.999 us; speedup vs baseline: 9.6877x; 1.0893x over previous
//
// ViT-Base/16 fwd + JVP — Round 4: dense MFMA GEMM re-partitioned to 8 waves
// (512 thr, 32x64 per wave, same 128x128 tile / LDS / swizzle) to double
// resident waves per CU. Everything else as R3.
#include <hip/hip_runtime.h>
#include <math.h>

static constexpr int B_   = 32;
static constexpr int S_   = 197;
static constexpr int D_   = 768;
static constexpr int H_   = 12;
static constexpr int L_   = 12;
static constexpr int MD_  = 3072;
static constexpr int NC_  = 1000;
static constexpr int GP_  = 196;
static constexpr int KP_  = 224;   // padded attention-K (7*32)
static constexpr int MP_  = 6400;  // padded row count (50*128)

typedef __attribute__((ext_vector_type(8))) short bf16x8v;
typedef __attribute__((ext_vector_type(4))) float f32x4v;

__device__ __forceinline__ unsigned short f2bf(float x) {
    union { float f; unsigned u; } v; v.f = x;
    unsigned r = v.u + 0x7fffu + ((v.u >> 16) & 1u);   // RNE
    return (unsigned short)(r >> 16);
}

#define GLOAD_LDS16(gptr, lptr) \
    __builtin_amdgcn_global_load_lds((const __attribute__((address_space(1))) void*)(gptr), \
        (__attribute__((address_space(3))) void*)(lptr), 16, 0, 0)

// ================= dense MFMA GEMM (128x128 tile, 8 waves) =================
// C[m,n] (+)= sum_k A[m][k]*B[n][k] (+bias[n] if row<bias_rows).
// A bf16 [gridM*128][K]; B bf16 [N][K]; C fp32 (opt ACC) or bf16.
// 512 thr = 8 waves (4 row-groups x 2 col-groups), wave tile 32x64.
template<bool ACC, bool BIAS, bool OUTBF>
__global__ __launch_bounds__(512, 4) void mfma_gemm_kernel(
    const short* __restrict__ A, const short* __restrict__ Bm,
    const float* __restrict__ bias, void* __restrict__ Cv,
    int M, int N, int K, int ldc, int bias_rows)
{
    // bijective XCD-aware swizzle (m204)
    int bx, by;
    {
        const int gx = gridDim.x, nwg = gx * gridDim.y;
        const int flat = blockIdx.y * gx + blockIdx.x;
        const int q = nwg >> 3, r = nwg & 7;
        const int xcd = flat & 7, idx = flat >> 3;
        const int nf = (xcd < r ? xcd * (q + 1) : r * (q + 1) + (xcd - r) * q) + idx;
        bx = nf % gx; by = nf / gx;
    }
    __shared__ __align__(16) short ldsA[128 * 32];
    __shared__ __align__(16) short ldsB[128 * 32];
    const int tid  = threadIdx.x;
    const int lane = tid & 63;
    const int w    = tid >> 6;            // 0..7
    const int m0 = by * 128, n0 = bx * 128;
    const int wr = w >> 1, wc = w & 1;    // 4x2 wave grid
    f32x4v acc[2][4] = {};

    // staging: wave w owns 16-row chunk w of both A and B tiles
    const int r_in = lane >> 2;
    const int cdst = lane & 3;
    const int srow = w * 16 + r_in;                 // 0..127
    const int csrc = cdst ^ ((srow >> 1) & 3);      // involutive chunk swizzle
    const size_t aoff = (size_t)(m0 + srow) * K + csrc * 8;
    const size_t boff = (size_t)(n0 + srow) * K + csrc * 8;

    for (int k0 = 0; k0 < K; k0 += 32) {
        GLOAD_LDS16(A  + aoff + k0, &ldsA[w * 16 * 32]);
        GLOAD_LDS16(Bm + boff + k0, &ldsB[w * 16 * 32]);
        __syncthreads();
        bf16x8v af[2], bfr[4];
        #pragma unroll
        for (int m = 0; m < 2; ++m) {
            const int row = wr * 32 + m * 16 + (lane & 15);
            const int c = (lane >> 4) ^ ((row >> 1) & 3);
            af[m] = *(const bf16x8v*)&ldsA[row * 32 + c * 8];
        }
        #pragma unroll
        for (int n = 0; n < 4; ++n) {
            const int row = wc * 64 + n * 16 + (lane & 15);
            const int c = (lane >> 4) ^ ((row >> 1) & 3);
            bfr[n] = *(const bf16x8v*)&ldsB[row * 32 + c * 8];
        }
        #pragma unroll
        for (int m = 0; m < 2; ++m)
            #pragma unroll
            for (int n = 0; n < 4; ++n)
                acc[m][n] = __builtin_amdgcn_mfma_f32_16x16x32_bf16(af[m], bfr[n], acc[m][n], 0, 0, 0);
        __syncthreads();
    }
    const int col_base = n0 + wc * 64 + (lane & 15);
    const int row_base = m0 + wr * 32 + (lane >> 4) * 4;
    #pragma unroll
    for (int n = 0; n < 4; ++n) {
        const int col = col_base + n * 16;
        const float bv = BIAS ? bias[col] : 0.f;
        #pragma unroll
        for (int m = 0; m < 2; ++m) {
            const int row = row_base + m * 16;
            const float bvr = (BIAS && row < bias_rows) ? bv : 0.f;
            #pragma unroll
            for (int r = 0; r < 4; ++r) {
                if (row + r < M) {
                    const size_t off = (size_t)(row + r) * ldc + col;
                    const float v = acc[m][n][r] + bvr;
                    if (OUTBF) ((short*)Cv)[off] = (short)f2bf(v);
                    else if (ACC) ((float*)Cv)[off] += v;
                    else ((float*)Cv)[off] = v;
                }
            }
        }
    }
}

// ================= fused attention scores JVP =================
__global__ __launch_bounds__(256) void attn_scores_kernel(
    const short* __restrict__ qkvb, const short* __restrict__ dqkvb,
    float* __restrict__ S, float* __restrict__ dS)
{
    const int bz = blockIdx.z;
    const int n = bz / H_, h = bz - n * H_;
    const short* qb  = qkvb  + (size_t)n * S_ * 2304 + h * 64;
    const short* kb  = qb + 768;
    const short* dqb = dqkvb + (size_t)n * S_ * 2304 + h * 64;
    const short* dkb = dqb + 768;
    float* Sb  = S  + (size_t)bz * S_ * S_;
    float* dSb = dS + (size_t)bz * S_ * S_;

    __shared__ __align__(16) short lq[64*32], ldq[64*32], lk[64*32], ldk[64*32];
    const int tid = threadIdx.x, lane = tid & 63, w = tid >> 6;
    const int m0 = blockIdx.y * 64, n0 = blockIdx.x * 64;
    const int wr = w >> 1, wc = w & 1;
    f32x4v aS[2][2] = {}, aD[2][2] = {};

    const int r_in = lane >> 2;
    const int cdst = lane & 3;
    const int row  = w * 16 + r_in;
    const int csrc = cdst ^ ((row >> 1) & 3);
    const size_t ar = (size_t)min(m0 + row, S_ - 1) * 2304;
    const size_t br = (size_t)min(n0 + row, S_ - 1) * 2304;

    #pragma unroll
    for (int k0 = 0; k0 < 64; k0 += 32) {
        GLOAD_LDS16(qb  + ar + k0 + csrc * 8, &lq [w * 16 * 32]);
        GLOAD_LDS16(dqb + ar + k0 + csrc * 8, &ldq[w * 16 * 32]);
        GLOAD_LDS16(kb  + br + k0 + csrc * 8, &lk [w * 16 * 32]);
        GLOAD_LDS16(dkb + br + k0 + csrc * 8, &ldk[w * 16 * 32]);
        __syncthreads();
        bf16x8v qf[2], dqf[2], kf[2], dkf[2];
        #pragma unroll
        for (int m = 0; m < 2; ++m) {
            const int rr = wr * 32 + m * 16 + (lane & 15);
            const int c = (lane >> 4) ^ ((rr >> 1) & 3);
            qf[m]  = *(const bf16x8v*)&lq [rr * 32 + c * 8];
            dqf[m] = *(const bf16x8v*)&ldq[rr * 32 + c * 8];
        }
        #pragma unroll
        for (int nn = 0; nn < 2; ++nn) {
            const int rr = wc * 32 + nn * 16 + (lane & 15);
            const int c = (lane >> 4) ^ ((rr >> 1) & 3);
            kf[nn]  = *(const bf16x8v*)&lk [rr * 32 + c * 8];
            dkf[nn] = *(const bf16x8v*)&ldk[rr * 32 + c * 8];
        }
        #pragma unroll
        for (int m = 0; m < 2; ++m)
            #pragma unroll
            for (int nn = 0; nn < 2; ++nn) {
                aS[m][nn] = __builtin_amdgcn_mfma_f32_16x16x32_bf16(qf[m],  kf[nn],  aS[m][nn], 0,0,0);
                aD[m][nn] = __builtin_amdgcn_mfma_f32_16x16x32_bf16(dqf[m], kf[nn],  aD[m][nn], 0,0,0);
                aD[m][nn] = __builtin_amdgcn_mfma_f32_16x16x32_bf16(qf[m],  dkf[nn], aD[m][nn], 0,0,0);
            }
        __syncthreads();
    }
    #pragma unroll
    for (int m = 0; m < 2; ++m) {
        const int rbase = m0 + wr * 32 + m * 16 + (lane >> 4) * 4;
        #pragma unroll
        for (int nn = 0; nn < 2; ++nn) {
            const int col = n0 + wc * 32 + nn * 16 + (lane & 15);
            if (col >= S_) continue;
            #pragma unroll
            for (int r = 0; r < 4; ++r) {
                const int rw = rbase + r;
                if (rw < S_) {
                    Sb [(size_t)rw * S_ + col] = aS[m][nn][r] * 0.125f;
                    dSb[(size_t)rw * S_ + col] = aD[m][nn][r] * 0.125f;
                }
            }
        }
    }
}

// ================= softmax JVP -> bf16 P/dP (padded to KP_) =================
__global__ __launch_bounds__(256) void softmax_pjvp_kernel(
    const float* __restrict__ S, const float* __restrict__ dS,
    short* __restrict__ P, short* __restrict__ dP)
{
    const size_t row = blockIdx.x;
    const float* sr  = S  + row * S_;
    const float* dsr = dS + row * S_;
    short* pr  = P  + row * KP_;
    short* dpr = dP + row * KP_;
    __shared__ float smem[4];
    const int t = threadIdx.x;
    float x = -3.4e38f, dx = 0.f;
    if (t < S_) { x = sr[t]; dx = dsr[t]; }
    float v = x;
    #pragma unroll
    for (int off = 32; off > 0; off >>= 1) v = fmaxf(v, __shfl_down(v, off));
    __syncthreads();
    if ((t & 63) == 0) smem[t >> 6] = v;
    __syncthreads();
    const float m = fmaxf(fmaxf(smem[0], smem[1]), fmaxf(smem[2], smem[3]));
    const float e = (t < S_) ? expf(x - m) : 0.f;
    float s = e;
    #pragma unroll
    for (int off = 32; off > 0; off >>= 1) s += __shfl_down(s, off);
    __syncthreads();
    if ((t & 63) == 0) smem[t >> 6] = s;
    __syncthreads();
    const float den = smem[0] + smem[1] + smem[2] + smem[3];
    const float av = e / den;
    float ts = av * dx;
    #pragma unroll
    for (int off = 32; off > 0; off >>= 1) ts += __shfl_down(ts, off);
    __syncthreads();
    if ((t & 63) == 0) smem[t >> 6] = ts;
    __syncthreads();
    const float tsum = smem[0] + smem[1] + smem[2] + smem[3];
    if (t < KP_) {
        pr[t]  = (t < S_) ? (short)f2bf(av) : (short)0;
        dpr[t] = (t < S_) ? (short)f2bf(av * (dx - tsum)) : (short)0;
    }
}

// ================= V transpose =================
__global__ __launch_bounds__(256) void vtrans_kernel(
    const short* __restrict__ qkvb, const short* __restrict__ dqkvb,
    short* __restrict__ Vt, short* __restrict__ dVt)
{
    const int blk = blockIdx.x;
    const int b = blk >> 2, kt = blk & 3;
    const int n = b / H_, h = b - n * H_;
    const short* vb  = qkvb  + (size_t)n * S_ * 2304 + 1536 + h * 64;
    const short* dvb = dqkvb + (size_t)n * S_ * 2304 + 1536 + h * 64;
    __shared__ short t1[64][65], t2[64][65];
    const int tid = threadIdx.x;
    #pragma unroll
    for (int j = 0; j < 16; ++j) {
        const int e = tid + 256 * j;
        const int kk = e >> 6, dh = e & 63;
        const int gk = kt * 64 + kk;
        short v = 0, dv = 0;
        if (gk < S_) { v = vb[(size_t)gk * 2304 + dh]; dv = dvb[(size_t)gk * 2304 + dh]; }
        t1[dh][kk] = v; t2[dh][kk] = dv;
    }
    __syncthreads();
    #pragma unroll
    for (int j = 0; j < 16; ++j) {
        const int e = tid + 256 * j;
        const int dh = e >> 6, kk = e & 63;
        const int ok = kt * 64 + kk;
        if (ok < KP_) {
            Vt [(size_t)b * 64 * KP_ + (size_t)dh * KP_ + ok] = t1[dh][kk];
            dVt[(size_t)b * 64 * KP_ + (size_t)dh * KP_ + ok] = t2[dh][kk];
        }
    }
}

// ================= fused PV JVP =================
__global__ __launch_bounds__(256) void attn_pv_kernel(
    const short* __restrict__ P, const short* __restrict__ dP,
    const short* __restrict__ Vt, const short* __restrict__ dVt,
    short* __restrict__ obf, short* __restrict__ dobf)
{
    const int bz = blockIdx.z;
    const int n = bz / H_, h = bz - n * H_;
    const short* Pb  = P   + (size_t)bz * S_ * KP_;
    const short* dPb = dP  + (size_t)bz * S_ * KP_;
    const short* Vb  = Vt  + (size_t)bz * 64 * KP_;
    const short* dVb = dVt + (size_t)bz * 64 * KP_;
    short* ob  = obf  + (size_t)n * S_ * D_ + h * 64;
    short* dob = dobf + (size_t)n * S_ * D_ + h * 64;

    __shared__ __align__(16) short lp[64*32], ldp[64*32], lv[64*32], ldv[64*32];
    const int tid = threadIdx.x, lane = tid & 63, w = tid >> 6;
    const int m0 = blockIdx.y * 64;
    const int wr = w >> 1, wc = w & 1;
    f32x4v aO[2][2] = {}, aDO[2][2] = {};

    const int r_in = lane >> 2;
    const int cdst = lane & 3;
    const int row  = w * 16 + r_in;
    const int csrc = cdst ^ ((row >> 1) & 3);
    const size_t pr = (size_t)min(m0 + row, S_ - 1) * KP_;
    const size_t vr = (size_t)row * KP_;

    for (int k0 = 0; k0 < KP_; k0 += 32) {
        GLOAD_LDS16(Pb  + pr + k0 + csrc * 8, &lp [w * 16 * 32]);
        GLOAD_LDS16(dPb + pr + k0 + csrc * 8, &ldp[w * 16 * 32]);
        GLOAD_LDS16(Vb  + vr + k0 + csrc * 8, &lv [w * 16 * 32]);
        GLOAD_LDS16(dVb + vr + k0 + csrc * 8, &ldv[w * 16 * 32]);
        __syncthreads();
        bf16x8v pf[2], dpf[2], vf[2], dvf[2];
        #pragma unroll
        for (int m = 0; m < 2; ++m) {
            const int rr = wr * 32 + m * 16 + (lane & 15);
            const int c = (lane >> 4) ^ ((rr >> 1) & 3);
            pf[m]  = *(const bf16x8v*)&lp [rr * 32 + c * 8];
            dpf[m] = *(const bf16x8v*)&ldp[rr * 32 + c * 8];
        }
        #pragma unroll
        for (int nn = 0; nn < 2; ++nn) {
            const int rr = wc * 32 + nn * 16 + (lane & 15);
            const int c = (lane >> 4) ^ ((rr >> 1) & 3);
            vf[nn]  = *(const bf16x8v*)&lv [rr * 32 + c * 8];
            dvf[nn] = *(const bf16x8v*)&ldv[rr * 32 + c * 8];
        }
        #pragma unroll
        for (int m = 0; m < 2; ++m)
            #pragma unroll
            for (int nn = 0; nn < 2; ++nn) {
                aO [m][nn] = __builtin_amdgcn_mfma_f32_16x16x32_bf16(pf[m],  vf[nn],  aO [m][nn], 0,0,0);
                aDO[m][nn] = __builtin_amdgcn_mfma_f32_16x16x32_bf16(dpf[m], vf[nn],  aDO[m][nn], 0,0,0);
                aDO[m][nn] = __builtin_amdgcn_mfma_f32_16x16x32_bf16(pf[m],  dvf[nn], aDO[m][nn], 0,0,0);
            }
        __syncthreads();
    }
    #pragma unroll
    for (int m = 0; m < 2; ++m) {
        const int rbase = m0 + wr * 32 + m * 16 + (lane >> 4) * 4;
        #pragma unroll
        for (int nn = 0; nn < 2; ++nn) {
            const int col = wc * 32 + nn * 16 + (lane & 15);
            #pragma unroll
            for (int r = 0; r < 4; ++r) {
                const int rw = rbase + r;
                if (rw < S_) {
                    ob [(size_t)rw * D_ + col] = (short)f2bf(aO [m][nn][r]);
                    dob[(size_t)rw * D_ + col] = (short)f2bf(aDO[m][nn][r]);
                }
            }
        }
    }
}

// ================= fp32 GEMM (head only) =================
template<bool BIAS>
__global__ __launch_bounds__(256) void gemm_kernel(
    const float* __restrict__ A, const float* __restrict__ Bm,
    const float* __restrict__ bias, float* __restrict__ C,
    int M, int N, int K, int lda, int ldb, int ldc)
{
    const int tile_m = blockIdx.y * 64, tile_n = blockIdx.x * 64;
    __shared__ float As[16][64];
    __shared__ float Bs[16][64];
    const int tid = threadIdx.x;
    const int tx = tid & 15, ty = tid >> 4;
    float acc[4][4] = {};
    for (int k0 = 0; k0 < K; k0 += 16) {
        {
            const int row = tid >> 2, kc = (tid & 3) * 4, gm = tile_m + row;
            #pragma unroll
            for (int i = 0; i < 4; ++i) {
                const int gk = k0 + kc + i;
                float v = 0.f;
                if (gm < M && gk < K) v = A[(long long)gm * lda + gk];
                As[kc + i][row] = v;
            }
        }
        {
            const int row = tid >> 2, kc = (tid & 3) * 4, gn = tile_n + row;
            #pragma unroll
            for (int i = 0; i < 4; ++i) {
                const int gk = k0 + kc + i;
                float v = 0.f;
                if (gn < N && gk < K) v = Bm[(long long)gn * ldb + gk];
                Bs[kc + i][row] = v;
            }
        }
        __syncthreads();
        #pragma unroll
        for (int kk = 0; kk < 16; ++kk) {
            float a[4], b[4];
            #pragma unroll
            for (int i = 0; i < 4; ++i) a[i] = As[kk][ty * 4 + i];
            #pragma unroll
            for (int j = 0; j < 4; ++j) b[j] = Bs[kk][tx * 4 + j];
            #pragma unroll
            for (int i = 0; i < 4; ++i)
                #pragma unroll
                for (int j = 0; j < 4; ++j)
                    acc[i][j] += a[i] * b[j];
        }
        __syncthreads();
    }
    #pragma unroll
    for (int i = 0; i < 4; ++i) {
        const int gm = tile_m + ty * 4 + i;
        if (gm >= M) continue;
        #pragma unroll
        for (int j = 0; j < 4; ++j) {
            const int gn = tile_n + tx * 4 + j;
            if (gn >= N) continue;
            float v = acc[i][j];
            if (BIAS) v += bias[gn];
            C[(long long)gm * ldc + gn] = v;
        }
    }
}

// ================= LayerNorm JVP =================
__device__ __forceinline__ float blk_sum4(float v, float* smem) {
    #pragma unroll
    for (int off = 32; off > 0; off >>= 1) v += __shfl_down(v, off);
    __syncthreads();
    if ((threadIdx.x & 63) == 0) smem[threadIdx.x >> 6] = v;
    __syncthreads();
    return smem[0] + smem[1] + smem[2] + smem[3];
}

template<bool WF32>
__global__ __launch_bounds__(256) void ln_jvp_kernel(
    const float* __restrict__ z, const float* __restrict__ dz,
    const float* __restrict__ g, const float* __restrict__ b,
    float* __restrict__ y, float* __restrict__ dy,
    short* __restrict__ ybf, short* __restrict__ dybf)
{
    const long long row = blockIdx.x;
    const float* xr  = z  + row * D_;
    const float* dxr = dz + row * D_;
    __shared__ float smem[4];
    const int t = threadIdx.x;
    float x[3], dx[3];
    #pragma unroll
    for (int i = 0; i < 3; ++i) { x[i] = xr[t + 256 * i]; dx[i] = dxr[t + 256 * i]; }
    float sx  = blk_sum4(x[0] + x[1] + x[2], smem);
    float sdx = blk_sum4(dx[0] + dx[1] + dx[2], smem);
    const float mu = sx / D_, dmu = sdx / D_;
    float sv = 0.f, sc = 0.f;
    #pragma unroll
    for (int i = 0; i < 3; ++i) {
        const float xc = x[i] - mu;
        sv += xc * xc;
        sc += xc * (dx[i] - dmu);
    }
    sv = blk_sum4(sv, smem);
    sc = blk_sum4(sc, smem);
    const float rstd = rsqrtf(sv / D_ + 1e-6f);
    const float k2   = (sc / D_) * rstd * rstd;
    #pragma unroll
    for (int i = 0; i < 3; ++i) {
        const int c = t + 256 * i;
        const float yh  = (x[i] - mu) * rstd;
        const float dyh = (dx[i] - dmu) * rstd - yh * k2;
        const float yv  = yh * g[c] + b[c];
        const float dyv = dyh * g[c];
        if (WF32) { y[row * D_ + c] = yv; dy[row * D_ + c] = dyv; }
        ybf[row * D_ + c]  = (short)f2bf(yv);
        dybf[row * D_ + c] = (short)f2bf(dyv);
    }
}

// ================= GELU JVP: fp32 in, bf16 out =================
__global__ __launch_bounds__(256) void gelu_jvp_kernel(
    const float* __restrict__ h, const float* __restrict__ dh,
    short* __restrict__ ho, short* __restrict__ dho, int n4)
{
    for (int i = blockIdx.x * blockDim.x + threadIdx.x; i < n4;
         i += gridDim.x * blockDim.x) {
        const float4 u4 = ((const float4*)h)[i];
        const float4 du4 = ((const float4*)dh)[i];
        short o[4], doo[4];
        const float us[4] = {u4.x, u4.y, u4.z, u4.w};
        const float dus[4] = {du4.x, du4.y, du4.z, du4.w};
        #pragma unroll
        for (int j = 0; j < 4; ++j) {
            const float u = us[j], du = dus[j];
            const float cdf = 0.5f * (1.0f + erff(u * 0.70710678118654752f));
            const float pdf = 0.3989422804014327f * expf(-0.5f * u * u);
            o[j]   = (short)f2bf(u * cdf);
            doo[j] = (short)f2bf(du * (cdf + u * pdf));
        }
        *(short4*)&ho[i * 4]  = *(short4*)o;
        *(short4*)&dho[i * 4] = *(short4*)doo;
    }
}

__global__ __launch_bounds__(256) void cast_bf16_kernel(
    const float* __restrict__ in, short* __restrict__ out, int n4)
{
    for (int i = blockIdx.x * blockDim.x + threadIdx.x; i < n4;
         i += gridDim.x * blockDim.x) {
        const float4 v = ((const float4*)in)[i];
        short o[4];
        o[0] = (short)f2bf(v.x); o[1] = (short)f2bf(v.y);
        o[2] = (short)f2bf(v.z); o[3] = (short)f2bf(v.w);
        *(short4*)&out[i * 4] = *(short4*)o;
    }
}

__global__ __launch_bounds__(256) void im2col_kernel(
    const float* __restrict__ x, short* __restrict__ xp, int total)
{
    for (int i = blockIdx.x * blockDim.x + threadIdx.x; i < total;
         i += gridDim.x * blockDim.x) {
        const int k  = i % 768;
        const int m  = i / 768;
        const int gh = m % GP_;
        const int n  = m / GP_;
        const int q  = k & 15;
        const int p  = (k >> 4) & 15;
        const int c  = k >> 8;
        const int hc = gh % 14, gr = gh / 14;
        const int ir = gr * 16 + p, ic = hc * 16 + q;
        xp[i] = (short)f2bf(x[(((long long)n * 3 + c) * 224 + ir) * 224 + ic]);
    }
}

__global__ __launch_bounds__(256) void assemble_kernel(
    const float* __restrict__ tok, const float* __restrict__ dtok,
    float* __restrict__ z, float* __restrict__ dz,
    const float* __restrict__ cls, const float* __restrict__ pos, int total)
{
    for (int i = blockIdx.x * blockDim.x + threadIdx.x; i < total;
         i += gridDim.x * blockDim.x) {
        const int d = i % D_;
        const int s = (i / D_) % S_;
        const int n = i / (D_ * S_);
        if (s == 0) {
            z[i]  = cls[d] + pos[d];
            dz[i] = 0.f;
        } else {
            const long long ti = ((long long)n * GP_ + s - 1) * D_ + d;
            z[i]  = tok[ti]  + pos[s * D_ + d];
            dz[i] = dtok[ti];
        }
    }
}

// ================= host helpers =================
static inline void mgemm(hipStream_t st, const short* A, const short* Bm, const float* bias,
                         void* C, int M, int N, int K, int ldc, int bias_rows,
                         bool acc, bool hasbias, bool outbf)
{
    dim3 grid(N / 128, (M + 127) / 128);
    dim3 blk(512);
#define MK(AC, BI, OB) mfma_gemm_kernel<AC, BI, OB><<<grid, blk, 0, st>>>(A, Bm, bias, C, M, N, K, ldc, bias_rows)
    if (outbf) { if (hasbias) MK(false, true, true); else MK(false, false, true); }
    else if (acc) { if (hasbias) MK(true, true, false);  else MK(true, false, false); }
    else     { if (hasbias) MK(false, true, false); else MK(false, false, false); }
#undef MK
}

static inline void cast_bf(hipStream_t st, const float* in, short* out, long long n) {
    const int n4 = (int)(n / 4);
    int g = (n4 + 255) / 256; if (g > 4096) g = 4096;
    cast_bf16_kernel<<<g, 256, 0, st>>>(in, out, n4);
}

extern "C" void kernel_launch(void* const* d_in, const int* in_sizes, int n_in,
                              void* d_out, int out_size, void* d_ws, size_t ws_size,
                              hipStream_t stream)
{
    const float* x       = (const float*)d_in[0];
    const float* tangent = (const float*)d_in[1];
    const float* conv_w  = (const float*)d_in[2];
    const float* conv_b  = (const float*)d_in[3];
    const float* cls     = (const float*)d_in[4];
    const float* pos     = (const float*)d_in[5];
    const float* ln1_g   = (const float*)d_in[6];
    const float* ln1_b   = (const float*)d_in[7];
    const float* qkv_w   = (const float*)d_in[8];
    const float* qkv_b   = (const float*)d_in[9];
    const float* out_w   = (const float*)d_in[10];
    const float* out_b   = (const float*)d_in[11];
    const float* ln2_g   = (const float*)d_in[12];
    const float* ln2_b   = (const float*)d_in[13];
    const float* fc1_w   = (const float*)d_in[14];
    const float* fc1_b   = (const float*)d_in[15];
    const float* fc2_w   = (const float*)d_in[16];
    const float* fc2_b   = (const float*)d_in[17];
    const float* lnf_g   = (const float*)d_in[18];
    const float* lnf_b   = (const float*)d_in[19];
    const float* head_w  = (const float*)d_in[20];
    const float* head_b  = (const float*)d_in[21];
    float* out = (float*)d_out;

    const int nBS = B_ * S_;                            // 6304
    const int NB = B_ * H_;                             // 384
    const long long SD = (long long)S_ * D_;
    const long long PZ = (long long)MP_ * D_;           // 4,915,200
    const long long PQ = (long long)MP_ * 2304;         // 14,745,600
    const long long PH = (long long)MP_ * MD_;          // 19,660,800
    const long long PTOK = (long long)B_ * GP_ * D_;    // 4,816,896

    // ---- fp32 region ----
    float* f = (float*)d_ws;
    float* z     = f;             // [6400][768]
    float* dz    = z + PZ;
    float* hbuf  = dz + PZ;       // [6400][3072] fwd; aliases: S, tok, final y
    float* dhbuf = hbuf + PH;
    float* Sb    = hbuf;
    float* dSb   = dhbuf;
    float* tok   = hbuf;
    float* dtok  = hbuf + PTOK;
    float* yf    = hbuf;
    float* dyf   = dhbuf;

    // ---- bf16 region ----
    short* sh     = (short*)(dhbuf + PH);
    short* ybf    = sh;                       // [2*6400][768]
    short* dybf   = ybf + PZ;
    short* qkvbf  = dybf + PZ;                // [2*6400][2304]
    short* dqkvbf = qkvbf + PQ;
    short* Vt     = dqkvbf + PQ;              // [384][64][224] x2
    short* dVt    = Vt + (long long)NB * 64 * KP_;
    short* hbf    = dVt + (long long)NB * 64 * KP_;   // [2*6400][3072]
    short* dhbf   = hbf + PH;
    short* Pbf    = hbf;   short* dPbf = dhbf;
    short* xpbf   = hbf;
    short* dxpbf  = xpbf + PTOK;
    short* wq     = dhbf + PH;
    short* wo     = wq + 2304 * 768;
    short* w1     = wo + 768 * 768;
    short* w2     = w1 + 3072 * 768;
    short* cwbf   = w2 + 768 * 3072;

    // ---- patch embedding (fused GEMM, M = 2*6272) ----
    {
        const int total = (int)PTOK;
        im2col_kernel<<<8192, 256, 0, stream>>>(x, xpbf, total);
        im2col_kernel<<<8192, 256, 0, stream>>>(tangent, dxpbf, total);
        cast_bf(stream, conv_w, cwbf, 768 * 768);
        mgemm(stream, xpbf, cwbf, conv_b, tok, 2 * B_ * GP_, D_, D_, D_,
              B_ * GP_, false, true, false);
        const int tz = (int)(B_ * SD);
        assemble_kernel<<<8192, 256, 0, stream>>>(tok, dtok, z, dz, cls, pos, tz);
    }

    for (int l = 0; l < L_; ++l) {
        const float* l1g = ln1_g + (long long)l * D_;
        const float* l1b = ln1_b + (long long)l * D_;
        const float* qb  = qkv_b + (long long)l * 3 * D_;
        const float* ob  = out_b + (long long)l * D_;
        const float* l2g = ln2_g + (long long)l * D_;
        const float* l2b = ln2_b + (long long)l * D_;
        const float* f1b = fc1_b + (long long)l * MD_;
        const float* f2b = fc2_b + (long long)l * D_;

        cast_bf(stream, qkv_w + (long long)l * 3 * D_ * D_, wq, (long long)3 * D_ * D_);
        cast_bf(stream, out_w + (long long)l * D_ * D_,     wo, (long long)D_ * D_);
        cast_bf(stream, fc1_w + (long long)l * MD_ * D_,    w1, (long long)MD_ * D_);
        cast_bf(stream, fc2_w + (long long)l * D_ * MD_,    w2, (long long)D_ * MD_);

        // LN1
        ln_jvp_kernel<false><<<nBS, 256, 0, stream>>>(z, dz, l1g, l1b, nullptr, nullptr, ybf, dybf);
        // QKV fwd+tan fused (bias only on fwd half)
        mgemm(stream, ybf, wq, qb, qkvbf, 2 * MP_, 3 * D_, D_, 3 * D_, MP_, false, true, true);

        // attention
        attn_scores_kernel<<<dim3(4, 4, NB), 256, 0, stream>>>(qkvbf, dqkvbf, Sb, dSb);
        vtrans_kernel<<<NB * 4, 256, 0, stream>>>(qkvbf, dqkvbf, Vt, dVt);
        softmax_pjvp_kernel<<<NB * S_, 256, 0, stream>>>(Sb, dSb, Pbf, dPbf);
        attn_pv_kernel<<<dim3(1, 4, NB), 256, 0, stream>>>(Pbf, dPbf, Vt, dVt, ybf, dybf);

        // projection + residual (ACC into z‖dz)
        mgemm(stream, ybf, wo, ob, z, 2 * MP_, D_, D_, D_, MP_, true, true, false);

        // LN2 + MLP
        ln_jvp_kernel<false><<<nBS, 256, 0, stream>>>(z, dz, l2g, l2b, nullptr, nullptr, ybf, dybf);
        mgemm(stream, ybf, w1, f1b, hbuf, 2 * MP_, MD_, D_, MD_, MP_, false, true, false);
        gelu_jvp_kernel<<<4096, 256, 0, stream>>>(hbuf, dhbuf, hbf, dhbf, (int)(PH / 4));
        mgemm(stream, hbf, w2, f2b, z, 2 * MP_, D_, MD_, D_, MP_, true, true, false);
    }

    // final LN (fp32 out) + head
    ln_jvp_kernel<true><<<nBS, 256, 0, stream>>>(z, dz, lnf_g, lnf_b, yf, dyf, ybf, dybf);
    gemm_kernel<true><<<dim3((NC_ + 63) / 64, 1), 256, 0, stream>>>(
        yf,  head_w, head_b, out,            B_, NC_, D_, (int)SD, D_, NC_);
    gemm_kernel<false><<<dim3((NC_ + 63) / 64, 1), 256, 0, stream>>>(
        dyf, head_w, nullptr, out + B_ * NC_, B_, NC_, D_, (int)SD, D_, NC_);
}

// Round 6
// 5706.752 us; speedup vs baseline: 12.7030x; 1.3113x over previous
//
// ViT-Base/16 fwd + JVP — Round 5: fully fused attention JVP kernel
// (scores + softmax-JVP + PV in one launch, S/P never hit global memory).
// Dense GEMMs as R4 (8-wave 128x128 MFMA).
#include <hip/hip_runtime.h>
#include <math.h>

static constexpr int B_   = 32;
static constexpr int S_   = 197;
static constexpr int D_   = 768;
static constexpr int H_   = 12;
static constexpr int L_   = 12;
static constexpr int MD_  = 3072;
static constexpr int NC_  = 1000;
static constexpr int GP_  = 196;
static constexpr int KP_  = 224;   // padded attention-K (7*32)
static constexpr int MP_  = 6400;  // padded row count (50*128)

typedef __attribute__((ext_vector_type(8))) short bf16x8v;
typedef __attribute__((ext_vector_type(4))) float f32x4v;

__device__ __forceinline__ unsigned short f2bf(float x) {
    union { float f; unsigned u; } v; v.f = x;
    unsigned r = v.u + 0x7fffu + ((v.u >> 16) & 1u);   // RNE
    return (unsigned short)(r >> 16);
}

#define GLOAD_LDS16(gptr, lptr) \
    __builtin_amdgcn_global_load_lds((const __attribute__((address_space(1))) void*)(gptr), \
        (__attribute__((address_space(3))) void*)(lptr), 16, 0, 0)

// ================= dense MFMA GEMM (128x128 tile, 8 waves) =================
template<bool ACC, bool BIAS, bool OUTBF>
__global__ __launch_bounds__(512, 4) void mfma_gemm_kernel(
    const short* __restrict__ A, const short* __restrict__ Bm,
    const float* __restrict__ bias, void* __restrict__ Cv,
    int M, int N, int K, int ldc, int bias_rows)
{
    int bx, by;
    {
        const int gx = gridDim.x, nwg = gx * gridDim.y;
        const int flat = blockIdx.y * gx + blockIdx.x;
        const int q = nwg >> 3, r = nwg & 7;
        const int xcd = flat & 7, idx = flat >> 3;
        const int nf = (xcd < r ? xcd * (q + 1) : r * (q + 1) + (xcd - r) * q) + idx;
        bx = nf % gx; by = nf / gx;
    }
    __shared__ __align__(16) short ldsA[128 * 32];
    __shared__ __align__(16) short ldsB[128 * 32];
    const int tid  = threadIdx.x;
    const int lane = tid & 63;
    const int w    = tid >> 6;
    const int m0 = by * 128, n0 = bx * 128;
    const int wr = w >> 1, wc = w & 1;
    f32x4v acc[2][4] = {};

    const int r_in = lane >> 2;
    const int cdst = lane & 3;
    const int srow = w * 16 + r_in;
    const int csrc = cdst ^ ((srow >> 1) & 3);
    const size_t aoff = (size_t)(m0 + srow) * K + csrc * 8;
    const size_t boff = (size_t)(n0 + srow) * K + csrc * 8;

    for (int k0 = 0; k0 < K; k0 += 32) {
        GLOAD_LDS16(A  + aoff + k0, &ldsA[w * 16 * 32]);
        GLOAD_LDS16(Bm + boff + k0, &ldsB[w * 16 * 32]);
        __syncthreads();
        bf16x8v af[2], bfr[4];
        #pragma unroll
        for (int m = 0; m < 2; ++m) {
            const int row = wr * 32 + m * 16 + (lane & 15);
            const int c = (lane >> 4) ^ ((row >> 1) & 3);
            af[m] = *(const bf16x8v*)&ldsA[row * 32 + c * 8];
        }
        #pragma unroll
        for (int n = 0; n < 4; ++n) {
            const int row = wc * 64 + n * 16 + (lane & 15);
            const int c = (lane >> 4) ^ ((row >> 1) & 3);
            bfr[n] = *(const bf16x8v*)&ldsB[row * 32 + c * 8];
        }
        #pragma unroll
        for (int m = 0; m < 2; ++m)
            #pragma unroll
            for (int n = 0; n < 4; ++n)
                acc[m][n] = __builtin_amdgcn_mfma_f32_16x16x32_bf16(af[m], bfr[n], acc[m][n], 0, 0, 0);
        __syncthreads();
    }
    const int col_base = n0 + wc * 64 + (lane & 15);
    const int row_base = m0 + wr * 32 + (lane >> 4) * 4;
    #pragma unroll
    for (int n = 0; n < 4; ++n) {
        const int col = col_base + n * 16;
        const float bv = BIAS ? bias[col] : 0.f;
        #pragma unroll
        for (int m = 0; m < 2; ++m) {
            const int row = row_base + m * 16;
            const float bvr = (BIAS && row < bias_rows) ? bv : 0.f;
            #pragma unroll
            for (int r = 0; r < 4; ++r) {
                if (row + r < M) {
                    const size_t off = (size_t)(row + r) * ldc + col;
                    const float v = acc[m][n][r] + bvr;
                    if (OUTBF) ((short*)Cv)[off] = (short)f2bf(v);
                    else if (ACC) ((float*)Cv)[off] += v;
                    else ((float*)Cv)[off] = v;
                }
            }
        }
    }
}

// ================= fully fused attention JVP =================
// Block = (qtile 0..3, head b 0..383); 4 waves; wave owns 16 q-rows x full 224 k.
// Phase1: S/dS via MFMA into regs. Softmax JVP in regs (k on lane&15 + frag).
// P/dP -> wave-local swizzled LDS. Phase2: PV via MFMA with Vt staged per ktile.
__global__ __launch_bounds__(256) void attn_fused_kernel(
    const short* __restrict__ qkvb, const short* __restrict__ dqkvb,
    const short* __restrict__ Vtb_, const short* __restrict__ dVtb_,
    short* __restrict__ obf, short* __restrict__ dobf)
{
    const int qt = blockIdx.x;
    const int b  = blockIdx.y;
    const int n = b / H_, h = b - n * H_;
    const short* qb  = qkvb  + (size_t)n * S_ * 2304 + h * 64;
    const short* kb  = qb + 768;
    const short* dqb = dqkvb + (size_t)n * S_ * 2304 + h * 64;
    const short* dkb = dqb + 768;
    const short* Vb  = Vtb_  + (size_t)b * 64 * KP_;
    const short* dVb = dVtb_ + (size_t)b * 64 * KP_;

    // LDS union (shorts): phase1: lq[w]=w*1024(x2 kwin x512), ldq=4096+, lk=8192 (2x1024), ldk=10240
    //                     phase2: lp[w]=w*3584 (7x512), ldp=14336+, lv=28672, ldv=30720
    __shared__ __align__(16) short lds[32768];
    const int tid = threadIdx.x, lane = tid & 63, w = tid >> 6;
    const int g = lane >> 4, kc = lane & 15;
    const int srow = lane >> 2, cdst = lane & 3;
    const int csrc = cdst ^ ((srow >> 1) & 3);

    // ---- stage Q/dQ (wave-local [2 kwin][16][32]) ----
    {
        const size_t qr = (size_t)min(qt * 64 + w * 16 + srow, S_ - 1) * 2304;
        #pragma unroll
        for (int kw = 0; kw < 2; ++kw) {
            GLOAD_LDS16(qb  + qr + kw * 32 + csrc * 8, &lds[w * 1024 + kw * 512]);
            GLOAD_LDS16(dqb + qr + kw * 32 + csrc * 8, &lds[4096 + w * 1024 + kw * 512]);
        }
    }

    f32x4v aS[14], aD[14];
    #pragma unroll
    for (int i = 0; i < 14; ++i) { aS[i] = (f32x4v){0,0,0,0}; aD[i] = (f32x4v){0,0,0,0}; }
    bf16x8v qf[2], dqf[2];

    #pragma unroll
    for (int kt = 0; kt < 7; ++kt) {
        // stage K/dK [2 kwin][32][32]: waves 0,1 -> K; waves 2,3 -> dK
        {
            const int kwin = w & 1;
            const short* src = (w < 2) ? kb : dkb;
            const int base = (w < 2) ? 8192 : 10240;
            #pragma unroll
            for (int half = 0; half < 2; ++half) {
                const size_t kr = (size_t)min(kt * 32 + half * 16 + srow, S_ - 1) * 2304;
                GLOAD_LDS16(src + kr + kwin * 32 + csrc * 8,
                            &lds[base + kwin * 1024 + half * 512]);
            }
        }
        __syncthreads();
        if (kt == 0) {
            #pragma unroll
            for (int kw = 0; kw < 2; ++kw) {
                const int c = g ^ ((kc >> 1) & 3);
                qf[kw]  = *(const bf16x8v*)&lds[w * 1024 + kw * 512 + kc * 32 + c * 8];
                dqf[kw] = *(const bf16x8v*)&lds[4096 + w * 1024 + kw * 512 + kc * 32 + c * 8];
            }
        }
        #pragma unroll
        for (int nf = 0; nf < 2; ++nf) {
            const int row = nf * 16 + kc;
            const int c = g ^ ((row >> 1) & 3);
            const bf16x8v kf0  = *(const bf16x8v*)&lds[8192  + row * 32 + c * 8];
            const bf16x8v kf1  = *(const bf16x8v*)&lds[8192  + 1024 + row * 32 + c * 8];
            const bf16x8v dkf0 = *(const bf16x8v*)&lds[10240 + row * 32 + c * 8];
            const bf16x8v dkf1 = *(const bf16x8v*)&lds[10240 + 1024 + row * 32 + c * 8];
            const int fi = kt * 2 + nf;
            aS[fi] = __builtin_amdgcn_mfma_f32_16x16x32_bf16(qf[0], kf0, aS[fi], 0,0,0);
            aS[fi] = __builtin_amdgcn_mfma_f32_16x16x32_bf16(qf[1], kf1, aS[fi], 0,0,0);
            aD[fi] = __builtin_amdgcn_mfma_f32_16x16x32_bf16(dqf[0], kf0, aD[fi], 0,0,0);
            aD[fi] = __builtin_amdgcn_mfma_f32_16x16x32_bf16(dqf[1], kf1, aD[fi], 0,0,0);
            aD[fi] = __builtin_amdgcn_mfma_f32_16x16x32_bf16(qf[0], dkf0, aD[fi], 0,0,0);
            aD[fi] = __builtin_amdgcn_mfma_f32_16x16x32_bf16(qf[1], dkf1, aD[fi], 0,0,0);
        }
        __syncthreads();
    }

    // ---- softmax JVP in registers (per lane: 4 q-rows x k = fi*16 + kc) ----
    float pm[4] = {-3.0e38f, -3.0e38f, -3.0e38f, -3.0e38f};
    #pragma unroll
    for (int fi = 0; fi < 14; ++fi) {
        if (fi * 16 + kc < S_) {
            #pragma unroll
            for (int r = 0; r < 4; ++r) pm[r] = fmaxf(pm[r], aS[fi][r]);
        }
    }
    #pragma unroll
    for (int off = 1; off < 16; off <<= 1)
        #pragma unroll
        for (int r = 0; r < 4; ++r) pm[r] = fmaxf(pm[r], __shfl_xor(pm[r], off));

    float den[4] = {0,0,0,0}, tsm[4] = {0,0,0,0};
    #pragma unroll
    for (int fi = 0; fi < 14; ++fi) {
        const bool val = fi * 16 + kc < S_;
        #pragma unroll
        for (int r = 0; r < 4; ++r) {
            const float s  = aS[fi][r] * 0.125f;
            const float ds = aD[fi][r] * 0.125f;
            const float e = val ? expf(s - pm[r] * 0.125f) : 0.f;
            den[r] += e; tsm[r] += e * ds;
            aS[fi][r] = e; aD[fi][r] = ds;
        }
    }
    #pragma unroll
    for (int off = 1; off < 16; off <<= 1)
        #pragma unroll
        for (int r = 0; r < 4; ++r) {
            den[r] += __shfl_xor(den[r], off);
            tsm[r] += __shfl_xor(tsm[r], off);
        }
    float inv[4], tq[4];
    #pragma unroll
    for (int r = 0; r < 4; ++r) { inv[r] = 1.f / den[r]; tq[r] = tsm[r] * inv[r]; }

    // ---- P/dP -> wave-local swizzled LDS [7 kwin][16][32] ----
    const int lpw = w * 3584, ldpw = 14336 + w * 3584;
    #pragma unroll
    for (int fi = 0; fi < 14; ++fi) {
        const int kwin = fi >> 1;
        const int chunkbase = (fi & 1) * 2 + (kc >> 3);
        #pragma unroll
        for (int r = 0; r < 4; ++r) {
            const int qs = g * 4 + r;
            const int swz = chunkbase ^ ((qs >> 1) & 3);
            const int addr = kwin * 512 + qs * 32 + swz * 8 + (kc & 7);
            const float p  = aS[fi][r] * inv[r];
            const float dp = p * (aD[fi][r] - tq[r]);
            lds[lpw  + addr] = (short)f2bf(p);
            lds[ldpw + addr] = (short)f2bf(dp);
        }
    }

    // ---- phase 2: PV ----
    f32x4v aO[4], aDO[4];
    #pragma unroll
    for (int i = 0; i < 4; ++i) { aO[i] = (f32x4v){0,0,0,0}; aDO[i] = (f32x4v){0,0,0,0}; }

    #pragma unroll
    for (int kt = 0; kt < 7; ++kt) {
        // stage Vt/dVt [64][32]: wave w stages rows w*16..+16 of each
        {
            const size_t vr = (size_t)(w * 16 + srow) * KP_ + kt * 32 + csrc * 8;
            GLOAD_LDS16(Vb  + vr, &lds[28672 + w * 512]);
            GLOAD_LDS16(dVb + vr, &lds[30720 + w * 512]);
        }
        __syncthreads();
        bf16x8v pa, dpa;
        {
            const int c = g ^ ((kc >> 1) & 3);
            pa  = *(const bf16x8v*)&lds[lpw  + kt * 512 + kc * 32 + c * 8];
            dpa = *(const bf16x8v*)&lds[ldpw + kt * 512 + kc * 32 + c * 8];
        }
        #pragma unroll
        for (int nf = 0; nf < 4; ++nf) {
            const int row = nf * 16 + kc;
            const int c = (g) ^ ((row >> 1) & 3);
            const bf16x8v vf  = *(const bf16x8v*)&lds[28672 + row * 32 + c * 8];
            const bf16x8v dvf = *(const bf16x8v*)&lds[30720 + row * 32 + c * 8];
            aO[nf]  = __builtin_amdgcn_mfma_f32_16x16x32_bf16(pa,  vf,  aO[nf], 0,0,0);
            aDO[nf] = __builtin_amdgcn_mfma_f32_16x16x32_bf16(dpa, vf,  aDO[nf], 0,0,0);
            aDO[nf] = __builtin_amdgcn_mfma_f32_16x16x32_bf16(pa,  dvf, aDO[nf], 0,0,0);
        }
        __syncthreads();
    }

    // ---- epilogue: o/do bf16 into proj A-operands ----
    short* ob  = obf  + (size_t)n * S_ * D_ + h * 64;
    short* dob = dobf + (size_t)n * S_ * D_ + h * 64;
    #pragma unroll
    for (int nf = 0; nf < 4; ++nf) {
        const int dh = nf * 16 + kc;
        #pragma unroll
        for (int r = 0; r < 4; ++r) {
            const int q = qt * 64 + w * 16 + g * 4 + r;
            if (q < S_) {
                ob [(size_t)q * D_ + dh] = (short)f2bf(aO[nf][r]);
                dob[(size_t)q * D_ + dh] = (short)f2bf(aDO[nf][r]);
            }
        }
    }
}

// ================= V transpose =================
__global__ __launch_bounds__(256) void vtrans_kernel(
    const short* __restrict__ qkvb, const short* __restrict__ dqkvb,
    short* __restrict__ Vt, short* __restrict__ dVt)
{
    const int blk = blockIdx.x;
    const int b = blk >> 2, kt = blk & 3;
    const int n = b / H_, h = b - n * H_;
    const short* vb  = qkvb  + (size_t)n * S_ * 2304 + 1536 + h * 64;
    const short* dvb = dqkvb + (size_t)n * S_ * 2304 + 1536 + h * 64;
    __shared__ short t1[64][65], t2[64][65];
    const int tid = threadIdx.x;
    #pragma unroll
    for (int j = 0; j < 16; ++j) {
        const int e = tid + 256 * j;
        const int kk = e >> 6, dh = e & 63;
        const int gk = kt * 64 + kk;
        short v = 0, dv = 0;
        if (gk < S_) { v = vb[(size_t)gk * 2304 + dh]; dv = dvb[(size_t)gk * 2304 + dh]; }
        t1[dh][kk] = v; t2[dh][kk] = dv;
    }
    __syncthreads();
    #pragma unroll
    for (int j = 0; j < 16; ++j) {
        const int e = tid + 256 * j;
        const int dh = e >> 6, kk = e & 63;
        const int ok = kt * 64 + kk;
        if (ok < KP_) {
            Vt [(size_t)b * 64 * KP_ + (size_t)dh * KP_ + ok] = t1[dh][kk];
            dVt[(size_t)b * 64 * KP_ + (size_t)dh * KP_ + ok] = t2[dh][kk];
        }
    }
}

// ================= fp32 GEMM (head only) =================
template<bool BIAS>
__global__ __launch_bounds__(256) void gemm_kernel(
    const float* __restrict__ A, const float* __restrict__ Bm,
    const float* __restrict__ bias, float* __restrict__ C,
    int M, int N, int K, int lda, int ldb, int ldc)
{
    const int tile_m = blockIdx.y * 64, tile_n = blockIdx.x * 64;
    __shared__ float As[16][64];
    __shared__ float Bs[16][64];
    const int tid = threadIdx.x;
    const int tx = tid & 15, ty = tid >> 4;
    float acc[4][4] = {};
    for (int k0 = 0; k0 < K; k0 += 16) {
        {
            const int row = tid >> 2, kc = (tid & 3) * 4, gm = tile_m + row;
            #pragma unroll
            for (int i = 0; i < 4; ++i) {
                const int gk = k0 + kc + i;
                float v = 0.f;
                if (gm < M && gk < K) v = A[(long long)gm * lda + gk];
                As[kc + i][row] = v;
            }
        }
        {
            const int row = tid >> 2, kc = (tid & 3) * 4, gn = tile_n + row;
            #pragma unroll
            for (int i = 0; i < 4; ++i) {
                const int gk = k0 + kc + i;
                float v = 0.f;
                if (gn < N && gk < K) v = Bm[(long long)gn * ldb + gk];
                Bs[kc + i][row] = v;
            }
        }
        __syncthreads();
        #pragma unroll
        for (int kk = 0; kk < 16; ++kk) {
            float a[4], bb[4];
            #pragma unroll
            for (int i = 0; i < 4; ++i) a[i] = As[kk][ty * 4 + i];
            #pragma unroll
            for (int j = 0; j < 4; ++j) bb[j] = Bs[kk][tx * 4 + j];
            #pragma unroll
            for (int i = 0; i < 4; ++i)
                #pragma unroll
                for (int j = 0; j < 4; ++j)
                    acc[i][j] += a[i] * bb[j];
        }
        __syncthreads();
    }
    #pragma unroll
    for (int i = 0; i < 4; ++i) {
        const int gm = tile_m + ty * 4 + i;
        if (gm >= M) continue;
        #pragma unroll
        for (int j = 0; j < 4; ++j) {
            const int gn = tile_n + tx * 4 + j;
            if (gn >= N) continue;
            float v = acc[i][j];
            if (BIAS) v += bias[gn];
            C[(long long)gm * ldc + gn] = v;
        }
    }
}

// ================= LayerNorm JVP =================
__device__ __forceinline__ float blk_sum4(float v, float* smem) {
    #pragma unroll
    for (int off = 32; off > 0; off >>= 1) v += __shfl_down(v, off);
    __syncthreads();
    if ((threadIdx.x & 63) == 0) smem[threadIdx.x >> 6] = v;
    __syncthreads();
    return smem[0] + smem[1] + smem[2] + smem[3];
}

template<bool WF32>
__global__ __launch_bounds__(256) void ln_jvp_kernel(
    const float* __restrict__ z, const float* __restrict__ dz,
    const float* __restrict__ g, const float* __restrict__ b,
    float* __restrict__ y, float* __restrict__ dy,
    short* __restrict__ ybf, short* __restrict__ dybf)
{
    const long long row = blockIdx.x;
    const float* xr  = z  + row * D_;
    const float* dxr = dz + row * D_;
    __shared__ float smem[4];
    const int t = threadIdx.x;
    float x[3], dx[3];
    #pragma unroll
    for (int i = 0; i < 3; ++i) { x[i] = xr[t + 256 * i]; dx[i] = dxr[t + 256 * i]; }
    float sx  = blk_sum4(x[0] + x[1] + x[2], smem);
    float sdx = blk_sum4(dx[0] + dx[1] + dx[2], smem);
    const float mu = sx / D_, dmu = sdx / D_;
    float sv = 0.f, sc = 0.f;
    #pragma unroll
    for (int i = 0; i < 3; ++i) {
        const float xc = x[i] - mu;
        sv += xc * xc;
        sc += xc * (dx[i] - dmu);
    }
    sv = blk_sum4(sv, smem);
    sc = blk_sum4(sc, smem);
    const float rstd = rsqrtf(sv / D_ + 1e-6f);
    const float k2   = (sc / D_) * rstd * rstd;
    #pragma unroll
    for (int i = 0; i < 3; ++i) {
        const int c = t + 256 * i;
        const float yh  = (x[i] - mu) * rstd;
        const float dyh = (dx[i] - dmu) * rstd - yh * k2;
        const float yv  = yh * g[c] + b[c];
        const float dyv = dyh * g[c];
        if (WF32) { y[row * D_ + c] = yv; dy[row * D_ + c] = dyv; }
        ybf[row * D_ + c]  = (short)f2bf(yv);
        dybf[row * D_ + c] = (short)f2bf(dyv);
    }
}

// ================= GELU JVP: fp32 in, bf16 out =================
__global__ __launch_bounds__(256) void gelu_jvp_kernel(
    const float* __restrict__ h, const float* __restrict__ dh,
    short* __restrict__ ho, short* __restrict__ dho, int n4)
{
    for (int i = blockIdx.x * blockDim.x + threadIdx.x; i < n4;
         i += gridDim.x * blockDim.x) {
        const float4 u4 = ((const float4*)h)[i];
        const float4 du4 = ((const float4*)dh)[i];
        short o[4], doo[4];
        const float us[4] = {u4.x, u4.y, u4.z, u4.w};
        const float dus[4] = {du4.x, du4.y, du4.z, du4.w};
        #pragma unroll
        for (int j = 0; j < 4; ++j) {
            const float u = us[j], du = dus[j];
            const float cdf = 0.5f * (1.0f + erff(u * 0.70710678118654752f));
            const float pdf = 0.3989422804014327f * expf(-0.5f * u * u);
            o[j]   = (short)f2bf(u * cdf);
            doo[j] = (short)f2bf(du * (cdf + u * pdf));
        }
        *(short4*)&ho[i * 4]  = *(short4*)o;
        *(short4*)&dho[i * 4] = *(short4*)doo;
    }
}

__global__ __launch_bounds__(256) void cast_bf16_kernel(
    const float* __restrict__ in, short* __restrict__ out, int n4)
{
    for (int i = blockIdx.x * blockDim.x + threadIdx.x; i < n4;
         i += gridDim.x * blockDim.x) {
        const float4 v = ((const float4*)in)[i];
        short o[4];
        o[0] = (short)f2bf(v.x); o[1] = (short)f2bf(v.y);
        o[2] = (short)f2bf(v.z); o[3] = (short)f2bf(v.w);
        *(short4*)&out[i * 4] = *(short4*)o;
    }
}

__global__ __launch_bounds__(256) void im2col_kernel(
    const float* __restrict__ x, short* __restrict__ xp, int total)
{
    for (int i = blockIdx.x * blockDim.x + threadIdx.x; i < total;
         i += gridDim.x * blockDim.x) {
        const int k  = i % 768;
        const int m  = i / 768;
        const int gh = m % GP_;
        const int n  = m / GP_;
        const int q  = k & 15;
        const int p  = (k >> 4) & 15;
        const int c  = k >> 8;
        const int hc = gh % 14, gr = gh / 14;
        const int ir = gr * 16 + p, ic = hc * 16 + q;
        xp[i] = (short)f2bf(x[(((long long)n * 3 + c) * 224 + ir) * 224 + ic]);
    }
}

__global__ __launch_bounds__(256) void assemble_kernel(
    const float* __restrict__ tok, const float* __restrict__ dtok,
    float* __restrict__ z, float* __restrict__ dz,
    const float* __restrict__ cls, const float* __restrict__ pos, int total)
{
    for (int i = blockIdx.x * blockDim.x + threadIdx.x; i < total;
         i += gridDim.x * blockDim.x) {
        const int d = i % D_;
        const int s = (i / D_) % S_;
        const int n = i / (D_ * S_);
        if (s == 0) {
            z[i]  = cls[d] + pos[d];
            dz[i] = 0.f;
        } else {
            const long long ti = ((long long)n * GP_ + s - 1) * D_ + d;
            z[i]  = tok[ti]  + pos[s * D_ + d];
            dz[i] = dtok[ti];
        }
    }
}

// ================= host helpers =================
static inline void mgemm(hipStream_t st, const short* A, const short* Bm, const float* bias,
                         void* C, int M, int N, int K, int ldc, int bias_rows,
                         bool acc, bool hasbias, bool outbf)
{
    dim3 grid(N / 128, (M + 127) / 128);
    dim3 blk(512);
#define MK(AC, BI, OB) mfma_gemm_kernel<AC, BI, OB><<<grid, blk, 0, st>>>(A, Bm, bias, C, M, N, K, ldc, bias_rows)
    if (outbf) { if (hasbias) MK(false, true, true); else MK(false, false, true); }
    else if (acc) { if (hasbias) MK(true, true, false);  else MK(true, false, false); }
    else     { if (hasbias) MK(false, true, false); else MK(false, false, false); }
#undef MK
}

static inline void cast_bf(hipStream_t st, const float* in, short* out, long long n) {
    const int n4 = (int)(n / 4);
    int g = (n4 + 255) / 256; if (g > 4096) g = 4096;
    cast_bf16_kernel<<<g, 256, 0, st>>>(in, out, n4);
}

extern "C" void kernel_launch(void* const* d_in, const int* in_sizes, int n_in,
                              void* d_out, int out_size, void* d_ws, size_t ws_size,
                              hipStream_t stream)
{
    const float* x       = (const float*)d_in[0];
    const float* tangent = (const float*)d_in[1];
    const float* conv_w  = (const float*)d_in[2];
    const float* conv_b  = (const float*)d_in[3];
    const float* cls     = (const float*)d_in[4];
    const float* pos     = (const float*)d_in[5];
    const float* ln1_g   = (const float*)d_in[6];
    const float* ln1_b   = (const float*)d_in[7];
    const float* qkv_w   = (const float*)d_in[8];
    const float* qkv_b   = (const float*)d_in[9];
    const float* out_w   = (const float*)d_in[10];
    const float* out_b   = (const float*)d_in[11];
    const float* ln2_g   = (const float*)d_in[12];
    const float* ln2_b   = (const float*)d_in[13];
    const float* fc1_w   = (const float*)d_in[14];
    const float* fc1_b   = (const float*)d_in[15];
    const float* fc2_w   = (const float*)d_in[16];
    const float* fc2_b   = (const float*)d_in[17];
    const float* lnf_g   = (const float*)d_in[18];
    const float* lnf_b   = (const float*)d_in[19];
    const float* head_w  = (const float*)d_in[20];
    const float* head_b  = (const float*)d_in[21];
    float* out = (float*)d_out;

    const int nBS = B_ * S_;                            // 6304
    const int NB = B_ * H_;                             // 384
    const long long SD = (long long)S_ * D_;
    const long long PZ = (long long)MP_ * D_;           // 4,915,200
    const long long PQ = (long long)MP_ * 2304;         // 14,745,600
    const long long PH = (long long)MP_ * MD_;          // 19,660,800
    const long long PTOK = (long long)B_ * GP_ * D_;    // 4,816,896

    // ---- fp32 region ----
    float* f = (float*)d_ws;
    float* z     = f;             // [6400][768]
    float* dz    = z + PZ;
    float* hbuf  = dz + PZ;       // [6400][3072] fwd; aliases tok, final y
    float* dhbuf = hbuf + PH;
    float* tok   = hbuf;
    float* dtok  = hbuf + PTOK;
    float* yf    = hbuf;
    float* dyf   = dhbuf;

    // ---- bf16 region ----
    short* sh     = (short*)(dhbuf + PH);
    short* ybf    = sh;                       // [2*6400][768]
    short* dybf   = ybf + PZ;
    short* qkvbf  = dybf + PZ;                // [2*6400][2304]
    short* dqkvbf = qkvbf + PQ;
    short* Vt     = dqkvbf + PQ;              // [384][64][224] x2
    short* dVt    = Vt + (long long)NB * 64 * KP_;
    short* hbf    = dVt + (long long)NB * 64 * KP_;   // [2*6400][3072]
    short* dhbf   = hbf + PH;
    short* xpbf   = hbf;
    short* dxpbf  = xpbf + PTOK;
    short* wq     = dhbf + PH;
    short* wo     = wq + 2304 * 768;
    short* w1     = wo + 768 * 768;
    short* w2     = w1 + 3072 * 768;
    short* cwbf   = w2 + 768 * 3072;

    // ---- patch embedding (fused GEMM, M = 2*6272) ----
    {
        const int total = (int)PTOK;
        im2col_kernel<<<8192, 256, 0, stream>>>(x, xpbf, total);
        im2col_kernel<<<8192, 256, 0, stream>>>(tangent, dxpbf, total);
        cast_bf(stream, conv_w, cwbf, 768 * 768);
        mgemm(stream, xpbf, cwbf, conv_b, tok, 2 * B_ * GP_, D_, D_, D_,
              B_ * GP_, false, true, false);
        const int tz = (int)(B_ * SD);
        assemble_kernel<<<8192, 256, 0, stream>>>(tok, dtok, z, dz, cls, pos, tz);
    }

    for (int l = 0; l < L_; ++l) {
        const float* l1g = ln1_g + (long long)l * D_;
        const float* l1b = ln1_b + (long long)l * D_;
        const float* qb  = qkv_b + (long long)l * 3 * D_;
        const float* ob  = out_b + (long long)l * D_;
        const float* l2g = ln2_g + (long long)l * D_;
        const float* l2b = ln2_b + (long long)l * D_;
        const float* f1b = fc1_b + (long long)l * MD_;
        const float* f2b = fc2_b + (long long)l * D_;

        cast_bf(stream, qkv_w + (long long)l * 3 * D_ * D_, wq, (long long)3 * D_ * D_);
        cast_bf(stream, out_w + (long long)l * D_ * D_,     wo, (long long)D_ * D_);
        cast_bf(stream, fc1_w + (long long)l * MD_ * D_,    w1, (long long)MD_ * D_);
        cast_bf(stream, fc2_w + (long long)l * D_ * MD_,    w2, (long long)D_ * MD_);

        // LN1
        ln_jvp_kernel<false><<<nBS, 256, 0, stream>>>(z, dz, l1g, l1b, nullptr, nullptr, ybf, dybf);
        // QKV fwd+tan fused
        mgemm(stream, ybf, wq, qb, qkvbf, 2 * MP_, 3 * D_, D_, 3 * D_, MP_, false, true, true);

        // attention: V transpose + single fused JVP kernel
        vtrans_kernel<<<NB * 4, 256, 0, stream>>>(qkvbf, dqkvbf, Vt, dVt);
        attn_fused_kernel<<<dim3(4, NB), 256, 0, stream>>>(qkvbf, dqkvbf, Vt, dVt, ybf, dybf);

        // projection + residual (ACC into z‖dz)
        mgemm(stream, ybf, wo, ob, z, 2 * MP_, D_, D_, D_, MP_, true, true, false);

        // LN2 + MLP
        ln_jvp_kernel<false><<<nBS, 256, 0, stream>>>(z, dz, l2g, l2b, nullptr, nullptr, ybf, dybf);
        mgemm(stream, ybf, w1, f1b, hbuf, 2 * MP_, MD_, D_, MD_, MP_, false, true, false);
        gelu_jvp_kernel<<<4096, 256, 0, stream>>>(hbuf, dhbuf, hbf, dhbf, (int)(PH / 4));
        mgemm(stream, hbf, w2, f2b, z, 2 * MP_, D_, MD_, D_, MP_, true, true, false);
    }

    // final LN (fp32 out) + head
    ln_jvp_kernel<true><<<nBS, 256, 0, stream>>>(z, dz, lnf_g, lnf_b, yf, dyf, ybf, dybf);
    gemm_kernel<true><<<dim3((NC_ + 63) / 64, 1), 256, 0, stream>>>(
        yf,  head_w, head_b, out,            B_, NC_, D_, (int)SD, D_, NC_);
    gemm_kernel<false><<<dim3((NC_ + 63) / 64, 1), 256, 0, stream>>>(
        dyf, head_w, nullptr, out + B_ * NC_, B_, NC_, D_, (int)SD, D_, NC_);
}

// Round 7
// 5616.862 us; speedup vs baseline: 12.9063x; 1.0160x over previous
//
// ViT-Base/16 fwd + JVP — Round 6: dense GEMM double-buffered (prefetch next
// K-tile before compute, single barrier per step — T3-minimum pipeline).
// Fused per-layer weight cast (4 -> 1 launch). Attention as R5.
#include <hip/hip_runtime.h>
#include <math.h>

static constexpr int B_   = 32;
static constexpr int S_   = 197;
static constexpr int D_   = 768;
static constexpr int H_   = 12;
static constexpr int L_   = 12;
static constexpr int MD_  = 3072;
static constexpr int NC_  = 1000;
static constexpr int GP_  = 196;
static constexpr int KP_  = 224;   // padded attention-K (7*32)
static constexpr int MP_  = 6400;  // padded row count (50*128)

typedef __attribute__((ext_vector_type(8))) short bf16x8v;
typedef __attribute__((ext_vector_type(4))) float f32x4v;

__device__ __forceinline__ unsigned short f2bf(float x) {
    union { float f; unsigned u; } v; v.f = x;
    unsigned r = v.u + 0x7fffu + ((v.u >> 16) & 1u);   // RNE
    return (unsigned short)(r >> 16);
}

#define GLOAD_LDS16(gptr, lptr) \
    __builtin_amdgcn_global_load_lds((const __attribute__((address_space(1))) void*)(gptr), \
        (__attribute__((address_space(3))) void*)(lptr), 16, 0, 0)

// ================= dense MFMA GEMM (128x128 tile, 8 waves, double-buffered) ==========
// C[m,n] (+)= sum_k A[m][k]*B[n][k] (+bias[n] if row<bias_rows).
// Pipeline per K-step: {issue stage(next buf)} || {ds_read+MFMA(cur buf)} -> 1 barrier.
template<bool ACC, bool BIAS, bool OUTBF>
__global__ __launch_bounds__(512, 4) void mfma_gemm_kernel(
    const short* __restrict__ A, const short* __restrict__ Bm,
    const float* __restrict__ bias, void* __restrict__ Cv,
    int M, int N, int K, int ldc, int bias_rows)
{
    int bx, by;
    {
        const int gx = gridDim.x, nwg = gx * gridDim.y;
        const int flat = blockIdx.y * gx + blockIdx.x;
        const int q = nwg >> 3, r = nwg & 7;
        const int xcd = flat & 7, idx = flat >> 3;
        const int nf = (xcd < r ? xcd * (q + 1) : r * (q + 1) + (xcd - r) * q) + idx;
        bx = nf % gx; by = nf / gx;
    }
    __shared__ __align__(16) short ldsA[2][128 * 32];
    __shared__ __align__(16) short ldsB[2][128 * 32];
    const int tid  = threadIdx.x;
    const int lane = tid & 63;
    const int w    = tid >> 6;
    const int m0 = by * 128, n0 = bx * 128;
    const int wr = w >> 1, wc = w & 1;
    f32x4v acc[2][4] = {};

    const int r_in = lane >> 2;
    const int cdst = lane & 3;
    const int srow = w * 16 + r_in;
    const int csrc = cdst ^ ((srow >> 1) & 3);
    const size_t aoff = (size_t)(m0 + srow) * K + csrc * 8;
    const size_t boff = (size_t)(n0 + srow) * K + csrc * 8;

    // prologue: stage k0=0 into buffer 0
    GLOAD_LDS16(A  + aoff, &ldsA[0][w * 512]);
    GLOAD_LDS16(Bm + boff, &ldsB[0][w * 512]);
    __syncthreads();

    int cur = 0;
    for (int k0 = 0; k0 < K; k0 += 32) {
        const int nxt = cur ^ 1;
        if (k0 + 32 < K) {             // issue next-tile loads BEFORE compute
            GLOAD_LDS16(A  + aoff + k0 + 32, &ldsA[nxt][w * 512]);
            GLOAD_LDS16(Bm + boff + k0 + 32, &ldsB[nxt][w * 512]);
        }
        const short* La = ldsA[cur];
        const short* Lb = ldsB[cur];
        bf16x8v af[2], bfr[4];
        #pragma unroll
        for (int m = 0; m < 2; ++m) {
            const int row = wr * 32 + m * 16 + (lane & 15);
            const int c = (lane >> 4) ^ ((row >> 1) & 3);
            af[m] = *(const bf16x8v*)&La[row * 32 + c * 8];
        }
        #pragma unroll
        for (int n = 0; n < 4; ++n) {
            const int row = wc * 64 + n * 16 + (lane & 15);
            const int c = (lane >> 4) ^ ((row >> 1) & 3);
            bfr[n] = *(const bf16x8v*)&Lb[row * 32 + c * 8];
        }
        #pragma unroll
        for (int m = 0; m < 2; ++m)
            #pragma unroll
            for (int n = 0; n < 4; ++n)
                acc[m][n] = __builtin_amdgcn_mfma_f32_16x16x32_bf16(af[m], bfr[n], acc[m][n], 0, 0, 0);
        __syncthreads();               // drains vmcnt (next buf ready) + lgkmcnt
        cur = nxt;
    }
    const int col_base = n0 + wc * 64 + (lane & 15);
    const int row_base = m0 + wr * 32 + (lane >> 4) * 4;
    #pragma unroll
    for (int n = 0; n < 4; ++n) {
        const int col = col_base + n * 16;
        const float bv = BIAS ? bias[col] : 0.f;
        #pragma unroll
        for (int m = 0; m < 2; ++m) {
            const int row = row_base + m * 16;
            const float bvr = (BIAS && row < bias_rows) ? bv : 0.f;
            #pragma unroll
            for (int r = 0; r < 4; ++r) {
                if (row + r < M) {
                    const size_t off = (size_t)(row + r) * ldc + col;
                    const float v = acc[m][n][r] + bvr;
                    if (OUTBF) ((short*)Cv)[off] = (short)f2bf(v);
                    else if (ACC) ((float*)Cv)[off] += v;
                    else ((float*)Cv)[off] = v;
                }
            }
        }
    }
}

// ================= fully fused attention JVP (as R5) =================
__global__ __launch_bounds__(256) void attn_fused_kernel(
    const short* __restrict__ qkvb, const short* __restrict__ dqkvb,
    const short* __restrict__ Vtb_, const short* __restrict__ dVtb_,
    short* __restrict__ obf, short* __restrict__ dobf)
{
    const int qt = blockIdx.x;
    const int b  = blockIdx.y;
    const int n = b / H_, h = b - n * H_;
    const short* qb  = qkvb  + (size_t)n * S_ * 2304 + h * 64;
    const short* kb  = qb + 768;
    const short* dqb = dqkvb + (size_t)n * S_ * 2304 + h * 64;
    const short* dkb = dqb + 768;
    const short* Vb  = Vtb_  + (size_t)b * 64 * KP_;
    const short* dVb = dVtb_ + (size_t)b * 64 * KP_;

    __shared__ __align__(16) short lds[32768];
    const int tid = threadIdx.x, lane = tid & 63, w = tid >> 6;
    const int g = lane >> 4, kc = lane & 15;
    const int srow = lane >> 2, cdst = lane & 3;
    const int csrc = cdst ^ ((srow >> 1) & 3);

    {
        const size_t qr = (size_t)min(qt * 64 + w * 16 + srow, S_ - 1) * 2304;
        #pragma unroll
        for (int kw = 0; kw < 2; ++kw) {
            GLOAD_LDS16(qb  + qr + kw * 32 + csrc * 8, &lds[w * 1024 + kw * 512]);
            GLOAD_LDS16(dqb + qr + kw * 32 + csrc * 8, &lds[4096 + w * 1024 + kw * 512]);
        }
    }

    f32x4v aS[14], aD[14];
    #pragma unroll
    for (int i = 0; i < 14; ++i) { aS[i] = (f32x4v){0,0,0,0}; aD[i] = (f32x4v){0,0,0,0}; }
    bf16x8v qf[2], dqf[2];

    #pragma unroll
    for (int kt = 0; kt < 7; ++kt) {
        {
            const int kwin = w & 1;
            const short* src = (w < 2) ? kb : dkb;
            const int base = (w < 2) ? 8192 : 10240;
            #pragma unroll
            for (int half = 0; half < 2; ++half) {
                const size_t kr = (size_t)min(kt * 32 + half * 16 + srow, S_ - 1) * 2304;
                GLOAD_LDS16(src + kr + kwin * 32 + csrc * 8,
                            &lds[base + kwin * 1024 + half * 512]);
            }
        }
        __syncthreads();
        if (kt == 0) {
            #pragma unroll
            for (int kw = 0; kw < 2; ++kw) {
                const int c = g ^ ((kc >> 1) & 3);
                qf[kw]  = *(const bf16x8v*)&lds[w * 1024 + kw * 512 + kc * 32 + c * 8];
                dqf[kw] = *(const bf16x8v*)&lds[4096 + w * 1024 + kw * 512 + kc * 32 + c * 8];
            }
        }
        #pragma unroll
        for (int nf = 0; nf < 2; ++nf) {
            const int row = nf * 16 + kc;
            const int c = g ^ ((row >> 1) & 3);
            const bf16x8v kf0  = *(const bf16x8v*)&lds[8192  + row * 32 + c * 8];
            const bf16x8v kf1  = *(const bf16x8v*)&lds[8192  + 1024 + row * 32 + c * 8];
            const bf16x8v dkf0 = *(const bf16x8v*)&lds[10240 + row * 32 + c * 8];
            const bf16x8v dkf1 = *(const bf16x8v*)&lds[10240 + 1024 + row * 32 + c * 8];
            const int fi = kt * 2 + nf;
            aS[fi] = __builtin_amdgcn_mfma_f32_16x16x32_bf16(qf[0], kf0, aS[fi], 0,0,0);
            aS[fi] = __builtin_amdgcn_mfma_f32_16x16x32_bf16(qf[1], kf1, aS[fi], 0,0,0);
            aD[fi] = __builtin_amdgcn_mfma_f32_16x16x32_bf16(dqf[0], kf0, aD[fi], 0,0,0);
            aD[fi] = __builtin_amdgcn_mfma_f32_16x16x32_bf16(dqf[1], kf1, aD[fi], 0,0,0);
            aD[fi] = __builtin_amdgcn_mfma_f32_16x16x32_bf16(qf[0], dkf0, aD[fi], 0,0,0);
            aD[fi] = __builtin_amdgcn_mfma_f32_16x16x32_bf16(qf[1], dkf1, aD[fi], 0,0,0);
        }
        __syncthreads();
    }

    float pm[4] = {-3.0e38f, -3.0e38f, -3.0e38f, -3.0e38f};
    #pragma unroll
    for (int fi = 0; fi < 14; ++fi) {
        if (fi * 16 + kc < S_) {
            #pragma unroll
            for (int r = 0; r < 4; ++r) pm[r] = fmaxf(pm[r], aS[fi][r]);
        }
    }
    #pragma unroll
    for (int off = 1; off < 16; off <<= 1)
        #pragma unroll
        for (int r = 0; r < 4; ++r) pm[r] = fmaxf(pm[r], __shfl_xor(pm[r], off));

    float den[4] = {0,0,0,0}, tsm[4] = {0,0,0,0};
    #pragma unroll
    for (int fi = 0; fi < 14; ++fi) {
        const bool val = fi * 16 + kc < S_;
        #pragma unroll
        for (int r = 0; r < 4; ++r) {
            const float s  = aS[fi][r] * 0.125f;
            const float ds = aD[fi][r] * 0.125f;
            const float e = val ? expf(s - pm[r] * 0.125f) : 0.f;
            den[r] += e; tsm[r] += e * ds;
            aS[fi][r] = e; aD[fi][r] = ds;
        }
    }
    #pragma unroll
    for (int off = 1; off < 16; off <<= 1)
        #pragma unroll
        for (int r = 0; r < 4; ++r) {
            den[r] += __shfl_xor(den[r], off);
            tsm[r] += __shfl_xor(tsm[r], off);
        }
    float inv[4], tq[4];
    #pragma unroll
    for (int r = 0; r < 4; ++r) { inv[r] = 1.f / den[r]; tq[r] = tsm[r] * inv[r]; }

    const int lpw = w * 3584, ldpw = 14336 + w * 3584;
    #pragma unroll
    for (int fi = 0; fi < 14; ++fi) {
        const int kwin = fi >> 1;
        const int chunkbase = (fi & 1) * 2 + (kc >> 3);
        #pragma unroll
        for (int r = 0; r < 4; ++r) {
            const int qs = g * 4 + r;
            const int swz = chunkbase ^ ((qs >> 1) & 3);
            const int addr = kwin * 512 + qs * 32 + swz * 8 + (kc & 7);
            const float p  = aS[fi][r] * inv[r];
            const float dp = p * (aD[fi][r] - tq[r]);
            lds[lpw  + addr] = (short)f2bf(p);
            lds[ldpw + addr] = (short)f2bf(dp);
        }
    }

    f32x4v aO[4], aDO[4];
    #pragma unroll
    for (int i = 0; i < 4; ++i) { aO[i] = (f32x4v){0,0,0,0}; aDO[i] = (f32x4v){0,0,0,0}; }

    #pragma unroll
    for (int kt = 0; kt < 7; ++kt) {
        {
            const size_t vr = (size_t)(w * 16 + srow) * KP_ + kt * 32 + csrc * 8;
            GLOAD_LDS16(Vb  + vr, &lds[28672 + w * 512]);
            GLOAD_LDS16(dVb + vr, &lds[30720 + w * 512]);
        }
        __syncthreads();
        bf16x8v pa, dpa;
        {
            const int c = g ^ ((kc >> 1) & 3);
            pa  = *(const bf16x8v*)&lds[lpw  + kt * 512 + kc * 32 + c * 8];
            dpa = *(const bf16x8v*)&lds[ldpw + kt * 512 + kc * 32 + c * 8];
        }
        #pragma unroll
        for (int nf = 0; nf < 4; ++nf) {
            const int row = nf * 16 + kc;
            const int c = (g) ^ ((row >> 1) & 3);
            const bf16x8v vf  = *(const bf16x8v*)&lds[28672 + row * 32 + c * 8];
            const bf16x8v dvf = *(const bf16x8v*)&lds[30720 + row * 32 + c * 8];
            aO[nf]  = __builtin_amdgcn_mfma_f32_16x16x32_bf16(pa,  vf,  aO[nf], 0,0,0);
            aDO[nf] = __builtin_amdgcn_mfma_f32_16x16x32_bf16(dpa, vf,  aDO[nf], 0,0,0);
            aDO[nf] = __builtin_amdgcn_mfma_f32_16x16x32_bf16(pa,  dvf, aDO[nf], 0,0,0);
        }
        __syncthreads();
    }

    short* ob  = obf  + (size_t)n * S_ * D_ + h * 64;
    short* dob = dobf + (size_t)n * S_ * D_ + h * 64;
    #pragma unroll
    for (int nf = 0; nf < 4; ++nf) {
        const int dh = nf * 16 + kc;
        #pragma unroll
        for (int r = 0; r < 4; ++r) {
            const int q = qt * 64 + w * 16 + g * 4 + r;
            if (q < S_) {
                ob [(size_t)q * D_ + dh] = (short)f2bf(aO[nf][r]);
                dob[(size_t)q * D_ + dh] = (short)f2bf(aDO[nf][r]);
            }
        }
    }
}

// ================= V transpose =================
__global__ __launch_bounds__(256) void vtrans_kernel(
    const short* __restrict__ qkvb, const short* __restrict__ dqkvb,
    short* __restrict__ Vt, short* __restrict__ dVt)
{
    const int blk = blockIdx.x;
    const int b = blk >> 2, kt = blk & 3;
    const int n = b / H_, h = b - n * H_;
    const short* vb  = qkvb  + (size_t)n * S_ * 2304 + 1536 + h * 64;
    const short* dvb = dqkvb + (size_t)n * S_ * 2304 + 1536 + h * 64;
    __shared__ short t1[64][65], t2[64][65];
    const int tid = threadIdx.x;
    #pragma unroll
    for (int j = 0; j < 16; ++j) {
        const int e = tid + 256 * j;
        const int kk = e >> 6, dh = e & 63;
        const int gk = kt * 64 + kk;
        short v = 0, dv = 0;
        if (gk < S_) { v = vb[(size_t)gk * 2304 + dh]; dv = dvb[(size_t)gk * 2304 + dh]; }
        t1[dh][kk] = v; t2[dh][kk] = dv;
    }
    __syncthreads();
    #pragma unroll
    for (int j = 0; j < 16; ++j) {
        const int e = tid + 256 * j;
        const int dh = e >> 6, kk = e & 63;
        const int ok = kt * 64 + kk;
        if (ok < KP_) {
            Vt [(size_t)b * 64 * KP_ + (size_t)dh * KP_ + ok] = t1[dh][kk];
            dVt[(size_t)b * 64 * KP_ + (size_t)dh * KP_ + ok] = t2[dh][kk];
        }
    }
}

// ================= fp32 GEMM (head only) =================
template<bool BIAS>
__global__ __launch_bounds__(256) void gemm_kernel(
    const float* __restrict__ A, const float* __restrict__ Bm,
    const float* __restrict__ bias, float* __restrict__ C,
    int M, int N, int K, int lda, int ldb, int ldc)
{
    const int tile_m = blockIdx.y * 64, tile_n = blockIdx.x * 64;
    __shared__ float As[16][64];
    __shared__ float Bs[16][64];
    const int tid = threadIdx.x;
    const int tx = tid & 15, ty = tid >> 4;
    float acc[4][4] = {};
    for (int k0 = 0; k0 < K; k0 += 16) {
        {
            const int row = tid >> 2, kc = (tid & 3) * 4, gm = tile_m + row;
            #pragma unroll
            for (int i = 0; i < 4; ++i) {
                const int gk = k0 + kc + i;
                float v = 0.f;
                if (gm < M && gk < K) v = A[(long long)gm * lda + gk];
                As[kc + i][row] = v;
            }
        }
        {
            const int row = tid >> 2, kc = (tid & 3) * 4, gn = tile_n + row;
            #pragma unroll
            for (int i = 0; i < 4; ++i) {
                const int gk = k0 + kc + i;
                float v = 0.f;
                if (gn < N && gk < K) v = Bm[(long long)gn * ldb + gk];
                Bs[kc + i][row] = v;
            }
        }
        __syncthreads();
        #pragma unroll
        for (int kk = 0; kk < 16; ++kk) {
            float a[4], bb[4];
            #pragma unroll
            for (int i = 0; i < 4; ++i) a[i] = As[kk][ty * 4 + i];
            #pragma unroll
            for (int j = 0; j < 4; ++j) bb[j] = Bs[kk][tx * 4 + j];
            #pragma unroll
            for (int i = 0; i < 4; ++i)
                #pragma unroll
                for (int j = 0; j < 4; ++j)
                    acc[i][j] += a[i] * bb[j];
        }
        __syncthreads();
    }
    #pragma unroll
    for (int i = 0; i < 4; ++i) {
        const int gm = tile_m + ty * 4 + i;
        if (gm >= M) continue;
        #pragma unroll
        for (int j = 0; j < 4; ++j) {
            const int gn = tile_n + tx * 4 + j;
            if (gn >= N) continue;
            float v = acc[i][j];
            if (BIAS) v += bias[gn];
            C[(long long)gm * ldc + gn] = v;
        }
    }
}

// ================= LayerNorm JVP =================
__device__ __forceinline__ float blk_sum4(float v, float* smem) {
    #pragma unroll
    for (int off = 32; off > 0; off >>= 1) v += __shfl_down(v, off);
    __syncthreads();
    if ((threadIdx.x & 63) == 0) smem[threadIdx.x >> 6] = v;
    __syncthreads();
    return smem[0] + smem[1] + smem[2] + smem[3];
}

template<bool WF32>
__global__ __launch_bounds__(256) void ln_jvp_kernel(
    const float* __restrict__ z, const float* __restrict__ dz,
    const float* __restrict__ g, const float* __restrict__ b,
    float* __restrict__ y, float* __restrict__ dy,
    short* __restrict__ ybf, short* __restrict__ dybf)
{
    const long long row = blockIdx.x;
    const float* xr  = z  + row * D_;
    const float* dxr = dz + row * D_;
    __shared__ float smem[4];
    const int t = threadIdx.x;
    float x[3], dx[3];
    #pragma unroll
    for (int i = 0; i < 3; ++i) { x[i] = xr[t + 256 * i]; dx[i] = dxr[t + 256 * i]; }
    float sx  = blk_sum4(x[0] + x[1] + x[2], smem);
    float sdx = blk_sum4(dx[0] + dx[1] + dx[2], smem);
    const float mu = sx / D_, dmu = sdx / D_;
    float sv = 0.f, sc = 0.f;
    #pragma unroll
    for (int i = 0; i < 3; ++i) {
        const float xc = x[i] - mu;
        sv += xc * xc;
        sc += xc * (dx[i] - dmu);
    }
    sv = blk_sum4(sv, smem);
    sc = blk_sum4(sc, smem);
    const float rstd = rsqrtf(sv / D_ + 1e-6f);
    const float k2   = (sc / D_) * rstd * rstd;
    #pragma unroll
    for (int i = 0; i < 3; ++i) {
        const int c = t + 256 * i;
        const float yh  = (x[i] - mu) * rstd;
        const float dyh = (dx[i] - dmu) * rstd - yh * k2;
        const float yv  = yh * g[c] + b[c];
        const float dyv = dyh * g[c];
        if (WF32) { y[row * D_ + c] = yv; dy[row * D_ + c] = dyv; }
        ybf[row * D_ + c]  = (short)f2bf(yv);
        dybf[row * D_ + c] = (short)f2bf(dyv);
    }
}

// ================= GELU JVP: fp32 in, bf16 out =================
__global__ __launch_bounds__(256) void gelu_jvp_kernel(
    const float* __restrict__ h, const float* __restrict__ dh,
    short* __restrict__ ho, short* __restrict__ dho, int n4)
{
    for (int i = blockIdx.x * blockDim.x + threadIdx.x; i < n4;
         i += gridDim.x * blockDim.x) {
        const float4 u4 = ((const float4*)h)[i];
        const float4 du4 = ((const float4*)dh)[i];
        short o[4], doo[4];
        const float us[4] = {u4.x, u4.y, u4.z, u4.w};
        const float dus[4] = {du4.x, du4.y, du4.z, du4.w};
        #pragma unroll
        for (int j = 0; j < 4; ++j) {
            const float u = us[j], du = dus[j];
            const float cdf = 0.5f * (1.0f + erff(u * 0.70710678118654752f));
            const float pdf = 0.3989422804014327f * expf(-0.5f * u * u);
            o[j]   = (short)f2bf(u * cdf);
            doo[j] = (short)f2bf(du * (cdf + u * pdf));
        }
        *(short4*)&ho[i * 4]  = *(short4*)o;
        *(short4*)&dho[i * 4] = *(short4*)doo;
    }
}

__global__ __launch_bounds__(256) void cast_bf16_kernel(
    const float* __restrict__ in, short* __restrict__ out, int n4)
{
    for (int i = blockIdx.x * blockDim.x + threadIdx.x; i < n4;
         i += gridDim.x * blockDim.x) {
        const float4 v = ((const float4*)in)[i];
        short o[4];
        o[0] = (short)f2bf(v.x); o[1] = (short)f2bf(v.y);
        o[2] = (short)f2bf(v.z); o[3] = (short)f2bf(v.w);
        *(short4*)&out[i * 4] = *(short4*)o;
    }
}

// fused per-layer weight cast: qkv_w | out_w | fc1_w | fc2_w -> bf16 slabs
__global__ __launch_bounds__(256) void wcast_kernel(
    const float* __restrict__ qw, const float* __restrict__ ow,
    const float* __restrict__ f1, const float* __restrict__ f2,
    short* __restrict__ dq, short* __restrict__ dow,
    short* __restrict__ d1, short* __restrict__ d2)
{
    const int b1 = 442368;            // 3*D*D/4
    const int b2 = b1 + 147456;       // + D*D/4
    const int b3 = b2 + 589824;       // + MD*D/4
    const int total = b3 + 589824;    // + D*MD/4
    for (int i = blockIdx.x * blockDim.x + threadIdx.x; i < total;
         i += gridDim.x * blockDim.x) {
        const float* s; short* d; int j;
        if (i < b1)      { s = qw; d = dq;  j = i; }
        else if (i < b2) { s = ow; d = dow; j = i - b1; }
        else if (i < b3) { s = f1; d = d1;  j = i - b2; }
        else             { s = f2; d = d2;  j = i - b3; }
        const float4 v = ((const float4*)s)[j];
        short o[4];
        o[0] = (short)f2bf(v.x); o[1] = (short)f2bf(v.y);
        o[2] = (short)f2bf(v.z); o[3] = (short)f2bf(v.w);
        *(short4*)&d[j * 4] = *(short4*)o;
    }
}

__global__ __launch_bounds__(256) void im2col_kernel(
    const float* __restrict__ x, short* __restrict__ xp, int total)
{
    for (int i = blockIdx.x * blockDim.x + threadIdx.x; i < total;
         i += gridDim.x * blockDim.x) {
        const int k  = i % 768;
        const int m  = i / 768;
        const int gh = m % GP_;
        const int n  = m / GP_;
        const int q  = k & 15;
        const int p  = (k >> 4) & 15;
        const int c  = k >> 8;
        const int hc = gh % 14, gr = gh / 14;
        const int ir = gr * 16 + p, ic = hc * 16 + q;
        xp[i] = (short)f2bf(x[(((long long)n * 3 + c) * 224 + ir) * 224 + ic]);
    }
}

__global__ __launch_bounds__(256) void assemble_kernel(
    const float* __restrict__ tok, const float* __restrict__ dtok,
    float* __restrict__ z, float* __restrict__ dz,
    const float* __restrict__ cls, const float* __restrict__ pos, int total)
{
    for (int i = blockIdx.x * blockDim.x + threadIdx.x; i < total;
         i += gridDim.x * blockDim.x) {
        const int d = i % D_;
        const int s = (i / D_) % S_;
        const int n = i / (D_ * S_);
        if (s == 0) {
            z[i]  = cls[d] + pos[d];
            dz[i] = 0.f;
        } else {
            const long long ti = ((long long)n * GP_ + s - 1) * D_ + d;
            z[i]  = tok[ti]  + pos[s * D_ + d];
            dz[i] = dtok[ti];
        }
    }
}

// ================= host helpers =================
static inline void mgemm(hipStream_t st, const short* A, const short* Bm, const float* bias,
                         void* C, int M, int N, int K, int ldc, int bias_rows,
                         bool acc, bool hasbias, bool outbf)
{
    dim3 grid(N / 128, (M + 127) / 128);
    dim3 blk(512);
#define MK(AC, BI, OB) mfma_gemm_kernel<AC, BI, OB><<<grid, blk, 0, st>>>(A, Bm, bias, C, M, N, K, ldc, bias_rows)
    if (outbf) { if (hasbias) MK(false, true, true); else MK(false, false, true); }
    else if (acc) { if (hasbias) MK(true, true, false);  else MK(true, false, false); }
    else     { if (hasbias) MK(false, true, false); else MK(false, false, false); }
#undef MK
}

static inline void cast_bf(hipStream_t st, const float* in, short* out, long long n) {
    const int n4 = (int)(n / 4);
    int g = (n4 + 255) / 256; if (g > 4096) g = 4096;
    cast_bf16_kernel<<<g, 256, 0, st>>>(in, out, n4);
}

extern "C" void kernel_launch(void* const* d_in, const int* in_sizes, int n_in,
                              void* d_out, int out_size, void* d_ws, size_t ws_size,
                              hipStream_t stream)
{
    const float* x       = (const float*)d_in[0];
    const float* tangent = (const float*)d_in[1];
    const float* conv_w  = (const float*)d_in[2];
    const float* conv_b  = (const float*)d_in[3];
    const float* cls     = (const float*)d_in[4];
    const float* pos     = (const float*)d_in[5];
    const float* ln1_g   = (const float*)d_in[6];
    const float* ln1_b   = (const float*)d_in[7];
    const float* qkv_w   = (const float*)d_in[8];
    const float* qkv_b   = (const float*)d_in[9];
    const float* out_w   = (const float*)d_in[10];
    const float* out_b   = (const float*)d_in[11];
    const float* ln2_g   = (const float*)d_in[12];
    const float* ln2_b   = (const float*)d_in[13];
    const float* fc1_w   = (const float*)d_in[14];
    const float* fc1_b   = (const float*)d_in[15];
    const float* fc2_w   = (const float*)d_in[16];
    const float* fc2_b   = (const float*)d_in[17];
    const float* lnf_g   = (const float*)d_in[18];
    const float* lnf_b   = (const float*)d_in[19];
    const float* head_w  = (const float*)d_in[20];
    const float* head_b  = (const float*)d_in[21];
    float* out = (float*)d_out;

    const int nBS = B_ * S_;                            // 6304
    const int NB = B_ * H_;                             // 384
    const long long SD = (long long)S_ * D_;
    const long long PZ = (long long)MP_ * D_;           // 4,915,200
    const long long PQ = (long long)MP_ * 2304;         // 14,745,600
    const long long PH = (long long)MP_ * MD_;          // 19,660,800
    const long long PTOK = (long long)B_ * GP_ * D_;    // 4,816,896

    // ---- fp32 region ----
    float* f = (float*)d_ws;
    float* z     = f;             // [6400][768]
    float* dz    = z + PZ;
    float* hbuf  = dz + PZ;       // [6400][3072] fwd; aliases tok, final y
    float* dhbuf = hbuf + PH;
    float* tok   = hbuf;
    float* dtok  = hbuf + PTOK;
    float* yf    = hbuf;
    float* dyf   = dhbuf;

    // ---- bf16 region ----
    short* sh     = (short*)(dhbuf + PH);
    short* ybf    = sh;                       // [2*6400][768]
    short* dybf   = ybf + PZ;
    short* qkvbf  = dybf + PZ;                // [2*6400][2304]
    short* dqkvbf = qkvbf + PQ;
    short* Vt     = dqkvbf + PQ;              // [384][64][224] x2
    short* dVt    = Vt + (long long)NB * 64 * KP_;
    short* hbf    = dVt + (long long)NB * 64 * KP_;   // [2*6400][3072]
    short* dhbf   = hbf + PH;
    short* xpbf   = hbf;
    short* dxpbf  = xpbf + PTOK;
    short* wq     = dhbf + PH;
    short* wo     = wq + 2304 * 768;
    short* w1     = wo + 768 * 768;
    short* w2     = w1 + 3072 * 768;
    short* cwbf   = w2 + 768 * 3072;

    // ---- patch embedding (fused GEMM, M = 2*6272) ----
    {
        const int total = (int)PTOK;
        im2col_kernel<<<8192, 256, 0, stream>>>(x, xpbf, total);
        im2col_kernel<<<8192, 256, 0, stream>>>(tangent, dxpbf, total);
        cast_bf(stream, conv_w, cwbf, 768 * 768);
        mgemm(stream, xpbf, cwbf, conv_b, tok, 2 * B_ * GP_, D_, D_, D_,
              B_ * GP_, false, true, false);
        const int tz = (int)(B_ * SD);
        assemble_kernel<<<8192, 256, 0, stream>>>(tok, dtok, z, dz, cls, pos, tz);
    }

    for (int l = 0; l < L_; ++l) {
        const float* l1g = ln1_g + (long long)l * D_;
        const float* l1b = ln1_b + (long long)l * D_;
        const float* qb  = qkv_b + (long long)l * 3 * D_;
        const float* ob  = out_b + (long long)l * D_;
        const float* l2g = ln2_g + (long long)l * D_;
        const float* l2b = ln2_b + (long long)l * D_;
        const float* f1b = fc1_b + (long long)l * MD_;
        const float* f2b = fc2_b + (long long)l * D_;

        // fused per-layer weight cast (1 launch instead of 4)
        wcast_kernel<<<4096, 256, 0, stream>>>(
            qkv_w + (long long)l * 3 * D_ * D_, out_w + (long long)l * D_ * D_,
            fc1_w + (long long)l * MD_ * D_,    fc2_w + (long long)l * D_ * MD_,
            wq, wo, w1, w2);

        // LN1
        ln_jvp_kernel<false><<<nBS, 256, 0, stream>>>(z, dz, l1g, l1b, nullptr, nullptr, ybf, dybf);
        // QKV fwd+tan fused
        mgemm(stream, ybf, wq, qb, qkvbf, 2 * MP_, 3 * D_, D_, 3 * D_, MP_, false, true, true);

        // attention: V transpose + single fused JVP kernel
        vtrans_kernel<<<NB * 4, 256, 0, stream>>>(qkvbf, dqkvbf, Vt, dVt);
        attn_fused_kernel<<<dim3(4, NB), 256, 0, stream>>>(qkvbf, dqkvbf, Vt, dVt, ybf, dybf);

        // projection + residual (ACC into z‖dz)
        mgemm(stream, ybf, wo, ob, z, 2 * MP_, D_, D_, D_, MP_, true, true, false);

        // LN2 + MLP
        ln_jvp_kernel<false><<<nBS, 256, 0, stream>>>(z, dz, l2g, l2b, nullptr, nullptr, ybf, dybf);
        mgemm(stream, ybf, w1, f1b, hbuf, 2 * MP_, MD_, D_, MD_, MP_, false, true, false);
        gelu_jvp_kernel<<<4096, 256, 0, stream>>>(hbuf, dhbuf, hbf, dhbf, (int)(PH / 4));
        mgemm(stream, hbf, w2, f2b, z, 2 * MP_, D_, MD_, D_, MP_, true, true, false);
    }

    // final LN (fp32 out) + head
    ln_jvp_kernel<true><<<nBS, 256, 0, stream>>>(z, dz, lnf_g, lnf_b, yf, dyf, ybf, dybf);
    gemm_kernel<true><<<dim3((NC_ + 63) / 64, 1), 256, 0, stream>>>(
        yf,  head_w, head_b, out,            B_, NC_, D_, (int)SD, D_, NC_);
    gemm_kernel<false><<<dim3((NC_ + 63) / 64, 1), 256, 0, stream>>>(
        dyf, head_w, nullptr, out + B_ * NC_, B_, NC_, D_, (int)SD, D_, NC_);
}

// Round 8
// 5081.376 us; speedup vs baseline: 14.2664x; 1.1054x over previous
//
// ViT-Base/16 fwd + JVP — Round 7: paired fwd+tangent GEMM blocks (shared B tile),
// GELU-JVP fused into FC1 epilogue (fp32 hidden roundtrip + gelu kernel deleted).
#include <hip/hip_runtime.h>
#include <math.h>

static constexpr int B_   = 32;
static constexpr int S_   = 197;
static constexpr int D_   = 768;
static constexpr int H_   = 12;
static constexpr int L_   = 12;
static constexpr int MD_  = 3072;
static constexpr int NC_  = 1000;
static constexpr int GP_  = 196;
static constexpr int KP_  = 224;   // padded attention-K (7*32)
static constexpr int MP_  = 6400;  // padded row count (50*128)

typedef __attribute__((ext_vector_type(8))) short bf16x8v;
typedef __attribute__((ext_vector_type(4))) float f32x4v;

__device__ __forceinline__ unsigned short f2bf(float x) {
    union { float f; unsigned u; } v; v.f = x;
    unsigned r = v.u + 0x7fffu + ((v.u >> 16) & 1u);   // RNE
    return (unsigned short)(r >> 16);
}

#define GLOAD_LDS16(gptr, lptr) \
    __builtin_amdgcn_global_load_lds((const __attribute__((address_space(1))) void*)(gptr), \
        (__attribute__((address_space(3))) void*)(lptr), 16, 0, 0)

// ============ paired MFMA GEMM: fwd+tangent in one block, shared B ============
// Cf[m,n] = sum_k Af[m][k]*B[n][k] (+bias), Ct[m,n] = sum_k At[m][k]*B[n][k].
// MODE: 0 fp32 store, 1 fp32 ACC, 2 bf16 store, 3 GELU-JVP -> bf16.
// 512 thr = 8 waves (4x2), wave tile 32x64 per half. Double-buffered LDS (48 KB).
template<int MODE, bool BIAS>
__global__ __launch_bounds__(512, 2) void mfma_pair_kernel(
    const short* __restrict__ Af, const short* __restrict__ At,
    const short* __restrict__ Bm, const float* __restrict__ bias,
    void* __restrict__ Cfv, void* __restrict__ Ctv,
    int Mhalf, int N, int K, int ldc)
{
    int bx, by;
    {
        const int gx = gridDim.x, nwg = gx * gridDim.y;
        const int flat = blockIdx.y * gx + blockIdx.x;
        const int q = nwg >> 3, r = nwg & 7;
        const int xcd = flat & 7, idx = flat >> 3;
        const int nf = (xcd < r ? xcd * (q + 1) : r * (q + 1) + (xcd - r) * q) + idx;
        bx = nf % gx; by = nf / gx;
    }
    __shared__ __align__(16) short ldsAf[2][128 * 32];
    __shared__ __align__(16) short ldsAt[2][128 * 32];
    __shared__ __align__(16) short ldsB [2][128 * 32];
    const int tid  = threadIdx.x;
    const int lane = tid & 63;
    const int w    = tid >> 6;
    const int m0 = by * 128, n0 = bx * 128;
    const int wr = w >> 1, wc = w & 1;
    f32x4v accf[2][4] = {}, acct[2][4] = {};

    const int r_in = lane >> 2;
    const int cdst = lane & 3;
    const int srow = w * 16 + r_in;
    const int csrc = cdst ^ ((srow >> 1) & 3);
    const size_t aoff = (size_t)(m0 + srow) * K + csrc * 8;
    const size_t boff = (size_t)(n0 + srow) * K + csrc * 8;

    // prologue: stage k0=0 into buffer 0
    GLOAD_LDS16(Af + aoff, &ldsAf[0][w * 512]);
    GLOAD_LDS16(At + aoff, &ldsAt[0][w * 512]);
    GLOAD_LDS16(Bm + boff, &ldsB [0][w * 512]);
    __syncthreads();

    int cur = 0;
    for (int k0 = 0; k0 < K; k0 += 32) {
        const int nxt = cur ^ 1;
        if (k0 + 32 < K) {
            GLOAD_LDS16(Af + aoff + k0 + 32, &ldsAf[nxt][w * 512]);
            GLOAD_LDS16(At + aoff + k0 + 32, &ldsAt[nxt][w * 512]);
            GLOAD_LDS16(Bm + boff + k0 + 32, &ldsB [nxt][w * 512]);
        }
        bf16x8v af[2], at[2], bfr[4];
        #pragma unroll
        for (int m = 0; m < 2; ++m) {
            const int row = wr * 32 + m * 16 + (lane & 15);
            const int c = (lane >> 4) ^ ((row >> 1) & 3);
            af[m] = *(const bf16x8v*)&ldsAf[cur][row * 32 + c * 8];
            at[m] = *(const bf16x8v*)&ldsAt[cur][row * 32 + c * 8];
        }
        #pragma unroll
        for (int n = 0; n < 4; ++n) {
            const int row = wc * 64 + n * 16 + (lane & 15);
            const int c = (lane >> 4) ^ ((row >> 1) & 3);
            bfr[n] = *(const bf16x8v*)&ldsB[cur][row * 32 + c * 8];
        }
        #pragma unroll
        for (int m = 0; m < 2; ++m)
            #pragma unroll
            for (int n = 0; n < 4; ++n) {
                accf[m][n] = __builtin_amdgcn_mfma_f32_16x16x32_bf16(af[m], bfr[n], accf[m][n], 0, 0, 0);
                acct[m][n] = __builtin_amdgcn_mfma_f32_16x16x32_bf16(at[m], bfr[n], acct[m][n], 0, 0, 0);
            }
        __syncthreads();
        cur = nxt;
    }
    const int col_base = n0 + wc * 64 + (lane & 15);
    const int row_base = m0 + wr * 32 + (lane >> 4) * 4;
    #pragma unroll
    for (int n = 0; n < 4; ++n) {
        const int col = col_base + n * 16;
        const float bv = BIAS ? bias[col] : 0.f;
        #pragma unroll
        for (int m = 0; m < 2; ++m) {
            const int row = row_base + m * 16;
            #pragma unroll
            for (int r = 0; r < 4; ++r) {
                if (row + r < Mhalf) {
                    const size_t off = (size_t)(row + r) * ldc + col;
                    const float vf = accf[m][n][r] + bv;
                    const float vt = acct[m][n][r];
                    if (MODE == 0) {
                        ((float*)Cfv)[off] = vf;
                        ((float*)Ctv)[off] = vt;
                    } else if (MODE == 1) {
                        ((float*)Cfv)[off] += vf;
                        ((float*)Ctv)[off] += vt;
                    } else if (MODE == 2) {
                        ((short*)Cfv)[off] = (short)f2bf(vf);
                        ((short*)Ctv)[off] = (short)f2bf(vt);
                    } else {  // GELU JVP
                        const float cdf = 0.5f * (1.0f + erff(vf * 0.70710678118654752f));
                        const float pdf = 0.3989422804014327f * expf(-0.5f * vf * vf);
                        ((short*)Cfv)[off] = (short)f2bf(vf * cdf);
                        ((short*)Ctv)[off] = (short)f2bf(vt * (cdf + vf * pdf));
                    }
                }
            }
        }
    }
}

// ================= fully fused attention JVP (as R5) =================
__global__ __launch_bounds__(256) void attn_fused_kernel(
    const short* __restrict__ qkvb, const short* __restrict__ dqkvb,
    const short* __restrict__ Vtb_, const short* __restrict__ dVtb_,
    short* __restrict__ obf, short* __restrict__ dobf)
{
    const int qt = blockIdx.x;
    const int b  = blockIdx.y;
    const int n = b / H_, h = b - n * H_;
    const short* qb  = qkvb  + (size_t)n * S_ * 2304 + h * 64;
    const short* kb  = qb + 768;
    const short* dqb = dqkvb + (size_t)n * S_ * 2304 + h * 64;
    const short* dkb = dqb + 768;
    const short* Vb  = Vtb_  + (size_t)b * 64 * KP_;
    const short* dVb = dVtb_ + (size_t)b * 64 * KP_;

    __shared__ __align__(16) short lds[32768];
    const int tid = threadIdx.x, lane = tid & 63, w = tid >> 6;
    const int g = lane >> 4, kc = lane & 15;
    const int srow = lane >> 2, cdst = lane & 3;
    const int csrc = cdst ^ ((srow >> 1) & 3);

    {
        const size_t qr = (size_t)min(qt * 64 + w * 16 + srow, S_ - 1) * 2304;
        #pragma unroll
        for (int kw = 0; kw < 2; ++kw) {
            GLOAD_LDS16(qb  + qr + kw * 32 + csrc * 8, &lds[w * 1024 + kw * 512]);
            GLOAD_LDS16(dqb + qr + kw * 32 + csrc * 8, &lds[4096 + w * 1024 + kw * 512]);
        }
    }

    f32x4v aS[14], aD[14];
    #pragma unroll
    for (int i = 0; i < 14; ++i) { aS[i] = (f32x4v){0,0,0,0}; aD[i] = (f32x4v){0,0,0,0}; }
    bf16x8v qf[2], dqf[2];

    #pragma unroll
    for (int kt = 0; kt < 7; ++kt) {
        {
            const int kwin = w & 1;
            const short* src = (w < 2) ? kb : dkb;
            const int base = (w < 2) ? 8192 : 10240;
            #pragma unroll
            for (int half = 0; half < 2; ++half) {
                const size_t kr = (size_t)min(kt * 32 + half * 16 + srow, S_ - 1) * 2304;
                GLOAD_LDS16(src + kr + kwin * 32 + csrc * 8,
                            &lds[base + kwin * 1024 + half * 512]);
            }
        }
        __syncthreads();
        if (kt == 0) {
            #pragma unroll
            for (int kw = 0; kw < 2; ++kw) {
                const int c = g ^ ((kc >> 1) & 3);
                qf[kw]  = *(const bf16x8v*)&lds[w * 1024 + kw * 512 + kc * 32 + c * 8];
                dqf[kw] = *(const bf16x8v*)&lds[4096 + w * 1024 + kw * 512 + kc * 32 + c * 8];
            }
        }
        #pragma unroll
        for (int nf = 0; nf < 2; ++nf) {
            const int row = nf * 16 + kc;
            const int c = g ^ ((row >> 1) & 3);
            const bf16x8v kf0  = *(const bf16x8v*)&lds[8192  + row * 32 + c * 8];
            const bf16x8v kf1  = *(const bf16x8v*)&lds[8192  + 1024 + row * 32 + c * 8];
            const bf16x8v dkf0 = *(const bf16x8v*)&lds[10240 + row * 32 + c * 8];
            const bf16x8v dkf1 = *(const bf16x8v*)&lds[10240 + 1024 + row * 32 + c * 8];
            const int fi = kt * 2 + nf;
            aS[fi] = __builtin_amdgcn_mfma_f32_16x16x32_bf16(qf[0], kf0, aS[fi], 0,0,0);
            aS[fi] = __builtin_amdgcn_mfma_f32_16x16x32_bf16(qf[1], kf1, aS[fi], 0,0,0);
            aD[fi] = __builtin_amdgcn_mfma_f32_16x16x32_bf16(dqf[0], kf0, aD[fi], 0,0,0);
            aD[fi] = __builtin_amdgcn_mfma_f32_16x16x32_bf16(dqf[1], kf1, aD[fi], 0,0,0);
            aD[fi] = __builtin_amdgcn_mfma_f32_16x16x32_bf16(qf[0], dkf0, aD[fi], 0,0,0);
            aD[fi] = __builtin_amdgcn_mfma_f32_16x16x32_bf16(qf[1], dkf1, aD[fi], 0,0,0);
        }
        __syncthreads();
    }

    float pm[4] = {-3.0e38f, -3.0e38f, -3.0e38f, -3.0e38f};
    #pragma unroll
    for (int fi = 0; fi < 14; ++fi) {
        if (fi * 16 + kc < S_) {
            #pragma unroll
            for (int r = 0; r < 4; ++r) pm[r] = fmaxf(pm[r], aS[fi][r]);
        }
    }
    #pragma unroll
    for (int off = 1; off < 16; off <<= 1)
        #pragma unroll
        for (int r = 0; r < 4; ++r) pm[r] = fmaxf(pm[r], __shfl_xor(pm[r], off));

    float den[4] = {0,0,0,0}, tsm[4] = {0,0,0,0};
    #pragma unroll
    for (int fi = 0; fi < 14; ++fi) {
        const bool val = fi * 16 + kc < S_;
        #pragma unroll
        for (int r = 0; r < 4; ++r) {
            const float s  = aS[fi][r] * 0.125f;
            const float ds = aD[fi][r] * 0.125f;
            const float e = val ? expf(s - pm[r] * 0.125f) : 0.f;
            den[r] += e; tsm[r] += e * ds;
            aS[fi][r] = e; aD[fi][r] = ds;
        }
    }
    #pragma unroll
    for (int off = 1; off < 16; off <<= 1)
        #pragma unroll
        for (int r = 0; r < 4; ++r) {
            den[r] += __shfl_xor(den[r], off);
            tsm[r] += __shfl_xor(tsm[r], off);
        }
    float inv[4], tq[4];
    #pragma unroll
    for (int r = 0; r < 4; ++r) { inv[r] = 1.f / den[r]; tq[r] = tsm[r] * inv[r]; }

    const int lpw = w * 3584, ldpw = 14336 + w * 3584;
    #pragma unroll
    for (int fi = 0; fi < 14; ++fi) {
        const int kwin = fi >> 1;
        const int chunkbase = (fi & 1) * 2 + (kc >> 3);
        #pragma unroll
        for (int r = 0; r < 4; ++r) {
            const int qs = g * 4 + r;
            const int swz = chunkbase ^ ((qs >> 1) & 3);
            const int addr = kwin * 512 + qs * 32 + swz * 8 + (kc & 7);
            const float p  = aS[fi][r] * inv[r];
            const float dp = p * (aD[fi][r] - tq[r]);
            lds[lpw  + addr] = (short)f2bf(p);
            lds[ldpw + addr] = (short)f2bf(dp);
        }
    }

    f32x4v aO[4], aDO[4];
    #pragma unroll
    for (int i = 0; i < 4; ++i) { aO[i] = (f32x4v){0,0,0,0}; aDO[i] = (f32x4v){0,0,0,0}; }

    #pragma unroll
    for (int kt = 0; kt < 7; ++kt) {
        {
            const size_t vr = (size_t)(w * 16 + srow) * KP_ + kt * 32 + csrc * 8;
            GLOAD_LDS16(Vb  + vr, &lds[28672 + w * 512]);
            GLOAD_LDS16(dVb + vr, &lds[30720 + w * 512]);
        }
        __syncthreads();
        bf16x8v pa, dpa;
        {
            const int c = g ^ ((kc >> 1) & 3);
            pa  = *(const bf16x8v*)&lds[lpw  + kt * 512 + kc * 32 + c * 8];
            dpa = *(const bf16x8v*)&lds[ldpw + kt * 512 + kc * 32 + c * 8];
        }
        #pragma unroll
        for (int nf = 0; nf < 4; ++nf) {
            const int row = nf * 16 + kc;
            const int c = (g) ^ ((row >> 1) & 3);
            const bf16x8v vf  = *(const bf16x8v*)&lds[28672 + row * 32 + c * 8];
            const bf16x8v dvf = *(const bf16x8v*)&lds[30720 + row * 32 + c * 8];
            aO[nf]  = __builtin_amdgcn_mfma_f32_16x16x32_bf16(pa,  vf,  aO[nf], 0,0,0);
            aDO[nf] = __builtin_amdgcn_mfma_f32_16x16x32_bf16(dpa, vf,  aDO[nf], 0,0,0);
            aDO[nf] = __builtin_amdgcn_mfma_f32_16x16x32_bf16(pa,  dvf, aDO[nf], 0,0,0);
        }
        __syncthreads();
    }

    short* ob  = obf  + (size_t)n * S_ * D_ + h * 64;
    short* dob = dobf + (size_t)n * S_ * D_ + h * 64;
    #pragma unroll
    for (int nf = 0; nf < 4; ++nf) {
        const int dh = nf * 16 + kc;
        #pragma unroll
        for (int r = 0; r < 4; ++r) {
            const int q = qt * 64 + w * 16 + g * 4 + r;
            if (q < S_) {
                ob [(size_t)q * D_ + dh] = (short)f2bf(aO[nf][r]);
                dob[(size_t)q * D_ + dh] = (short)f2bf(aDO[nf][r]);
            }
        }
    }
}

// ================= V transpose =================
__global__ __launch_bounds__(256) void vtrans_kernel(
    const short* __restrict__ qkvb, const short* __restrict__ dqkvb,
    short* __restrict__ Vt, short* __restrict__ dVt)
{
    const int blk = blockIdx.x;
    const int b = blk >> 2, kt = blk & 3;
    const int n = b / H_, h = b - n * H_;
    const short* vb  = qkvb  + (size_t)n * S_ * 2304 + 1536 + h * 64;
    const short* dvb = dqkvb + (size_t)n * S_ * 2304 + 1536 + h * 64;
    __shared__ short t1[64][65], t2[64][65];
    const int tid = threadIdx.x;
    #pragma unroll
    for (int j = 0; j < 16; ++j) {
        const int e = tid + 256 * j;
        const int kk = e >> 6, dh = e & 63;
        const int gk = kt * 64 + kk;
        short v = 0, dv = 0;
        if (gk < S_) { v = vb[(size_t)gk * 2304 + dh]; dv = dvb[(size_t)gk * 2304 + dh]; }
        t1[dh][kk] = v; t2[dh][kk] = dv;
    }
    __syncthreads();
    #pragma unroll
    for (int j = 0; j < 16; ++j) {
        const int e = tid + 256 * j;
        const int dh = e >> 6, kk = e & 63;
        const int ok = kt * 64 + kk;
        if (ok < KP_) {
            Vt [(size_t)b * 64 * KP_ + (size_t)dh * KP_ + ok] = t1[dh][kk];
            dVt[(size_t)b * 64 * KP_ + (size_t)dh * KP_ + ok] = t2[dh][kk];
        }
    }
}

// ================= fp32 GEMM (head only) =================
template<bool BIAS>
__global__ __launch_bounds__(256) void gemm_kernel(
    const float* __restrict__ A, const float* __restrict__ Bm,
    const float* __restrict__ bias, float* __restrict__ C,
    int M, int N, int K, int lda, int ldb, int ldc)
{
    const int tile_m = blockIdx.y * 64, tile_n = blockIdx.x * 64;
    __shared__ float As[16][64];
    __shared__ float Bs[16][64];
    const int tid = threadIdx.x;
    const int tx = tid & 15, ty = tid >> 4;
    float acc[4][4] = {};
    for (int k0 = 0; k0 < K; k0 += 16) {
        {
            const int row = tid >> 2, kc = (tid & 3) * 4, gm = tile_m + row;
            #pragma unroll
            for (int i = 0; i < 4; ++i) {
                const int gk = k0 + kc + i;
                float v = 0.f;
                if (gm < M && gk < K) v = A[(long long)gm * lda + gk];
                As[kc + i][row] = v;
            }
        }
        {
            const int row = tid >> 2, kc = (tid & 3) * 4, gn = tile_n + row;
            #pragma unroll
            for (int i = 0; i < 4; ++i) {
                const int gk = k0 + kc + i;
                float v = 0.f;
                if (gn < N && gk < K) v = Bm[(long long)gn * ldb + gk];
                Bs[kc + i][row] = v;
            }
        }
        __syncthreads();
        #pragma unroll
        for (int kk = 0; kk < 16; ++kk) {
            float a[4], bb[4];
            #pragma unroll
            for (int i = 0; i < 4; ++i) a[i] = As[kk][ty * 4 + i];
            #pragma unroll
            for (int j = 0; j < 4; ++j) bb[j] = Bs[kk][tx * 4 + j];
            #pragma unroll
            for (int i = 0; i < 4; ++i)
                #pragma unroll
                for (int j = 0; j < 4; ++j)
                    acc[i][j] += a[i] * bb[j];
        }
        __syncthreads();
    }
    #pragma unroll
    for (int i = 0; i < 4; ++i) {
        const int gm = tile_m + ty * 4 + i;
        if (gm >= M) continue;
        #pragma unroll
        for (int j = 0; j < 4; ++j) {
            const int gn = tile_n + tx * 4 + j;
            if (gn >= N) continue;
            float v = acc[i][j];
            if (BIAS) v += bias[gn];
            C[(long long)gm * ldc + gn] = v;
        }
    }
}

// ================= LayerNorm JVP =================
__device__ __forceinline__ float blk_sum4(float v, float* smem) {
    #pragma unroll
    for (int off = 32; off > 0; off >>= 1) v += __shfl_down(v, off);
    __syncthreads();
    if ((threadIdx.x & 63) == 0) smem[threadIdx.x >> 6] = v;
    __syncthreads();
    return smem[0] + smem[1] + smem[2] + smem[3];
}

template<bool WF32>
__global__ __launch_bounds__(256) void ln_jvp_kernel(
    const float* __restrict__ z, const float* __restrict__ dz,
    const float* __restrict__ g, const float* __restrict__ b,
    float* __restrict__ y, float* __restrict__ dy,
    short* __restrict__ ybf, short* __restrict__ dybf)
{
    const long long row = blockIdx.x;
    const float* xr  = z  + row * D_;
    const float* dxr = dz + row * D_;
    __shared__ float smem[4];
    const int t = threadIdx.x;
    float x[3], dx[3];
    #pragma unroll
    for (int i = 0; i < 3; ++i) { x[i] = xr[t + 256 * i]; dx[i] = dxr[t + 256 * i]; }
    float sx  = blk_sum4(x[0] + x[1] + x[2], smem);
    float sdx = blk_sum4(dx[0] + dx[1] + dx[2], smem);
    const float mu = sx / D_, dmu = sdx / D_;
    float sv = 0.f, sc = 0.f;
    #pragma unroll
    for (int i = 0; i < 3; ++i) {
        const float xc = x[i] - mu;
        sv += xc * xc;
        sc += xc * (dx[i] - dmu);
    }
    sv = blk_sum4(sv, smem);
    sc = blk_sum4(sc, smem);
    const float rstd = rsqrtf(sv / D_ + 1e-6f);
    const float k2   = (sc / D_) * rstd * rstd;
    #pragma unroll
    for (int i = 0; i < 3; ++i) {
        const int c = t + 256 * i;
        const float yh  = (x[i] - mu) * rstd;
        const float dyh = (dx[i] - dmu) * rstd - yh * k2;
        const float yv  = yh * g[c] + b[c];
        const float dyv = dyh * g[c];
        if (WF32) { y[row * D_ + c] = yv; dy[row * D_ + c] = dyv; }
        ybf[row * D_ + c]  = (short)f2bf(yv);
        dybf[row * D_ + c] = (short)f2bf(dyv);
    }
}

__global__ __launch_bounds__(256) void cast_bf16_kernel(
    const float* __restrict__ in, short* __restrict__ out, int n4)
{
    for (int i = blockIdx.x * blockDim.x + threadIdx.x; i < n4;
         i += gridDim.x * blockDim.x) {
        const float4 v = ((const float4*)in)[i];
        short o[4];
        o[0] = (short)f2bf(v.x); o[1] = (short)f2bf(v.y);
        o[2] = (short)f2bf(v.z); o[3] = (short)f2bf(v.w);
        *(short4*)&out[i * 4] = *(short4*)o;
    }
}

// fused per-layer weight cast: qkv_w | out_w | fc1_w | fc2_w -> bf16 slabs
__global__ __launch_bounds__(256) void wcast_kernel(
    const float* __restrict__ qw, const float* __restrict__ ow,
    const float* __restrict__ f1, const float* __restrict__ f2,
    short* __restrict__ dq, short* __restrict__ dow,
    short* __restrict__ d1, short* __restrict__ d2)
{
    const int b1 = 442368;            // 3*D*D/4
    const int b2 = b1 + 147456;       // + D*D/4
    const int b3 = b2 + 589824;       // + MD*D/4
    const int total = b3 + 589824;    // + D*MD/4
    for (int i = blockIdx.x * blockDim.x + threadIdx.x; i < total;
         i += gridDim.x * blockDim.x) {
        const float* s; short* d; int j;
        if (i < b1)      { s = qw; d = dq;  j = i; }
        else if (i < b2) { s = ow; d = dow; j = i - b1; }
        else if (i < b3) { s = f1; d = d1;  j = i - b2; }
        else             { s = f2; d = d2;  j = i - b3; }
        const float4 v = ((const float4*)s)[j];
        short o[4];
        o[0] = (short)f2bf(v.x); o[1] = (short)f2bf(v.y);
        o[2] = (short)f2bf(v.z); o[3] = (short)f2bf(v.w);
        *(short4*)&d[j * 4] = *(short4*)o;
    }
}

__global__ __launch_bounds__(256) void im2col_kernel(
    const float* __restrict__ x, short* __restrict__ xp, int total)
{
    for (int i = blockIdx.x * blockDim.x + threadIdx.x; i < total;
         i += gridDim.x * blockDim.x) {
        const int k  = i % 768;
        const int m  = i / 768;
        const int gh = m % GP_;
        const int n  = m / GP_;
        const int q  = k & 15;
        const int p  = (k >> 4) & 15;
        const int c  = k >> 8;
        const int hc = gh % 14, gr = gh / 14;
        const int ir = gr * 16 + p, ic = hc * 16 + q;
        xp[i] = (short)f2bf(x[(((long long)n * 3 + c) * 224 + ir) * 224 + ic]);
    }
}

__global__ __launch_bounds__(256) void assemble_kernel(
    const float* __restrict__ tok, const float* __restrict__ dtok,
    float* __restrict__ z, float* __restrict__ dz,
    const float* __restrict__ cls, const float* __restrict__ pos, int total)
{
    for (int i = blockIdx.x * blockDim.x + threadIdx.x; i < total;
         i += gridDim.x * blockDim.x) {
        const int d = i % D_;
        const int s = (i / D_) % S_;
        const int n = i / (D_ * S_);
        if (s == 0) {
            z[i]  = cls[d] + pos[d];
            dz[i] = 0.f;
        } else {
            const long long ti = ((long long)n * GP_ + s - 1) * D_ + d;
            z[i]  = tok[ti]  + pos[s * D_ + d];
            dz[i] = dtok[ti];
        }
    }
}

// ================= host helpers =================
static inline void mgemm_pair(hipStream_t st, const short* Af, const short* At,
                              const short* Bm, const float* bias,
                              void* Cf, void* Ct, int Mhalf, int N, int K, int ldc,
                              int mode, bool hasbias)
{
    dim3 grid(N / 128, (Mhalf + 127) / 128);
    dim3 blk(512);
#define PK(MD_, BI) mfma_pair_kernel<MD_, BI><<<grid, blk, 0, st>>>(Af, At, Bm, bias, Cf, Ct, Mhalf, N, K, ldc)
    if (mode == 0) { if (hasbias) PK(0, true); else PK(0, false); }
    else if (mode == 1) { if (hasbias) PK(1, true); else PK(1, false); }
    else if (mode == 2) { if (hasbias) PK(2, true); else PK(2, false); }
    else { if (hasbias) PK(3, true); else PK(3, false); }
#undef PK
}

static inline void cast_bf(hipStream_t st, const float* in, short* out, long long n) {
    const int n4 = (int)(n / 4);
    int g = (n4 + 255) / 256; if (g > 4096) g = 4096;
    cast_bf16_kernel<<<g, 256, 0, st>>>(in, out, n4);
}

extern "C" void kernel_launch(void* const* d_in, const int* in_sizes, int n_in,
                              void* d_out, int out_size, void* d_ws, size_t ws_size,
                              hipStream_t stream)
{
    const float* x       = (const float*)d_in[0];
    const float* tangent = (const float*)d_in[1];
    const float* conv_w  = (const float*)d_in[2];
    const float* conv_b  = (const float*)d_in[3];
    const float* cls     = (const float*)d_in[4];
    const float* pos     = (const float*)d_in[5];
    const float* ln1_g   = (const float*)d_in[6];
    const float* ln1_b   = (const float*)d_in[7];
    const float* qkv_w   = (const float*)d_in[8];
    const float* qkv_b   = (const float*)d_in[9];
    const float* out_w   = (const float*)d_in[10];
    const float* out_b   = (const float*)d_in[11];
    const float* ln2_g   = (const float*)d_in[12];
    const float* ln2_b   = (const float*)d_in[13];
    const float* fc1_w   = (const float*)d_in[14];
    const float* fc1_b   = (const float*)d_in[15];
    const float* fc2_w   = (const float*)d_in[16];
    const float* fc2_b   = (const float*)d_in[17];
    const float* lnf_g   = (const float*)d_in[18];
    const float* lnf_b   = (const float*)d_in[19];
    const float* head_w  = (const float*)d_in[20];
    const float* head_b  = (const float*)d_in[21];
    float* out = (float*)d_out;

    const int nBS = B_ * S_;                            // 6304
    const int NB = B_ * H_;                             // 384
    const long long SD = (long long)S_ * D_;
    const long long PZ = (long long)MP_ * D_;           // 4,915,200
    const long long PQ = (long long)MP_ * 2304;         // 14,745,600
    const long long PH = (long long)MP_ * MD_;          // 19,660,800
    const long long PTOK = (long long)B_ * GP_ * D_;    // 4,816,896

    // ---- fp32 region ----
    float* f = (float*)d_ws;
    float* z     = f;             // [6400][768]
    float* dz    = z + PZ;
    float* tok   = dz + PZ;       // patch C: tok‖dtok; also final-LN y/dy
    float* dtok  = tok + PTOK;
    float* yf    = tok;
    float* dyf   = tok + PTOK;    // reuse (nBS*D < PTOK? 6304*768 > 6272*768; use separate)
    // NOTE: final-LN needs nBS rows; place dyf after yf with PZ stride instead:
    yf  = tok;                    // [6400][768] region available (PTOK*2 floats)
    dyf = tok + PZ;

    // ---- bf16 region ----
    short* sh     = (short*)(tok + 2 * PZ);
    short* ybf    = sh;                       // [6400][768] x2
    short* dybf   = ybf + PZ;
    short* qkvbf  = dybf + PZ;                // [6400][2304] x2
    short* dqkvbf = qkvbf + PQ;
    short* Vt     = dqkvbf + PQ;              // [384][64][224] x2
    short* dVt    = Vt + (long long)NB * 64 * KP_;
    short* hbf    = dVt + (long long)NB * 64 * KP_;   // [6400][3072] x2
    short* dhbf   = hbf + PH;
    short* xpbf   = hbf;                      // patch A alias
    short* dxpbf  = hbf + PTOK;
    short* wq     = dhbf + PH;
    short* wo     = wq + 2304 * 768;
    short* w1     = wo + 768 * 768;
    short* w2     = w1 + 3072 * 768;
    short* cwbf   = w2 + 768 * 3072;

    // ---- patch embedding (paired GEMM, Mhalf = 6272) ----
    {
        const int total = (int)PTOK;
        im2col_kernel<<<8192, 256, 0, stream>>>(x, xpbf, total);
        im2col_kernel<<<8192, 256, 0, stream>>>(tangent, dxpbf, total);
        cast_bf(stream, conv_w, cwbf, 768 * 768);
        mgemm_pair(stream, xpbf, dxpbf, cwbf, conv_b, tok, dtok,
                   B_ * GP_, D_, D_, D_, 0, true);
        const int tz = (int)(B_ * SD);
        assemble_kernel<<<8192, 256, 0, stream>>>(tok, dtok, z, dz, cls, pos, tz);
    }

    for (int l = 0; l < L_; ++l) {
        const float* l1g = ln1_g + (long long)l * D_;
        const float* l1b = ln1_b + (long long)l * D_;
        const float* qb  = qkv_b + (long long)l * 3 * D_;
        const float* ob  = out_b + (long long)l * D_;
        const float* l2g = ln2_g + (long long)l * D_;
        const float* l2b = ln2_b + (long long)l * D_;
        const float* f1b = fc1_b + (long long)l * MD_;
        const float* f2b = fc2_b + (long long)l * D_;

        wcast_kernel<<<4096, 256, 0, stream>>>(
            qkv_w + (long long)l * 3 * D_ * D_, out_w + (long long)l * D_ * D_,
            fc1_w + (long long)l * MD_ * D_,    fc2_w + (long long)l * D_ * MD_,
            wq, wo, w1, w2);

        // LN1
        ln_jvp_kernel<false><<<nBS, 256, 0, stream>>>(z, dz, l1g, l1b, nullptr, nullptr, ybf, dybf);
        // QKV (paired, bf16 out)
        mgemm_pair(stream, ybf, dybf, wq, qb, qkvbf, dqkvbf,
                   nBS, 3 * D_, D_, 3 * D_, 2, true);

        // attention: V transpose + fused JVP
        vtrans_kernel<<<NB * 4, 256, 0, stream>>>(qkvbf, dqkvbf, Vt, dVt);
        attn_fused_kernel<<<dim3(4, NB), 256, 0, stream>>>(qkvbf, dqkvbf, Vt, dVt, ybf, dybf);

        // projection + residual (paired, fp32 ACC into z/dz)
        mgemm_pair(stream, ybf, dybf, wo, ob, z, dz, nBS, D_, D_, D_, 1, true);

        // LN2 + MLP: FC1 with fused GELU-JVP -> bf16 hidden, FC2 ACC
        ln_jvp_kernel<false><<<nBS, 256, 0, stream>>>(z, dz, l2g, l2b, nullptr, nullptr, ybf, dybf);
        mgemm_pair(stream, ybf, dybf, w1, f1b, hbf, dhbf, nBS, MD_, D_, MD_, 3, true);
        mgemm_pair(stream, hbf, dhbf, w2, f2b, z, dz, nBS, D_, MD_, D_, 1, true);
    }

    // final LN (fp32 out) + head
    ln_jvp_kernel<true><<<nBS, 256, 0, stream>>>(z, dz, lnf_g, lnf_b, yf, dyf, ybf, dybf);
    gemm_kernel<true><<<dim3((NC_ + 63) / 64, 1), 256, 0, stream>>>(
        yf,  head_w, head_b, out,            B_, NC_, D_, (int)SD, D_, NC_);
    gemm_kernel<false><<<dim3((NC_ + 63) / 64, 1), 256, 0, stream>>>(
        dyf, head_w, nullptr, out + B_ * NC_, B_, NC_, D_, (int)SD, D_, NC_);
}